// Round 1
// baseline (2259.657 us; speedup 1.0000x reference)
//
#include <hip/hip_runtime.h>

#define H 4096
#define F 14336
#define NE 8
#define RR 32
#define NT 1024
#define MAXT 136

typedef unsigned short ushort_t;
typedef __attribute__((ext_vector_type(4))) float f32x4;
typedef __attribute__((ext_vector_type(8))) short short8v;
typedef __attribute__((ext_vector_type(8))) unsigned short ushort8;
typedef __attribute__((ext_vector_type(4))) unsigned short ushort4v;

__device__ inline unsigned short f2bf(float f){
  unsigned int x = __float_as_uint(f);
  return (unsigned short)((x + 0x7fffu + ((x>>16)&1u)) >> 16);
}
__device__ inline float bf2f(unsigned short u){
  return __uint_as_float(((unsigned int)u)<<16);
}

// ---------------- router: logits, softmax, top-2, counts ----------------
__global__ __launch_bounds__(256) void router_kernel(const float* __restrict__ x,
    const float* __restrict__ gw, float* __restrict__ logits,
    int* __restrict__ sel, float* __restrict__ rwn, int* __restrict__ cnt){
  int t = blockIdx.x*4 + (threadIdx.x>>6);
  int lane = threadIdx.x & 63;
  const float4* xr = (const float4*)(x + (size_t)t*H);
  float s[NE];
  #pragma unroll
  for (int e=0;e<NE;++e) s[e]=0.f;
  for (int c=lane; c<H/4; c+=64){
    float4 xv = xr[c];
    #pragma unroll
    for (int e=0;e<NE;++e){
      float4 g = ((const float4*)(gw + (size_t)e*H))[c];
      s[e] += xv.x*g.x + xv.y*g.y + xv.z*g.z + xv.w*g.w;
    }
  }
  #pragma unroll
  for (int e=0;e<NE;++e){
    for (int off=32; off; off>>=1) s[e] += __shfl_down(s[e], off);
  }
  if (lane==0){
    float mx = s[0];
    #pragma unroll
    for (int e=1;e<NE;++e) mx = fmaxf(mx, s[e]);
    float p[NE]; float den=0.f;
    #pragma unroll
    for (int e=0;e<NE;++e){ p[e]=__expf(s[e]-mx); den+=p[e]; }
    int i0=0;
    #pragma unroll
    for (int e=1;e<NE;++e) if (p[e]>p[i0]) i0=e;
    int i1 = (i0==0)?1:0;
    #pragma unroll
    for (int e=0;e<NE;++e){ if (e!=i0 && p[e]>p[i1]) i1=e; }
    float p0=p[i0]/den, p1=p[i1]/den;
    float inv = 1.f/(p0+p1);
    #pragma unroll
    for (int e=0;e<NE;++e) logits[t*NE+e] = s[e];
    sel[t*2]=i0; sel[t*2+1]=i1;
    rwn[t*2]=p0*inv; rwn[t*2+1]=p1*inv;
    atomicAdd(&cnt[i0],1); atomicAdd(&cnt[i1],1);
  }
}

// ---------------- prefix + tile table ----------------
__global__ void prefix_kernel(const int* __restrict__ cnt, int* __restrict__ off, int* __restrict__ meta){
  if (threadIdx.x==0 && blockIdx.x==0){
    int o=0;
    for (int e=0;e<NE;++e){ off[e]=o; o+=cnt[e]; }
    off[NE]=o;
    int ntl=0;
    for (int e=0;e<NE;++e){
      int c=cnt[e], b=off[e];
      for (int ps=0; ps<c; ps+=16){
        meta[1+ntl] = e;
        meta[1+MAXT+ntl] = b+ps;
        meta[1+2*MAXT+ntl] = (c-ps<16)?(c-ps):16;
        ++ntl;
      }
    }
    meta[0]=ntl;
  }
}

// ---------------- scatter: build pair lists ----------------
__global__ void scatter_kernel(const int* __restrict__ sel, const int* __restrict__ off,
    int* __restrict__ cnt2, int* __restrict__ list_tok, int* __restrict__ list_e,
    int* __restrict__ tok2pair){
  int idx = blockIdx.x*256 + threadIdx.x;
  if (idx >= NT*2) return;
  int e = sel[idx];
  int pos = atomicAdd(&cnt2[e], 1);
  int pair = off[e] + pos;
  list_tok[pair] = idx>>1;
  list_e[pair] = e;
  tok2pair[idx] = pair;
}

// ---------------- cast hidden states to bf16 ----------------
__global__ __launch_bounds__(256) void cast_x(const float* __restrict__ x, ushort_t* __restrict__ xbf){
  size_t i = ((size_t)blockIdx.x*256 + threadIdx.x)*4;
  if (i >= (size_t)NT*H) return;
  float4 v = *(const float4*)(x+i);
  ushort4v o;
  o[0]=f2bf(v.x); o[1]=f2bf(v.y); o[2]=f2bf(v.z); o[3]=f2bf(v.w);
  *(ushort4v*)(xbf+i) = o;
}

// ---------------- 128xBN MFMA GEMM, A bf16, B fp32 (NxK, converted in staging) ----------------
template<int BN, bool OUTBF>
__global__ __launch_bounds__(256) void gemm_bt(const ushort_t* __restrict__ A,
    const float* __restrict__ Bw, void* __restrict__ Cout, int M, int N, int K){
  constexpr int BM=128, BK=32, LD=40;
  __shared__ ushort_t As[BM*LD];
  __shared__ ushort_t Bs[BN*LD];
  const int tid = threadIdx.x;
  const int bm = blockIdx.x*BM, bn = blockIdx.y*BN;
  const int wv = tid>>6, lane = tid&63;
  const int wm = (wv>>1)*64, wn = (wv&1)*(BN/2);
  const int lr = lane&15, lk = lane>>4;
  constexpr int NJ = BN/32;
  f32x4 acc[4][NJ];
  #pragma unroll
  for (int i=0;i<4;++i)
    #pragma unroll
    for (int j=0;j<NJ;++j) acc[i][j] = (f32x4){0.f,0.f,0.f,0.f};
  const int arow = tid>>1, ak=(tid&1)*16;
  constexpr int BPT = BN*BK/256;
  const int brow = (BN==128)?(tid>>1):(tid>>2);
  const int bk   = (BN==128)?((tid&1)*16):((tid&3)*8);
  const ushort_t* gA = A + (size_t)(bm+arow)*K + ak;
  const float*    gB = Bw + (size_t)(bn+brow)*K + bk;
  for (int k0=0;k0<K;k0+=BK){
    ushort8 a0 = *(const ushort8*)(gA + k0);
    ushort8 a1 = *(const ushort8*)(gA + k0 + 8);
    float vals[BPT];
    #pragma unroll
    for (int i=0;i<BPT;i+=4){
      float4 v = *(const float4*)(gB + k0 + i);
      vals[i]=v.x; vals[i+1]=v.y; vals[i+2]=v.z; vals[i+3]=v.w;
    }
    *(ushort8*)&As[arow*LD+ak]   = a0;
    *(ushort8*)&As[arow*LD+ak+8] = a1;
    #pragma unroll
    for (int i=0;i<BPT;i+=8){
      ushort8 u;
      #pragma unroll
      for (int q=0;q<8;++q) u[q]=f2bf(vals[i+q]);
      *(ushort8*)&Bs[brow*LD+bk+i] = u;
    }
    __syncthreads();
    short8v af[4], bfv[NJ];
    #pragma unroll
    for (int i=0;i<4;++i) af[i] = *(const short8v*)&As[(wm+i*16+lr)*LD + lk*8];
    #pragma unroll
    for (int j=0;j<NJ;++j) bfv[j] = *(const short8v*)&Bs[(wn+j*16+lr)*LD + lk*8];
    #pragma unroll
    for (int i=0;i<4;++i)
      #pragma unroll
      for (int j=0;j<NJ;++j)
        acc[i][j] = __builtin_amdgcn_mfma_f32_16x16x32_bf16(af[i], bfv[j], acc[i][j], 0,0,0);
    __syncthreads();
  }
  #pragma unroll
  for (int i=0;i<4;++i)
    #pragma unroll
    for (int j=0;j<NJ;++j)
      #pragma unroll
      for (int r=0;r<4;++r){
        int row = bm + wm + i*16 + lk*4 + r;
        int col = bn + wn + j*16 + lr;
        if (OUTBF) ((ushort_t*)Cout)[(size_t)row*N + col] = f2bf(acc[i][j][r]);
        else       ((float*)Cout)[(size_t)row*N + col]    = acc[i][j][r];
      }
}

// ---------------- LoRA A projections: u1,u3 per pair (fp32 x, fp32 A) ----------------
__global__ __launch_bounds__(256) void lora_a(const int* __restrict__ list_tok, const int* __restrict__ list_e,
    const float* __restrict__ x, const float* __restrict__ A1, const float* __restrict__ A3,
    ushort_t* __restrict__ u1bf, ushort_t* __restrict__ u3bf){
  int pair = blockIdx.x*8 + (threadIdx.x>>5);
  int r = threadIdx.x&31;
  int t = list_tok[pair], e = list_e[pair];
  const float4* a1 = (const float4*)(A1 + ((size_t)e*RR + r)*H);
  const float4* a3 = (const float4*)(A3 + ((size_t)e*RR + r)*H);
  const float4* xr = (const float4*)(x + (size_t)t*H);
  float s1=0.f, s3=0.f;
  for (int c=0;c<H/4;++c){
    float4 xv = xr[c];
    float4 v1 = a1[c]; s1 += xv.x*v1.x + xv.y*v1.y + xv.z*v1.z + xv.w*v1.w;
    float4 v3 = a3[c]; s3 += xv.x*v3.x + xv.y*v3.y + xv.z*v3.z + xv.w*v3.w;
  }
  u1bf[pair*RR + r] = f2bf(s1);
  u3bf[pair*RR + r] = f2bf(s3);
}

// ---------------- per-expert fused: d1/d3 via MFMA (K=R=32), silu, x2 ----------------
__global__ __launch_bounds__(256) void expert_x2(const int* __restrict__ meta, const int* __restrict__ list_tok,
    const float* __restrict__ B1g, const float* __restrict__ B3g,
    const ushort_t* __restrict__ u1bf, const ushort_t* __restrict__ u3bf,
    const ushort_t* __restrict__ x1b, const ushort_t* __restrict__ x3b,
    ushort_t* __restrict__ x2buf){
  int ti = blockIdx.x;
  if (ti >= meta[0]) return;
  int e  = meta[1+ti];
  int p0 = meta[1+MAXT+ti];
  int np = meta[1+2*MAXT+ti];
  int fc = blockIdx.y*128 + (threadIdx.x>>6)*32;
  int lane = threadIdx.x&63;
  int lr = lane&15, lk = lane>>4;
  short8v au1 = *(const short8v*)(u1bf + (size_t)(p0+lr)*RR + lk*8);
  short8v au3 = *(const short8v*)(u3bf + (size_t)(p0+lr)*RR + lk*8);
  f32x4 z = (f32x4){0.f,0.f,0.f,0.f};
  f32x4 acc1[2], acc3[2];
  #pragma unroll
  for (int j=0;j<2;++j){
    acc1[j]=z; acc3[j]=z;
    int f = fc + j*16 + lr;
    const float* b1r = B1g + ((size_t)e*F + f)*RR + lk*8;
    const float* b3r = B3g + ((size_t)e*F + f)*RR + lk*8;
    float4 v0=*(const float4*)b1r, v1=*(const float4*)(b1r+4);
    float4 w0=*(const float4*)b3r, w1=*(const float4*)(b3r+4);
    short8v bb1, bb3;
    bb1[0]=(short)f2bf(v0.x); bb1[1]=(short)f2bf(v0.y); bb1[2]=(short)f2bf(v0.z); bb1[3]=(short)f2bf(v0.w);
    bb1[4]=(short)f2bf(v1.x); bb1[5]=(short)f2bf(v1.y); bb1[6]=(short)f2bf(v1.z); bb1[7]=(short)f2bf(v1.w);
    bb3[0]=(short)f2bf(w0.x); bb3[1]=(short)f2bf(w0.y); bb3[2]=(short)f2bf(w0.z); bb3[3]=(short)f2bf(w0.w);
    bb3[4]=(short)f2bf(w1.x); bb3[5]=(short)f2bf(w1.y); bb3[6]=(short)f2bf(w1.z); bb3[7]=(short)f2bf(w1.w);
    acc1[j] = __builtin_amdgcn_mfma_f32_16x16x32_bf16(au1, bb1, acc1[j], 0,0,0);
    acc3[j] = __builtin_amdgcn_mfma_f32_16x16x32_bf16(au3, bb3, acc3[j], 0,0,0);
  }
  #pragma unroll
  for (int r=0;r<4;++r){
    int p = lk*4 + r;
    if (p < np){
      int t = list_tok[p0+p];
      #pragma unroll
      for (int j=0;j<2;++j){
        int f = fc + j*16 + lr;
        size_t ix = (size_t)t*F + f;
        float x1  = bf2f(x1b[ix]) + acc1[j][r];
        float x3v = bf2f(x3b[ix]) + acc3[j][r];
        float sl = x1/(1.f + __expf(-x1));
        x2buf[(size_t)(p0+p)*F + f] = f2bf(sl*x3v);
      }
    }
  }
}

// ---------------- combine the two expert outputs per token -> x2c (bf16) ----------------
__global__ __launch_bounds__(256) void combine_x2(const int* __restrict__ tok2pair, const float* __restrict__ rwn,
    const ushort_t* __restrict__ x2buf, ushort_t* __restrict__ x2c){
  size_t i = (size_t)blockIdx.x*256 + threadIdx.x;
  size_t total = (size_t)NT*(F/8);
  if (i>=total) return;
  int t = (int)(i/(F/8));
  int c = (int)(i%(F/8))*8;
  int pa = tok2pair[t*2], pb = tok2pair[t*2+1];
  float wa = rwn[t*2], wb = rwn[t*2+1];
  ushort8 va = *(const ushort8*)(x2buf + (size_t)pa*F + c);
  ushort8 vb = *(const ushort8*)(x2buf + (size_t)pb*F + c);
  ushort8 o;
  #pragma unroll
  for (int q=0;q<8;++q) o[q] = f2bf(wa*bf2f(va[q]) + wb*bf2f(vb[q]));
  *(ushort8*)(x2c + (size_t)t*F + c) = o;
}

// ---------------- u2 = A2[e] @ x2 per pair ----------------
__global__ __launch_bounds__(256) void u2_kernel(const int* __restrict__ list_e,
    const float* __restrict__ A2, const ushort_t* __restrict__ x2buf, float* __restrict__ u2){
  int pair = blockIdx.x*8 + (threadIdx.x>>5);
  int r = threadIdx.x&31;
  int e = list_e[pair];
  const float4* a = (const float4*)(A2 + ((size_t)e*RR + r)*F);
  const ushort4v* xp = (const ushort4v*)(x2buf + (size_t)pair*F);
  float s=0.f;
  for (int c=0;c<F/4;++c){
    float4 av = a[c];
    ushort4v xv = xp[c];
    s += av.x*bf2f(xv[0]) + av.y*bf2f(xv[1]) + av.z*bf2f(xv[2]) + av.w*bf2f(xv[3]);
  }
  u2[(size_t)pair*RR + r] = s;
}

// ---------------- lora2 add: out += sum_slots w * B2[e] @ u2 ----------------
__global__ __launch_bounds__(256) void lora2_add(const int* __restrict__ tok2pair, const int* __restrict__ list_e,
    const float* __restrict__ rwn, const float* __restrict__ B2, const float* __restrict__ u2,
    float* __restrict__ out){
  int t = blockIdx.x;
  __shared__ float u2s[2][RR];
  __shared__ int es[2];
  __shared__ float wss[2];
  if (threadIdx.x < 64){
    int s = threadIdx.x>>5, r = threadIdx.x&31;
    int pair = tok2pair[t*2+s];
    u2s[s][r] = u2[(size_t)pair*RR + r];
    if (r==0){ es[s]=list_e[pair]; wss[s]=rwn[t*2+s]; }
  }
  __syncthreads();
  int e0=es[0], e1=es[1];
  float w0=wss[0], w1=wss[1];
  for (int h=threadIdx.x; h<H; h+=256){
    const float4* b0 = (const float4*)(B2 + ((size_t)e0*H + h)*RR);
    const float4* b1 = (const float4*)(B2 + ((size_t)e1*H + h)*RR);
    float d0=0.f, d1=0.f;
    #pragma unroll
    for (int c=0;c<RR/4;++c){
      float4 v0=b0[c]; d0 += v0.x*u2s[0][c*4+0] + v0.y*u2s[0][c*4+1] + v0.z*u2s[0][c*4+2] + v0.w*u2s[0][c*4+3];
      float4 v1=b1[c]; d1 += v1.x*u2s[1][c*4+0] + v1.y*u2s[1][c*4+1] + v1.z*u2s[1][c*4+2] + v1.w*u2s[1][c*4+3];
    }
    out[(size_t)t*H + h] += w0*d0 + w1*d1;
  }
}

extern "C" void kernel_launch(void* const* d_in, const int* in_sizes, int n_in,
                              void* d_out, int out_size, void* d_ws, size_t ws_size,
                              hipStream_t stream){
  const float* x   = (const float*)d_in[0];
  const float* gw  = (const float*)d_in[1];
  const float* W1  = (const float*)d_in[2];
  const float* W2  = (const float*)d_in[3];
  const float* W3  = (const float*)d_in[4];
  const float* A1  = (const float*)d_in[5];
  const float* B1  = (const float*)d_in[6];
  const float* A2  = (const float*)d_in[7];
  const float* B2  = (const float*)d_in[8];
  const float* A3  = (const float*)d_in[9];
  const float* B3  = (const float*)d_in[10];
  float* outF = (float*)d_out;
  float* outL = outF + (size_t)NT*H;

  char* base = (char*)d_ws;
  size_t o = 0;
  auto mk = [&](size_t bytes){ void* p = base + o; o += (bytes + 255) & ~(size_t)255; return p; };
  int*   sel      = (int*)  mk((size_t)NT*2*4);
  float* rwn      = (float*)mk((size_t)NT*2*4);
  int*   cnts     = (int*)  mk(512);
  int*   cnt      = cnts;
  int*   cnt2     = cnts + 64;
  int*   off      = (int*)  mk(256);
  int*   meta     = (int*)  mk((size_t)(1+3*MAXT)*4);
  int*   list_tok = (int*)  mk(2048*4);
  int*   list_e   = (int*)  mk(2048*4);
  int*   tok2pair = (int*)  mk((size_t)NT*2*4);
  ushort_t* xbf   = (ushort_t*)mk((size_t)NT*H*2);
  ushort_t* x1b   = (ushort_t*)mk((size_t)NT*F*2);
  ushort_t* x3b   = (ushort_t*)mk((size_t)NT*F*2);
  ushort_t* x2buf = (ushort_t*)mk((size_t)2048*F*2);
  ushort_t* x2c   = (ushort_t*)mk((size_t)NT*F*2);
  ushort_t* u1bf  = (ushort_t*)mk((size_t)2048*RR*2);
  ushort_t* u3bf  = (ushort_t*)mk((size_t)2048*RR*2);
  float* u2       = (float*)mk((size_t)2048*RR*4);
  (void)ws_size; (void)in_sizes; (void)n_in; (void)out_size;

  hipMemsetAsync(cnts, 0, 512, stream);
  router_kernel<<<NT/4, 256, 0, stream>>>(x, gw, outL, sel, rwn, cnt);
  prefix_kernel<<<1, 1, 0, stream>>>(cnt, off, meta);
  scatter_kernel<<<(NT*2+255)/256, 256, 0, stream>>>(sel, off, cnt2, list_tok, list_e, tok2pair);
  cast_x<<<(NT*H/4)/256, 256, 0, stream>>>(x, xbf);
  gemm_bt<128,true><<<dim3(NT/128, F/128), 256, 0, stream>>>(xbf, W1, x1b, NT, F, H);
  gemm_bt<128,true><<<dim3(NT/128, F/128), 256, 0, stream>>>(xbf, W3, x3b, NT, F, H);
  lora_a<<<2048/8, 256, 0, stream>>>(list_tok, list_e, x, A1, A3, u1bf, u3bf);
  expert_x2<<<dim3(MAXT, F/128), 256, 0, stream>>>(meta, list_tok, B1, B3, u1bf, u3bf, x1b, x3b, x2buf);
  combine_x2<<<(NT*(F/8))/256, 256, 0, stream>>>(tok2pair, rwn, x2buf, x2c);
  u2_kernel<<<2048/8, 256, 0, stream>>>(list_e, A2, x2buf, u2);
  gemm_bt<64,false><<<dim3(NT/128, H/64), 256, 0, stream>>>(x2c, W2, outF, NT, H, F);
  lora2_add<<<NT, 256, 0, stream>>>(tok2pair, list_e, rwn, B2, u2, outF);
}

// Round 2
// 1693.791 us; speedup vs baseline: 1.3341x; 1.3341x over previous
//
#include <hip/hip_runtime.h>

#define H 4096
#define F 14336
#define NE 8
#define RR 32
#define NT 1024
#define MAXT 136
#define NPAIR 2048
#define NPAIRP 2064   // padded (tile overrun on last expert)

typedef unsigned short ushort_t;
typedef __attribute__((ext_vector_type(4))) float f32x4;
typedef __attribute__((ext_vector_type(8))) short short8v;
typedef __attribute__((ext_vector_type(8))) unsigned short ushort8;
typedef __attribute__((ext_vector_type(4))) unsigned short ushort4v;

__device__ inline unsigned short f2bf(float f){
  unsigned int x = __float_as_uint(f);
  return (unsigned short)((x + 0x7fffu + ((x>>16)&1u)) >> 16);
}
__device__ inline float bf2f(unsigned short u){
  return __uint_as_float(((unsigned int)u)<<16);
}
__device__ inline short8v cvt8(const float* p){
  float4 v0 = *(const float4*)p, v1 = *(const float4*)(p+4);
  short8v b;
  b[0]=(short)f2bf(v0.x); b[1]=(short)f2bf(v0.y); b[2]=(short)f2bf(v0.z); b[3]=(short)f2bf(v0.w);
  b[4]=(short)f2bf(v1.x); b[5]=(short)f2bf(v1.y); b[6]=(short)f2bf(v1.z); b[7]=(short)f2bf(v1.w);
  return b;
}

// ---------------- router: logits, softmax, top-2, counts ----------------
__global__ __launch_bounds__(256) void router_kernel(const float* __restrict__ x,
    const float* __restrict__ gw, float* __restrict__ logits,
    int* __restrict__ sel, float* __restrict__ rwn, int* __restrict__ cnt){
  int t = blockIdx.x*4 + (threadIdx.x>>6);
  int lane = threadIdx.x & 63;
  const float4* xr = (const float4*)(x + (size_t)t*H);
  float s[NE];
  #pragma unroll
  for (int e=0;e<NE;++e) s[e]=0.f;
  for (int c=lane; c<H/4; c+=64){
    float4 xv = xr[c];
    #pragma unroll
    for (int e=0;e<NE;++e){
      float4 g = ((const float4*)(gw + (size_t)e*H))[c];
      s[e] += xv.x*g.x + xv.y*g.y + xv.z*g.z + xv.w*g.w;
    }
  }
  #pragma unroll
  for (int e=0;e<NE;++e){
    for (int off=32; off; off>>=1) s[e] += __shfl_down(s[e], off);
  }
  if (lane==0){
    float mx = s[0];
    #pragma unroll
    for (int e=1;e<NE;++e) mx = fmaxf(mx, s[e]);
    float p[NE]; float den=0.f;
    #pragma unroll
    for (int e=0;e<NE;++e){ p[e]=__expf(s[e]-mx); den+=p[e]; }
    int i0=0;
    #pragma unroll
    for (int e=1;e<NE;++e) if (p[e]>p[i0]) i0=e;
    int i1 = (i0==0)?1:0;
    #pragma unroll
    for (int e=0;e<NE;++e){ if (e!=i0 && p[e]>p[i1]) i1=e; }
    float p0=p[i0]/den, p1=p[i1]/den;
    float inv = 1.f/(p0+p1);
    #pragma unroll
    for (int e=0;e<NE;++e) logits[t*NE+e] = s[e];
    sel[t*2]=i0; sel[t*2+1]=i1;
    rwn[t*2]=p0*inv; rwn[t*2+1]=p1*inv;
    atomicAdd(&cnt[i0],1); atomicAdd(&cnt[i1],1);
  }
}

// ---------------- prefix + tile table ----------------
__global__ void prefix_kernel(const int* __restrict__ cnt, int* __restrict__ off, int* __restrict__ meta){
  if (threadIdx.x==0 && blockIdx.x==0){
    int o=0;
    for (int e=0;e<NE;++e){ off[e]=o; o+=cnt[e]; }
    off[NE]=o;
    int ntl=0;
    for (int e=0;e<NE;++e){
      int c=cnt[e], b=off[e];
      for (int ps=0; ps<c; ps+=16){
        meta[1+ntl] = e;
        meta[1+MAXT+ntl] = b+ps;
        meta[1+2*MAXT+ntl] = (c-ps<16)?(c-ps):16;
        ++ntl;
      }
    }
    meta[0]=ntl;
  }
}

// ---------------- scatter: build pair lists (+pad) ----------------
__global__ void scatter_kernel(const int* __restrict__ sel, const int* __restrict__ off,
    int* __restrict__ cnt2, int* __restrict__ list_tok, int* __restrict__ list_e,
    int* __restrict__ tok2pair){
  int idx = blockIdx.x*256 + threadIdx.x;
  if (idx >= NT*2){
    if (idx < NPAIRP){ list_tok[idx]=0; list_e[idx]=0; }
    return;
  }
  int e = sel[idx];
  int pos = atomicAdd(&cnt2[e], 1);
  int pair = off[e] + pos;
  list_tok[pair] = idx>>1;
  list_e[pair] = e;
  tok2pair[idx] = pair;
}

// ---------------- cast hidden states to bf16 ----------------
__global__ __launch_bounds__(256) void cast_x(const float* __restrict__ x, ushort_t* __restrict__ xbf){
  size_t i = ((size_t)blockIdx.x*256 + threadIdx.x)*4;
  if (i >= (size_t)NT*H) return;
  float4 v = *(const float4*)(x+i);
  ushort4v o;
  o[0]=f2bf(v.x); o[1]=f2bf(v.y); o[2]=f2bf(v.z); o[3]=f2bf(v.w);
  *(ushort4v*)(xbf+i) = o;
}

// ---------------- 128xBN MFMA GEMM, A bf16, B fp32 (NxK, converted in staging) ----------------
template<int BN, bool OUTBF>
__global__ __launch_bounds__(256) void gemm_bt(const ushort_t* __restrict__ A,
    const float* __restrict__ Bw, void* __restrict__ Cout, int M, int N, int K){
  constexpr int BM=128, BK=32, LD=40;
  __shared__ ushort_t As[BM*LD];
  __shared__ ushort_t Bs[BN*LD];
  const int tid = threadIdx.x;
  const int bm = blockIdx.x*BM, bn = blockIdx.y*BN;
  const int wv = tid>>6, lane = tid&63;
  const int wm = (wv>>1)*64, wn = (wv&1)*(BN/2);
  const int lr = lane&15, lk = lane>>4;
  constexpr int NJ = BN/32;
  f32x4 acc[4][NJ];
  #pragma unroll
  for (int i=0;i<4;++i)
    #pragma unroll
    for (int j=0;j<NJ;++j) acc[i][j] = (f32x4){0.f,0.f,0.f,0.f};
  const int arow = tid>>1, ak=(tid&1)*16;
  constexpr int BPT = BN*BK/256;
  const int brow = (BN==128)?(tid>>1):(tid>>2);
  const int bk   = (BN==128)?((tid&1)*16):((tid&3)*8);
  const ushort_t* gA = A + (size_t)(bm+arow)*K + ak;
  const float*    gB = Bw + (size_t)(bn+brow)*K + bk;
  for (int k0=0;k0<K;k0+=BK){
    ushort8 a0 = *(const ushort8*)(gA + k0);
    ushort8 a1 = *(const ushort8*)(gA + k0 + 8);
    float vals[BPT];
    #pragma unroll
    for (int i=0;i<BPT;i+=4){
      float4 v = *(const float4*)(gB + k0 + i);
      vals[i]=v.x; vals[i+1]=v.y; vals[i+2]=v.z; vals[i+3]=v.w;
    }
    *(ushort8*)&As[arow*LD+ak]   = a0;
    *(ushort8*)&As[arow*LD+ak+8] = a1;
    #pragma unroll
    for (int i=0;i<BPT;i+=8){
      ushort8 u;
      #pragma unroll
      for (int q=0;q<8;++q) u[q]=f2bf(vals[i+q]);
      *(ushort8*)&Bs[brow*LD+bk+i] = u;
    }
    __syncthreads();
    short8v af[4], bfv[NJ];
    #pragma unroll
    for (int i=0;i<4;++i) af[i] = *(const short8v*)&As[(wm+i*16+lr)*LD + lk*8];
    #pragma unroll
    for (int j=0;j<NJ;++j) bfv[j] = *(const short8v*)&Bs[(wn+j*16+lr)*LD + lk*8];
    #pragma unroll
    for (int i=0;i<4;++i)
      #pragma unroll
      for (int j=0;j<NJ;++j)
        acc[i][j] = __builtin_amdgcn_mfma_f32_16x16x32_bf16(af[i], bfv[j], acc[i][j], 0,0,0);
    __syncthreads();
  }
  #pragma unroll
  for (int i=0;i<4;++i)
    #pragma unroll
    for (int j=0;j<NJ;++j)
      #pragma unroll
      for (int r=0;r<4;++r){
        int row = bm + wm + i*16 + lk*4 + r;
        int col = bn + wn + j*16 + lr;
        if (OUTBF) ((ushort_t*)Cout)[(size_t)row*N + col] = f2bf(acc[i][j][r]);
        else       ((float*)Cout)[(size_t)row*N + col]    = acc[i][j][r];
      }
}

// ---------------- LoRA A projections via MFMA: u1,u3 per pair-tile ----------------
// M=16 pairs (gathered token rows), N=32 ranks, K=H. 4 waves split K; LDS reduce.
__global__ __launch_bounds__(256) void lora_a_mfma(const int* __restrict__ meta,
    const int* __restrict__ list_tok, const ushort_t* __restrict__ xbf,
    const float* __restrict__ A1, const float* __restrict__ A3,
    ushort_t* __restrict__ u1bf, ushort_t* __restrict__ u3bf){
  int ti = blockIdx.x;
  if (ti >= meta[0]) return;
  int e  = meta[1+ti];
  int p0 = meta[1+MAXT+ti];
  int np = meta[1+2*MAXT+ti];
  int wv = threadIdx.x>>6, lane = threadIdx.x&63;
  int lr = lane&15, lk = lane>>4;
  int t = list_tok[p0+lr];
  const ushort_t* xrow = xbf + (size_t)t*H;
  const int kbase = wv*(H/4);
  f32x4 acc1[2], acc3[2];
  #pragma unroll
  for (int j=0;j<2;++j){ acc1[j]=(f32x4){0,0,0,0}; acc3[j]=(f32x4){0,0,0,0}; }
  for (int ks=0; ks<H/4; ks+=32){
    int k = kbase + ks + lk*8;
    short8v a = *(const short8v*)(xrow + k);
    #pragma unroll
    for (int j=0;j<2;++j){
      const float* b1 = A1 + ((size_t)e*RR + j*16 + lr)*H + k;
      const float* b3 = A3 + ((size_t)e*RR + j*16 + lr)*H + k;
      acc1[j] = __builtin_amdgcn_mfma_f32_16x16x32_bf16(a, cvt8(b1), acc1[j], 0,0,0);
      acc3[j] = __builtin_amdgcn_mfma_f32_16x16x32_bf16(a, cvt8(b3), acc3[j], 0,0,0);
    }
  }
  __shared__ float red[4][2][2][4][64];
  #pragma unroll
  for (int j=0;j<2;++j)
    #pragma unroll
    for (int r=0;r<4;++r){
      red[wv][0][j][r][lane] = acc1[j][r];
      red[wv][1][j][r][lane] = acc3[j][r];
    }
  __syncthreads();
  if (wv==0){
    #pragma unroll
    for (int j=0;j<2;++j)
      #pragma unroll
      for (int r=0;r<4;++r){
        int p = lk*4 + r;
        if (p < np){
          float s1 = red[0][0][j][r][lane]+red[1][0][j][r][lane]+red[2][0][j][r][lane]+red[3][0][j][r][lane];
          float s3 = red[0][1][j][r][lane]+red[1][1][j][r][lane]+red[2][1][j][r][lane]+red[3][1][j][r][lane];
          u1bf[(size_t)(p0+p)*RR + j*16 + lr] = f2bf(s1);
          u3bf[(size_t)(p0+p)*RR + j*16 + lr] = f2bf(s3);
        }
      }
  }
}

// ---------------- per-expert fused: d1/d3 via MFMA (K=R=32), silu, x2 ----------------
__global__ __launch_bounds__(256) void expert_x2(const int* __restrict__ meta, const int* __restrict__ list_tok,
    const float* __restrict__ B1g, const float* __restrict__ B3g,
    const ushort_t* __restrict__ u1bf, const ushort_t* __restrict__ u3bf,
    const ushort_t* __restrict__ x1b, const ushort_t* __restrict__ x3b,
    ushort_t* __restrict__ x2buf){
  int ti = blockIdx.x;
  if (ti >= meta[0]) return;
  int e  = meta[1+ti];
  int p0 = meta[1+MAXT+ti];
  int np = meta[1+2*MAXT+ti];
  int fc = blockIdx.y*128 + (threadIdx.x>>6)*32;
  int lane = threadIdx.x&63;
  int lr = lane&15, lk = lane>>4;
  short8v au1 = *(const short8v*)(u1bf + (size_t)(p0+lr)*RR + lk*8);
  short8v au3 = *(const short8v*)(u3bf + (size_t)(p0+lr)*RR + lk*8);
  f32x4 z = (f32x4){0.f,0.f,0.f,0.f};
  f32x4 acc1[2], acc3[2];
  #pragma unroll
  for (int j=0;j<2;++j){
    acc1[j]=z; acc3[j]=z;
    int f = fc + j*16 + lr;
    const float* b1r = B1g + ((size_t)e*F + f)*RR + lk*8;
    const float* b3r = B3g + ((size_t)e*F + f)*RR + lk*8;
    acc1[j] = __builtin_amdgcn_mfma_f32_16x16x32_bf16(au1, cvt8(b1r), acc1[j], 0,0,0);
    acc3[j] = __builtin_amdgcn_mfma_f32_16x16x32_bf16(au3, cvt8(b3r), acc3[j], 0,0,0);
  }
  #pragma unroll
  for (int r=0;r<4;++r){
    int p = lk*4 + r;
    if (p < np){
      int t = list_tok[p0+p];
      #pragma unroll
      for (int j=0;j<2;++j){
        int f = fc + j*16 + lr;
        size_t ix = (size_t)t*F + f;
        float x1  = bf2f(x1b[ix]) + acc1[j][r];
        float x3v = bf2f(x3b[ix]) + acc3[j][r];
        float sl = x1/(1.f + __expf(-x1));
        x2buf[(size_t)(p0+p)*F + f] = f2bf(sl*x3v);
      }
    }
  }
}

// ---------------- combine the two expert outputs per token -> x2c (bf16) ----------------
__global__ __launch_bounds__(256) void combine_x2(const int* __restrict__ tok2pair, const float* __restrict__ rwn,
    const ushort_t* __restrict__ x2buf, ushort_t* __restrict__ x2c){
  size_t i = (size_t)blockIdx.x*256 + threadIdx.x;
  size_t total = (size_t)NT*(F/8);
  if (i>=total) return;
  int t = (int)(i/(F/8));
  int c = (int)(i%(F/8))*8;
  int pa = tok2pair[t*2], pb = tok2pair[t*2+1];
  float wa = rwn[t*2], wb = rwn[t*2+1];
  ushort8 va = *(const ushort8*)(x2buf + (size_t)pa*F + c);
  ushort8 vb = *(const ushort8*)(x2buf + (size_t)pb*F + c);
  ushort8 o;
  #pragma unroll
  for (int q=0;q<8;++q) o[q] = f2bf(wa*bf2f(va[q]) + wb*bf2f(vb[q]));
  *(ushort8*)(x2c + (size_t)t*F + c) = o;
}

// ---------------- u2 = A2[e] @ x2 via MFMA per pair-tile ----------------
// M=16 pairs (x2buf rows), N=32 ranks, K=F. 4 waves split K; LDS reduce.
__global__ __launch_bounds__(256) void u2_mfma(const int* __restrict__ meta,
    const float* __restrict__ A2, const ushort_t* __restrict__ x2buf, float* __restrict__ u2){
  int ti = blockIdx.x;
  if (ti >= meta[0]) return;
  int e  = meta[1+ti];
  int p0 = meta[1+MAXT+ti];
  int np = meta[1+2*MAXT+ti];
  int wv = threadIdx.x>>6, lane = threadIdx.x&63;
  int lr = lane&15, lk = lane>>4;
  const ushort_t* xrow = x2buf + (size_t)(p0+lr)*F;
  const int kbase = wv*(F/4);
  f32x4 acc[2];
  acc[0]=(f32x4){0,0,0,0}; acc[1]=(f32x4){0,0,0,0};
  for (int ks=0; ks<F/4; ks+=32){
    int k = kbase + ks + lk*8;
    short8v a = *(const short8v*)(xrow + k);
    #pragma unroll
    for (int j=0;j<2;++j){
      const float* br = A2 + ((size_t)e*RR + j*16 + lr)*F + k;
      acc[j] = __builtin_amdgcn_mfma_f32_16x16x32_bf16(a, cvt8(br), acc[j], 0,0,0);
    }
  }
  __shared__ float red[4][2][4][64];
  #pragma unroll
  for (int j=0;j<2;++j)
    #pragma unroll
    for (int r=0;r<4;++r) red[wv][j][r][lane] = acc[j][r];
  __syncthreads();
  if (wv==0){
    #pragma unroll
    for (int j=0;j<2;++j)
      #pragma unroll
      for (int r=0;r<4;++r){
        int p = lk*4 + r;
        if (p < np){
          float s = red[0][j][r][lane]+red[1][j][r][lane]+red[2][j][r][lane]+red[3][j][r][lane];
          u2[(size_t)(p0+p)*RR + j*16 + lr] = s;
        }
      }
  }
}

// ---------------- lora2 add: out += sum_slots w * B2[e] @ u2 ----------------
__global__ __launch_bounds__(256) void lora2_add(const int* __restrict__ tok2pair, const int* __restrict__ list_e,
    const float* __restrict__ rwn, const float* __restrict__ B2, const float* __restrict__ u2,
    float* __restrict__ out){
  int t = blockIdx.x;
  __shared__ float u2s[2][RR];
  __shared__ int es[2];
  __shared__ float wss[2];
  if (threadIdx.x < 64){
    int s = threadIdx.x>>5, r = threadIdx.x&31;
    int pair = tok2pair[t*2+s];
    u2s[s][r] = u2[(size_t)pair*RR + r];
    if (r==0){ es[s]=list_e[pair]; wss[s]=rwn[t*2+s]; }
  }
  __syncthreads();
  int e0=es[0], e1=es[1];
  float w0=wss[0], w1=wss[1];
  for (int h=threadIdx.x; h<H; h+=256){
    const float4* b0 = (const float4*)(B2 + ((size_t)e0*H + h)*RR);
    const float4* b1 = (const float4*)(B2 + ((size_t)e1*H + h)*RR);
    float d0=0.f, d1=0.f;
    #pragma unroll
    for (int c=0;c<RR/4;++c){
      float4 v0=b0[c]; d0 += v0.x*u2s[0][c*4+0] + v0.y*u2s[0][c*4+1] + v0.z*u2s[0][c*4+2] + v0.w*u2s[0][c*4+3];
      float4 v1=b1[c]; d1 += v1.x*u2s[1][c*4+0] + v1.y*u2s[1][c*4+1] + v1.z*u2s[1][c*4+2] + v1.w*u2s[1][c*4+3];
    }
    out[(size_t)t*H + h] += w0*d0 + w1*d1;
  }
}

extern "C" void kernel_launch(void* const* d_in, const int* in_sizes, int n_in,
                              void* d_out, int out_size, void* d_ws, size_t ws_size,
                              hipStream_t stream){
  const float* x   = (const float*)d_in[0];
  const float* gw  = (const float*)d_in[1];
  const float* W1  = (const float*)d_in[2];
  const float* W2  = (const float*)d_in[3];
  const float* W3  = (const float*)d_in[4];
  const float* A1  = (const float*)d_in[5];
  const float* B1  = (const float*)d_in[6];
  const float* A2  = (const float*)d_in[7];
  const float* B2  = (const float*)d_in[8];
  const float* A3  = (const float*)d_in[9];
  const float* B3  = (const float*)d_in[10];
  float* outF = (float*)d_out;
  float* outL = outF + (size_t)NT*H;

  char* base = (char*)d_ws;
  size_t o = 0;
  auto mk = [&](size_t bytes){ void* p = base + o; o += (bytes + 255) & ~(size_t)255; return p; };
  int*   sel      = (int*)  mk((size_t)NT*2*4);
  float* rwn      = (float*)mk((size_t)NT*2*4);
  int*   cnts     = (int*)  mk(512);
  int*   cnt      = cnts;
  int*   cnt2     = cnts + 64;
  int*   off      = (int*)  mk(256);
  int*   meta     = (int*)  mk((size_t)(1+3*MAXT)*4);
  int*   list_tok = (int*)  mk((size_t)NPAIRP*4);
  int*   list_e   = (int*)  mk((size_t)NPAIRP*4);
  int*   tok2pair = (int*)  mk((size_t)NT*2*4);
  ushort_t* xbf   = (ushort_t*)mk((size_t)NT*H*2);
  ushort_t* x1b   = (ushort_t*)mk((size_t)NT*F*2);
  ushort_t* x3b   = (ushort_t*)mk((size_t)NT*F*2);
  ushort_t* x2buf = (ushort_t*)mk((size_t)NPAIRP*F*2);
  ushort_t* x2c   = (ushort_t*)mk((size_t)NT*F*2);
  ushort_t* u1bf  = (ushort_t*)mk((size_t)NPAIRP*RR*2);
  ushort_t* u3bf  = (ushort_t*)mk((size_t)NPAIRP*RR*2);
  float* u2       = (float*)mk((size_t)NPAIRP*RR*4);
  (void)ws_size; (void)in_sizes; (void)n_in; (void)out_size;

  hipMemsetAsync(cnts, 0, 512, stream);
  cast_x<<<(NT*H/4)/256, 256, 0, stream>>>(x, xbf);
  router_kernel<<<NT/4, 256, 0, stream>>>(x, gw, outL, sel, rwn, cnt);
  prefix_kernel<<<1, 1, 0, stream>>>(cnt, off, meta);
  scatter_kernel<<<(NPAIRP+255)/256, 256, 0, stream>>>(sel, off, cnt2, list_tok, list_e, tok2pair);
  gemm_bt<128,true><<<dim3(NT/128, F/128), 256, 0, stream>>>(xbf, W1, x1b, NT, F, H);
  gemm_bt<128,true><<<dim3(NT/128, F/128), 256, 0, stream>>>(xbf, W3, x3b, NT, F, H);
  lora_a_mfma<<<MAXT, 256, 0, stream>>>(meta, list_tok, xbf, A1, A3, u1bf, u3bf);
  expert_x2<<<dim3(MAXT, F/128), 256, 0, stream>>>(meta, list_tok, B1, B3, u1bf, u3bf, x1b, x3b, x2buf);
  combine_x2<<<(NT*(F/8))/256, 256, 0, stream>>>(tok2pair, rwn, x2buf, x2c);
  u2_mfma<<<MAXT, 256, 0, stream>>>(meta, A2, x2buf, u2);
  gemm_bt<128,false><<<dim3(NT/128, H/128), 256, 0, stream>>>(x2c, W2, outF, NT, H, F);
  lora2_add<<<NT, 256, 0, stream>>>(tok2pair, list_e, rwn, B2, u2, outF);
}

// Round 3
// 1390.528 us; speedup vs baseline: 1.6250x; 1.2181x over previous
//
#include <hip/hip_runtime.h>

#define H 4096
#define F 14336
#define NE 8
#define RR 32
#define NT 1024
#define MAXT 136
#define NPAIR 2048
#define NPAIRP 2064   // padded (tile overrun on last expert)

typedef unsigned short ushort_t;
typedef __attribute__((ext_vector_type(4))) float f32x4;
typedef __attribute__((ext_vector_type(8))) short short8v;
typedef __attribute__((ext_vector_type(8))) unsigned short ushort8;
typedef __attribute__((ext_vector_type(4))) unsigned short ushort4v;

__device__ inline unsigned short f2bf(float f){
  unsigned int x = __float_as_uint(f);
  return (unsigned short)((x + 0x7fffu + ((x>>16)&1u)) >> 16);
}
__device__ inline float bf2f(unsigned short u){
  return __uint_as_float(((unsigned int)u)<<16);
}
__device__ inline short8v cvt8(const float* p){
  float4 v0 = *(const float4*)p, v1 = *(const float4*)(p+4);
  short8v b;
  b[0]=(short)f2bf(v0.x); b[1]=(short)f2bf(v0.y); b[2]=(short)f2bf(v0.z); b[3]=(short)f2bf(v0.w);
  b[4]=(short)f2bf(v1.x); b[5]=(short)f2bf(v1.y); b[6]=(short)f2bf(v1.z); b[7]=(short)f2bf(v1.w);
  return b;
}
__device__ inline short8v load8w(const float* p){ return cvt8(p); }
__device__ inline short8v load8w(const ushort_t* p){ return *(const short8v*)p; }

__device__ inline void gload16(const void* g, void* l){
  __builtin_amdgcn_global_load_lds(
      (const __attribute__((address_space(1))) void*)g,
      (__attribute__((address_space(3))) void*)l, 16, 0, 0);
}

// ---------------- fp32 -> bf16 streaming cast ----------------
__global__ __launch_bounds__(256) void cast_f2bf(const float* __restrict__ src,
    ushort_t* __restrict__ dst, long n8){
  long stride = (long)gridDim.x*256;
  for (long i = (long)blockIdx.x*256 + threadIdx.x; i < n8; i += stride){
    const float4* p = (const float4*)(src + i*8);
    float4 v0 = p[0], v1 = p[1];
    ushort8 o;
    o[0]=f2bf(v0.x); o[1]=f2bf(v0.y); o[2]=f2bf(v0.z); o[3]=f2bf(v0.w);
    o[4]=f2bf(v1.x); o[5]=f2bf(v1.y); o[6]=f2bf(v1.z); o[7]=f2bf(v1.w);
    *(ushort8*)(dst + i*8) = o;
  }
}

// ---------------- router ----------------
__global__ __launch_bounds__(256) void router_kernel(const float* __restrict__ x,
    const float* __restrict__ gw, float* __restrict__ logits,
    int* __restrict__ sel, float* __restrict__ rwn, int* __restrict__ cnt){
  int t = blockIdx.x*4 + (threadIdx.x>>6);
  int lane = threadIdx.x & 63;
  const float4* xr = (const float4*)(x + (size_t)t*H);
  float s[NE];
  #pragma unroll
  for (int e=0;e<NE;++e) s[e]=0.f;
  for (int c=lane; c<H/4; c+=64){
    float4 xv = xr[c];
    #pragma unroll
    for (int e=0;e<NE;++e){
      float4 g = ((const float4*)(gw + (size_t)e*H))[c];
      s[e] += xv.x*g.x + xv.y*g.y + xv.z*g.z + xv.w*g.w;
    }
  }
  #pragma unroll
  for (int e=0;e<NE;++e){
    for (int off=32; off; off>>=1) s[e] += __shfl_down(s[e], off);
  }
  if (lane==0){
    float mx = s[0];
    #pragma unroll
    for (int e=1;e<NE;++e) mx = fmaxf(mx, s[e]);
    float p[NE]; float den=0.f;
    #pragma unroll
    for (int e=0;e<NE;++e){ p[e]=__expf(s[e]-mx); den+=p[e]; }
    int i0=0;
    #pragma unroll
    for (int e=1;e<NE;++e) if (p[e]>p[i0]) i0=e;
    int i1 = (i0==0)?1:0;
    #pragma unroll
    for (int e=0;e<NE;++e){ if (e!=i0 && p[e]>p[i1]) i1=e; }
    float p0=p[i0]/den, p1=p[i1]/den;
    float inv = 1.f/(p0+p1);
    #pragma unroll
    for (int e=0;e<NE;++e) logits[t*NE+e] = s[e];
    sel[t*2]=i0; sel[t*2+1]=i1;
    rwn[t*2]=p0*inv; rwn[t*2+1]=p1*inv;
    atomicAdd(&cnt[i0],1); atomicAdd(&cnt[i1],1);
  }
}

// ---------------- prefix + tile table ----------------
__global__ void prefix_kernel(const int* __restrict__ cnt, int* __restrict__ off, int* __restrict__ meta){
  if (threadIdx.x==0 && blockIdx.x==0){
    int o=0;
    for (int e=0;e<NE;++e){ off[e]=o; o+=cnt[e]; }
    off[NE]=o;
    int ntl=0;
    for (int e=0;e<NE;++e){
      int c=cnt[e], b=off[e];
      for (int ps=0; ps<c; ps+=16){
        meta[1+ntl] = e;
        meta[1+MAXT+ntl] = b+ps;
        meta[1+2*MAXT+ntl] = (c-ps<16)?(c-ps):16;
        ++ntl;
      }
    }
    meta[0]=ntl;
  }
}

// ---------------- scatter ----------------
__global__ void scatter_kernel(const int* __restrict__ sel, const int* __restrict__ off,
    int* __restrict__ cnt2, int* __restrict__ list_tok, int* __restrict__ list_e,
    int* __restrict__ tok2pair){
  int idx = blockIdx.x*256 + threadIdx.x;
  if (idx >= NT*2){
    if (idx < NPAIRP){ list_tok[idx]=0; list_e[idx]=0; }
    return;
  }
  int e = sel[idx];
  int pos = atomicAdd(&cnt2[e], 1);
  int pair = off[e] + pos;
  list_tok[pair] = idx>>1;
  list_e[pair] = e;
  tok2pair[idx] = pair;
}

// ---------------- cast hidden states to bf16 ----------------
__global__ __launch_bounds__(256) void cast_x(const float* __restrict__ x, ushort_t* __restrict__ xbf){
  size_t i = ((size_t)blockIdx.x*256 + threadIdx.x)*4;
  if (i >= (size_t)NT*H) return;
  float4 v = *(const float4*)(x+i);
  ushort4v o;
  o[0]=f2bf(v.x); o[1]=f2bf(v.y); o[2]=f2bf(v.z); o[3]=f2bf(v.w);
  *(ushort4v*)(xbf+i) = o;
}

// ---------------- bf16 x bf16^T MFMA GEMM, global_load_lds staged, XCD swizzle ----------------
template<bool OUTBF>
__global__ __launch_bounds__(256) void gemm_lds(const ushort_t* __restrict__ A,
    const ushort_t* __restrict__ Bw, void* __restrict__ Cout, int M, int N, int K){
  constexpr int BM=128, BN=128, BK=32;
  __shared__ ushort_t As[BM*BK];
  __shared__ ushort_t Bs[BN*BK];
  const int tid = threadIdx.x;
  const int w = tid>>6, l = tid&63;
  const int GM = M/BM, GN = N/BN;
  int id = blockIdx.x;
  int m, n;
  if ((GN & 7) == 0){
    int xcd = id & 7, t = id >> 3;
    m = t % GM;
    n = xcd*(GN>>3) + t/GM;
  } else { m = id % GM; n = id / GM; }
  const int bm = m*BM, bn = n*BN;
  const int lr = l&15, lk = l>>4;
  const int wm = (w>>1)*64, wn = (w&1)*64;
  f32x4 acc[4][4];
  #pragma unroll
  for (int i=0;i<4;++i)
    #pragma unroll
    for (int j=0;j<4;++j) acc[i][j] = (f32x4){0.f,0.f,0.f,0.f};
  const int rowA = tid>>2, k8 = (tid&3)*8;
  const ushort_t* gA0 = A  + (size_t)(bm+rowA)*K + k8;
  const ushort_t* gA1 = A  + (size_t)(bm+64+rowA)*K + k8;
  const ushort_t* gB0 = Bw + (size_t)(bn+rowA)*K + k8;
  const ushort_t* gB1 = Bw + (size_t)(bn+64+rowA)*K + k8;
  ushort_t* ldsA0 = As + w*512;
  ushort_t* ldsA1 = As + 2048 + w*512;
  ushort_t* ldsB0 = Bs + w*512;
  ushort_t* ldsB1 = Bs + 2048 + w*512;
  for (int k0=0; k0<K; k0+=BK){
    gload16(gA0 + k0, ldsA0);
    gload16(gA1 + k0, ldsA1);
    gload16(gB0 + k0, ldsB0);
    gload16(gB1 + k0, ldsB1);
    __syncthreads();
    short8v af[4], bfv[4];
    #pragma unroll
    for (int i=0;i<4;++i) af[i]  = *(const short8v*)&As[(wm+i*16+lr)*BK + lk*8];
    #pragma unroll
    for (int j=0;j<4;++j) bfv[j] = *(const short8v*)&Bs[(wn+j*16+lr)*BK + lk*8];
    #pragma unroll
    for (int i=0;i<4;++i)
      #pragma unroll
      for (int j=0;j<4;++j)
        acc[i][j] = __builtin_amdgcn_mfma_f32_16x16x32_bf16(af[i], bfv[j], acc[i][j], 0,0,0);
    __syncthreads();
  }
  #pragma unroll
  for (int i=0;i<4;++i)
    #pragma unroll
    for (int j=0;j<4;++j)
      #pragma unroll
      for (int r=0;r<4;++r){
        int row = bm + wm + i*16 + lk*4 + r;
        int col = bn + wn + j*16 + lr;
        if (OUTBF) ((ushort_t*)Cout)[(size_t)row*N + col] = f2bf(acc[i][j][r]);
        else       ((float*)Cout)[(size_t)row*N + col]    = acc[i][j][r];
      }
}

// ---------------- fallback fp32-B fused-cvt GEMM (round-2 path) ----------------
template<int BN, bool OUTBF>
__global__ __launch_bounds__(256) void gemm_bt(const ushort_t* __restrict__ A,
    const float* __restrict__ Bw, void* __restrict__ Cout, int M, int N, int K){
  constexpr int BM=128, BK=32, LD=40;
  __shared__ ushort_t As[BM*LD];
  __shared__ ushort_t Bs[BN*LD];
  const int tid = threadIdx.x;
  const int bm = blockIdx.x*BM, bn = blockIdx.y*BN;
  const int wv = tid>>6, lane = tid&63;
  const int wm = (wv>>1)*64, wn = (wv&1)*(BN/2);
  const int lr = lane&15, lk = lane>>4;
  constexpr int NJ = BN/32;
  f32x4 acc[4][NJ];
  #pragma unroll
  for (int i=0;i<4;++i)
    #pragma unroll
    for (int j=0;j<NJ;++j) acc[i][j] = (f32x4){0.f,0.f,0.f,0.f};
  const int arow = tid>>1, ak=(tid&1)*16;
  constexpr int BPT = BN*BK/256;
  const int brow = (BN==128)?(tid>>1):(tid>>2);
  const int bk   = (BN==128)?((tid&1)*16):((tid&3)*8);
  const ushort_t* gA = A + (size_t)(bm+arow)*K + ak;
  const float*    gB = Bw + (size_t)(bn+brow)*K + bk;
  for (int k0=0;k0<K;k0+=BK){
    ushort8 a0 = *(const ushort8*)(gA + k0);
    ushort8 a1 = *(const ushort8*)(gA + k0 + 8);
    float vals[BPT];
    #pragma unroll
    for (int i=0;i<BPT;i+=4){
      float4 v = *(const float4*)(gB + k0 + i);
      vals[i]=v.x; vals[i+1]=v.y; vals[i+2]=v.z; vals[i+3]=v.w;
    }
    *(ushort8*)&As[arow*LD+ak]   = a0;
    *(ushort8*)&As[arow*LD+ak+8] = a1;
    #pragma unroll
    for (int i=0;i<BPT;i+=8){
      ushort8 u;
      #pragma unroll
      for (int q=0;q<8;++q) u[q]=f2bf(vals[i+q]);
      *(ushort8*)&Bs[brow*LD+bk+i] = u;
    }
    __syncthreads();
    short8v af[4], bfv[NJ];
    #pragma unroll
    for (int i=0;i<4;++i) af[i] = *(const short8v*)&As[(wm+i*16+lr)*LD + lk*8];
    #pragma unroll
    for (int j=0;j<NJ;++j) bfv[j] = *(const short8v*)&Bs[(wn+j*16+lr)*LD + lk*8];
    #pragma unroll
    for (int i=0;i<4;++i)
      #pragma unroll
      for (int j=0;j<NJ;++j)
        acc[i][j] = __builtin_amdgcn_mfma_f32_16x16x32_bf16(af[i], bfv[j], acc[i][j], 0,0,0);
    __syncthreads();
  }
  #pragma unroll
  for (int i=0;i<4;++i)
    #pragma unroll
    for (int j=0;j<NJ;++j)
      #pragma unroll
      for (int r=0;r<4;++r){
        int row = bm + wm + i*16 + lk*4 + r;
        int col = bn + wn + j*16 + lr;
        if (OUTBF) ((ushort_t*)Cout)[(size_t)row*N + col] = f2bf(acc[i][j][r]);
        else       ((float*)Cout)[(size_t)row*N + col]    = acc[i][j][r];
      }
}

// ---------------- LoRA A projections via MFMA ----------------
__global__ __launch_bounds__(256) void lora_a_mfma(const int* __restrict__ meta,
    const int* __restrict__ list_tok, const ushort_t* __restrict__ xbf,
    const float* __restrict__ A1, const float* __restrict__ A3,
    ushort_t* __restrict__ u1bf, ushort_t* __restrict__ u3bf){
  int ti = blockIdx.x;
  if (ti >= meta[0]) return;
  int e  = meta[1+ti];
  int p0 = meta[1+MAXT+ti];
  int np = meta[1+2*MAXT+ti];
  int wv = threadIdx.x>>6, lane = threadIdx.x&63;
  int lr = lane&15, lk = lane>>4;
  int t = list_tok[p0+lr];
  const ushort_t* xrow = xbf + (size_t)t*H;
  const int kbase = wv*(H/4);
  f32x4 acc1[2], acc3[2];
  #pragma unroll
  for (int j=0;j<2;++j){ acc1[j]=(f32x4){0,0,0,0}; acc3[j]=(f32x4){0,0,0,0}; }
  for (int ks=0; ks<H/4; ks+=32){
    int k = kbase + ks + lk*8;
    short8v a = *(const short8v*)(xrow + k);
    #pragma unroll
    for (int j=0;j<2;++j){
      const float* b1 = A1 + ((size_t)e*RR + j*16 + lr)*H + k;
      const float* b3 = A3 + ((size_t)e*RR + j*16 + lr)*H + k;
      acc1[j] = __builtin_amdgcn_mfma_f32_16x16x32_bf16(a, cvt8(b1), acc1[j], 0,0,0);
      acc3[j] = __builtin_amdgcn_mfma_f32_16x16x32_bf16(a, cvt8(b3), acc3[j], 0,0,0);
    }
  }
  __shared__ float red[4][2][2][4][64];
  #pragma unroll
  for (int j=0;j<2;++j)
    #pragma unroll
    for (int r=0;r<4;++r){
      red[wv][0][j][r][lane] = acc1[j][r];
      red[wv][1][j][r][lane] = acc3[j][r];
    }
  __syncthreads();
  if (wv==0){
    #pragma unroll
    for (int j=0;j<2;++j)
      #pragma unroll
      for (int r=0;r<4;++r){
        int p = lk*4 + r;
        if (p < np){
          float s1 = red[0][0][j][r][lane]+red[1][0][j][r][lane]+red[2][0][j][r][lane]+red[3][0][j][r][lane];
          float s3 = red[0][1][j][r][lane]+red[1][1][j][r][lane]+red[2][1][j][r][lane]+red[3][1][j][r][lane];
          u1bf[(size_t)(p0+p)*RR + j*16 + lr] = f2bf(s1);
          u3bf[(size_t)(p0+p)*RR + j*16 + lr] = f2bf(s3);
        }
      }
  }
}

// ---------------- per-expert fused: d1/d3 via MFMA, silu, x2 ----------------
template<typename WT>
__global__ __launch_bounds__(256) void expert_x2(const int* __restrict__ meta, const int* __restrict__ list_tok,
    const WT* __restrict__ B1g, const WT* __restrict__ B3g,
    const ushort_t* __restrict__ u1bf, const ushort_t* __restrict__ u3bf,
    const ushort_t* __restrict__ x1b, const ushort_t* __restrict__ x3b,
    ushort_t* __restrict__ x2buf){
  int ti = blockIdx.x;
  if (ti >= meta[0]) return;
  int e  = meta[1+ti];
  int p0 = meta[1+MAXT+ti];
  int np = meta[1+2*MAXT+ti];
  int fc = blockIdx.y*128 + (threadIdx.x>>6)*32;
  int lane = threadIdx.x&63;
  int lr = lane&15, lk = lane>>4;
  short8v au1 = *(const short8v*)(u1bf + (size_t)(p0+lr)*RR + lk*8);
  short8v au3 = *(const short8v*)(u3bf + (size_t)(p0+lr)*RR + lk*8);
  f32x4 z = (f32x4){0.f,0.f,0.f,0.f};
  f32x4 acc1[2], acc3[2];
  #pragma unroll
  for (int j=0;j<2;++j){
    acc1[j]=z; acc3[j]=z;
    int f = fc + j*16 + lr;
    const WT* b1r = B1g + ((size_t)e*F + f)*RR + lk*8;
    const WT* b3r = B3g + ((size_t)e*F + f)*RR + lk*8;
    acc1[j] = __builtin_amdgcn_mfma_f32_16x16x32_bf16(au1, load8w(b1r), acc1[j], 0,0,0);
    acc3[j] = __builtin_amdgcn_mfma_f32_16x16x32_bf16(au3, load8w(b3r), acc3[j], 0,0,0);
  }
  #pragma unroll
  for (int r=0;r<4;++r){
    int p = lk*4 + r;
    if (p < np){
      int t = list_tok[p0+p];
      #pragma unroll
      for (int j=0;j<2;++j){
        int f = fc + j*16 + lr;
        size_t ix = (size_t)t*F + f;
        float x1  = bf2f(x1b[ix]) + acc1[j][r];
        float x3v = bf2f(x3b[ix]) + acc3[j][r];
        float sl = x1/(1.f + __expf(-x1));
        x2buf[(size_t)(p0+p)*F + f] = f2bf(sl*x3v);
      }
    }
  }
}

// ---------------- combine ----------------
__global__ __launch_bounds__(256) void combine_x2(const int* __restrict__ tok2pair, const float* __restrict__ rwn,
    const ushort_t* __restrict__ x2buf, ushort_t* __restrict__ x2c){
  size_t i = (size_t)blockIdx.x*256 + threadIdx.x;
  size_t total = (size_t)NT*(F/8);
  if (i>=total) return;
  int t = (int)(i/(F/8));
  int c = (int)(i%(F/8))*8;
  int pa = tok2pair[t*2], pb = tok2pair[t*2+1];
  float wa = rwn[t*2], wb = rwn[t*2+1];
  ushort8 va = *(const ushort8*)(x2buf + (size_t)pa*F + c);
  ushort8 vb = *(const ushort8*)(x2buf + (size_t)pb*F + c);
  ushort8 o;
  #pragma unroll
  for (int q=0;q<8;++q) o[q] = f2bf(wa*bf2f(va[q]) + wb*bf2f(vb[q]));
  *(ushort8*)(x2c + (size_t)t*F + c) = o;
}

// ---------------- u2 = A2[e] @ x2 via MFMA ----------------
__global__ __launch_bounds__(256) void u2_mfma(const int* __restrict__ meta,
    const float* __restrict__ A2, const ushort_t* __restrict__ x2buf, float* __restrict__ u2){
  int ti = blockIdx.x;
  if (ti >= meta[0]) return;
  int e  = meta[1+ti];
  int p0 = meta[1+MAXT+ti];
  int np = meta[1+2*MAXT+ti];
  int wv = threadIdx.x>>6, lane = threadIdx.x&63;
  int lr = lane&15, lk = lane>>4;
  const ushort_t* xrow = x2buf + (size_t)(p0+lr)*F;
  const int kbase = wv*(F/4);
  f32x4 acc[2];
  acc[0]=(f32x4){0,0,0,0}; acc[1]=(f32x4){0,0,0,0};
  for (int ks=0; ks<F/4; ks+=32){
    int k = kbase + ks + lk*8;
    short8v a = *(const short8v*)(xrow + k);
    #pragma unroll
    for (int j=0;j<2;++j){
      const float* br = A2 + ((size_t)e*RR + j*16 + lr)*F + k;
      acc[j] = __builtin_amdgcn_mfma_f32_16x16x32_bf16(a, cvt8(br), acc[j], 0,0,0);
    }
  }
  __shared__ float red[4][2][4][64];
  #pragma unroll
  for (int j=0;j<2;++j)
    #pragma unroll
    for (int r=0;r<4;++r) red[wv][j][r][lane] = acc[j][r];
  __syncthreads();
  if (wv==0){
    #pragma unroll
    for (int j=0;j<2;++j)
      #pragma unroll
      for (int r=0;r<4;++r){
        int p = lk*4 + r;
        if (p < np){
          float s = red[0][j][r][lane]+red[1][j][r][lane]+red[2][j][r][lane]+red[3][j][r][lane];
          u2[(size_t)(p0+p)*RR + j*16 + lr] = s;
        }
      }
  }
}

// ---------------- lora2 add ----------------
__global__ __launch_bounds__(256) void lora2_add(const int* __restrict__ tok2pair, const int* __restrict__ list_e,
    const float* __restrict__ rwn, const float* __restrict__ B2, const float* __restrict__ u2,
    float* __restrict__ out){
  int t = blockIdx.x;
  __shared__ float u2s[2][RR];
  __shared__ int es[2];
  __shared__ float wss[2];
  if (threadIdx.x < 64){
    int s = threadIdx.x>>5, r = threadIdx.x&31;
    int pair = tok2pair[t*2+s];
    u2s[s][r] = u2[(size_t)pair*RR + r];
    if (r==0){ es[s]=list_e[pair]; wss[s]=rwn[t*2+s]; }
  }
  __syncthreads();
  int e0=es[0], e1=es[1];
  float w0=wss[0], w1=wss[1];
  for (int h=threadIdx.x; h<H; h+=256){
    const float4* b0 = (const float4*)(B2 + ((size_t)e0*H + h)*RR);
    const float4* b1 = (const float4*)(B2 + ((size_t)e1*H + h)*RR);
    float d0=0.f, d1=0.f;
    #pragma unroll
    for (int c=0;c<RR/4;++c){
      float4 v0=b0[c]; d0 += v0.x*u2s[0][c*4+0] + v0.y*u2s[0][c*4+1] + v0.z*u2s[0][c*4+2] + v0.w*u2s[0][c*4+3];
      float4 v1=b1[c]; d1 += v1.x*u2s[1][c*4+0] + v1.y*u2s[1][c*4+1] + v1.z*u2s[1][c*4+2] + v1.w*u2s[1][c*4+3];
    }
    out[(size_t)t*H + h] += w0*d0 + w1*d1;
  }
}

extern "C" void kernel_launch(void* const* d_in, const int* in_sizes, int n_in,
                              void* d_out, int out_size, void* d_ws, size_t ws_size,
                              hipStream_t stream){
  const float* x   = (const float*)d_in[0];
  const float* gw  = (const float*)d_in[1];
  const float* W1  = (const float*)d_in[2];
  const float* W2  = (const float*)d_in[3];
  const float* W3  = (const float*)d_in[4];
  const float* A1  = (const float*)d_in[5];
  const float* B1  = (const float*)d_in[6];
  const float* A2  = (const float*)d_in[7];
  const float* B2  = (const float*)d_in[8];
  const float* A3  = (const float*)d_in[9];
  const float* B3  = (const float*)d_in[10];
  float* outF = (float*)d_out;
  float* outL = outF + (size_t)NT*H;

  char* base = (char*)d_ws;
  size_t o = 0;
  auto mk = [&](size_t bytes){ void* p = base + o; o += (bytes + 255) & ~(size_t)255; return p; };
  int*   sel      = (int*)  mk((size_t)NT*2*4);
  float* rwn      = (float*)mk((size_t)NT*2*4);
  int*   cnts     = (int*)  mk(512);
  int*   cnt      = cnts;
  int*   cnt2     = cnts + 64;
  int*   off      = (int*)  mk(256);
  int*   meta     = (int*)  mk((size_t)(1+3*MAXT)*4);
  int*   list_tok = (int*)  mk((size_t)NPAIRP*4);
  int*   list_e   = (int*)  mk((size_t)NPAIRP*4);
  int*   tok2pair = (int*)  mk((size_t)NT*2*4);
  ushort_t* xbf   = (ushort_t*)mk((size_t)NT*H*2);
  ushort_t* x1b   = (ushort_t*)mk((size_t)NT*F*2);
  ushort_t* x3b   = (ushort_t*)mk((size_t)NT*F*2);
  ushort_t* x2buf = (ushort_t*)mk((size_t)NPAIRP*F*2);
  ushort_t* x2c   = (ushort_t*)mk((size_t)NT*F*2);
  ushort_t* u1bf  = (ushort_t*)mk((size_t)NPAIRP*RR*2);
  ushort_t* u3bf  = (ushort_t*)mk((size_t)NPAIRP*RR*2);
  float* u2       = (float*)mk((size_t)NPAIRP*RR*4);
  // bf16 weight copies (used only if ws is large enough)
  ushort_t* w1bf = (ushort_t*)mk((size_t)F*H*2);
  ushort_t* w3bf = (ushort_t*)mk((size_t)F*H*2);
  ushort_t* w2bf = (ushort_t*)mk((size_t)H*F*2);
  ushort_t* b1bf = (ushort_t*)mk((size_t)NE*F*RR*2);
  ushort_t* b3bf = (ushort_t*)mk((size_t)NE*F*RR*2);
  bool useBF = (o <= ws_size);
  (void)in_sizes; (void)n_in; (void)out_size;

  hipMemsetAsync(cnts, 0, 512, stream);
  cast_x<<<(NT*H/4)/256, 256, 0, stream>>>(x, xbf);
  router_kernel<<<NT/4, 256, 0, stream>>>(x, gw, outL, sel, rwn, cnt);
  prefix_kernel<<<1, 1, 0, stream>>>(cnt, off, meta);
  scatter_kernel<<<(NPAIRP+255)/256, 256, 0, stream>>>(sel, off, cnt2, list_tok, list_e, tok2pair);

  if (useBF){
    cast_f2bf<<<2048, 256, 0, stream>>>(W1, w1bf, (long)F*H/8);
    cast_f2bf<<<2048, 256, 0, stream>>>(W3, w3bf, (long)F*H/8);
    cast_f2bf<<<2048, 256, 0, stream>>>(W2, w2bf, (long)H*F/8);
    cast_f2bf<<<512, 256, 0, stream>>>(B1, b1bf, (long)NE*F*RR/8);
    cast_f2bf<<<512, 256, 0, stream>>>(B3, b3bf, (long)NE*F*RR/8);
    gemm_lds<true><<<(NT/128)*(F/128), 256, 0, stream>>>(xbf, w1bf, x1b, NT, F, H);
    gemm_lds<true><<<(NT/128)*(F/128), 256, 0, stream>>>(xbf, w3bf, x3b, NT, F, H);
  } else {
    gemm_bt<128,true><<<dim3(NT/128, F/128), 256, 0, stream>>>(xbf, W1, x1b, NT, F, H);
    gemm_bt<128,true><<<dim3(NT/128, F/128), 256, 0, stream>>>(xbf, W3, x3b, NT, F, H);
  }
  lora_a_mfma<<<MAXT, 256, 0, stream>>>(meta, list_tok, xbf, A1, A3, u1bf, u3bf);
  if (useBF)
    expert_x2<ushort_t><<<dim3(MAXT, F/128), 256, 0, stream>>>(meta, list_tok, b1bf, b3bf, u1bf, u3bf, x1b, x3b, x2buf);
  else
    expert_x2<float><<<dim3(MAXT, F/128), 256, 0, stream>>>(meta, list_tok, B1, B3, u1bf, u3bf, x1b, x3b, x2buf);
  combine_x2<<<(NT*(F/8))/256, 256, 0, stream>>>(tok2pair, rwn, x2buf, x2c);
  u2_mfma<<<MAXT, 256, 0, stream>>>(meta, A2, x2buf, u2);
  if (useBF)
    gemm_lds<false><<<(NT/128)*(H/128), 256, 0, stream>>>(x2c, w2bf, outF, NT, H, F);
  else
    gemm_bt<128,false><<<dim3(NT/128, H/128), 256, 0, stream>>>(x2c, W2, outF, NT, H, F);
  lora2_add<<<NT, 256, 0, stream>>>(tok2pair, list_e, rwn, B2, u2, outF);
}

// Round 4
// 1342.110 us; speedup vs baseline: 1.6837x; 1.0361x over previous
//
#include <hip/hip_runtime.h>

#define H 4096
#define F 14336
#define NE 8
#define RR 32
#define NT 1024
#define MAXT 136
#define NPAIR 2048
#define NPAIRP 2064   // padded (tile overrun on last expert)

typedef unsigned short ushort_t;
typedef __attribute__((ext_vector_type(4))) float f32x4;
typedef __attribute__((ext_vector_type(8))) short short8v;
typedef __attribute__((ext_vector_type(8))) unsigned short ushort8;
typedef __attribute__((ext_vector_type(4))) unsigned short ushort4v;

__device__ inline unsigned short f2bf(float f){
  unsigned int x = __float_as_uint(f);
  return (unsigned short)((x + 0x7fffu + ((x>>16)&1u)) >> 16);
}
__device__ inline float bf2f(unsigned short u){
  return __uint_as_float(((unsigned int)u)<<16);
}
__device__ inline short8v cvt8(const float* p){
  float4 v0 = *(const float4*)p, v1 = *(const float4*)(p+4);
  short8v b;
  b[0]=(short)f2bf(v0.x); b[1]=(short)f2bf(v0.y); b[2]=(short)f2bf(v0.z); b[3]=(short)f2bf(v0.w);
  b[4]=(short)f2bf(v1.x); b[5]=(short)f2bf(v1.y); b[6]=(short)f2bf(v1.z); b[7]=(short)f2bf(v1.w);
  return b;
}
__device__ inline short8v load8w(const float* p){ return cvt8(p); }
__device__ inline short8v load8w(const ushort_t* p){ return *(const short8v*)p; }

__device__ inline void gload16(const void* g, void* l){
  __builtin_amdgcn_global_load_lds(
      (const __attribute__((address_space(1))) void*)g,
      (__attribute__((address_space(3))) void*)l, 16, 0, 0);
}

// ---------------- fp32 -> bf16 streaming cast ----------------
__global__ __launch_bounds__(256) void cast_f2bf(const float* __restrict__ src,
    ushort_t* __restrict__ dst, long n8){
  long stride = (long)gridDim.x*256;
  for (long i = (long)blockIdx.x*256 + threadIdx.x; i < n8; i += stride){
    const float4* p = (const float4*)(src + i*8);
    float4 v0 = p[0], v1 = p[1];
    ushort8 o;
    o[0]=f2bf(v0.x); o[1]=f2bf(v0.y); o[2]=f2bf(v0.z); o[3]=f2bf(v0.w);
    o[4]=f2bf(v1.x); o[5]=f2bf(v1.y); o[6]=f2bf(v1.z); o[7]=f2bf(v1.w);
    *(ushort8*)(dst + i*8) = o;
  }
}

// ---------------- router ----------------
__global__ __launch_bounds__(256) void router_kernel(const float* __restrict__ x,
    const float* __restrict__ gw, float* __restrict__ logits,
    int* __restrict__ sel, float* __restrict__ rwn, int* __restrict__ cnt){
  int t = blockIdx.x*4 + (threadIdx.x>>6);
  int lane = threadIdx.x & 63;
  const float4* xr = (const float4*)(x + (size_t)t*H);
  float s[NE];
  #pragma unroll
  for (int e=0;e<NE;++e) s[e]=0.f;
  for (int c=lane; c<H/4; c+=64){
    float4 xv = xr[c];
    #pragma unroll
    for (int e=0;e<NE;++e){
      float4 g = ((const float4*)(gw + (size_t)e*H))[c];
      s[e] += xv.x*g.x + xv.y*g.y + xv.z*g.z + xv.w*g.w;
    }
  }
  #pragma unroll
  for (int e=0;e<NE;++e){
    for (int off=32; off; off>>=1) s[e] += __shfl_down(s[e], off);
  }
  if (lane==0){
    float mx = s[0];
    #pragma unroll
    for (int e=1;e<NE;++e) mx = fmaxf(mx, s[e]);
    float p[NE]; float den=0.f;
    #pragma unroll
    for (int e=0;e<NE;++e){ p[e]=__expf(s[e]-mx); den+=p[e]; }
    int i0=0;
    #pragma unroll
    for (int e=1;e<NE;++e) if (p[e]>p[i0]) i0=e;
    int i1 = (i0==0)?1:0;
    #pragma unroll
    for (int e=0;e<NE;++e){ if (e!=i0 && p[e]>p[i1]) i1=e; }
    float p0=p[i0]/den, p1=p[i1]/den;
    float inv = 1.f/(p0+p1);
    #pragma unroll
    for (int e=0;e<NE;++e) logits[t*NE+e] = s[e];
    sel[t*2]=i0; sel[t*2+1]=i1;
    rwn[t*2]=p0*inv; rwn[t*2+1]=p1*inv;
    atomicAdd(&cnt[i0],1); atomicAdd(&cnt[i1],1);
  }
}

// ---------------- prefix + tile table ----------------
__global__ void prefix_kernel(const int* __restrict__ cnt, int* __restrict__ off, int* __restrict__ meta){
  if (threadIdx.x==0 && blockIdx.x==0){
    int o=0;
    for (int e=0;e<NE;++e){ off[e]=o; o+=cnt[e]; }
    off[NE]=o;
    int ntl=0;
    for (int e=0;e<NE;++e){
      int c=cnt[e], b=off[e];
      for (int ps=0; ps<c; ps+=16){
        meta[1+ntl] = e;
        meta[1+MAXT+ntl] = b+ps;
        meta[1+2*MAXT+ntl] = (c-ps<16)?(c-ps):16;
        ++ntl;
      }
    }
    meta[0]=ntl;
  }
}

// ---------------- scatter ----------------
__global__ void scatter_kernel(const int* __restrict__ sel, const int* __restrict__ off,
    int* __restrict__ cnt2, int* __restrict__ list_tok, int* __restrict__ list_e,
    int* __restrict__ tok2pair){
  int idx = blockIdx.x*256 + threadIdx.x;
  if (idx >= NT*2){
    if (idx < NPAIRP){ list_tok[idx]=0; list_e[idx]=0; }
    return;
  }
  int e = sel[idx];
  int pos = atomicAdd(&cnt2[e], 1);
  int pair = off[e] + pos;
  list_tok[pair] = idx>>1;
  list_e[pair] = e;
  tok2pair[idx] = pair;
}

// ---------------- cast hidden states to bf16 ----------------
__global__ __launch_bounds__(256) void cast_x(const float* __restrict__ x, ushort_t* __restrict__ xbf){
  size_t i = ((size_t)blockIdx.x*256 + threadIdx.x)*4;
  if (i >= (size_t)NT*H) return;
  float4 v = *(const float4*)(x+i);
  ushort4v o;
  o[0]=f2bf(v.x); o[1]=f2bf(v.y); o[2]=f2bf(v.z); o[3]=f2bf(v.w);
  *(ushort4v*)(xbf+i) = o;
}

// ---------------- bf16 MFMA GEMM, 2-phase double-buffered global_load_lds, XCD swizzle ----------------
template<bool OUTBF>
__global__ __launch_bounds__(256) void gemm_2ph(const ushort_t* __restrict__ A,
    const ushort_t* __restrict__ Bw, void* __restrict__ Cout, int M, int N, int K){
  constexpr int BM=128, BN=128, BK=32;
  __shared__ ushort_t As[2][BM*BK];
  __shared__ ushort_t Bs[2][BN*BK];
  const int tid = threadIdx.x;
  const int w = tid>>6, l = tid&63;
  const int GM = M/BM, GN = N/BN;
  int id = blockIdx.x;
  int m, n;
  if ((GN & 7) == 0){
    int xcd = id & 7, t = id >> 3;
    m = t % GM;
    n = xcd*(GN>>3) + t/GM;
  } else { m = id % GM; n = id / GM; }
  const int bm = m*BM, bn = n*BN;
  const int lr = l&15, lk = l>>4;
  const int wm = (w>>1)*64, wn = (w&1)*64;
  f32x4 acc[4][4];
  #pragma unroll
  for (int i=0;i<4;++i)
    #pragma unroll
    for (int j=0;j<4;++j) acc[i][j] = (f32x4){0.f,0.f,0.f,0.f};
  const int rowA = tid>>2, k8 = (tid&3)*8;
  const ushort_t* gA0 = A  + (size_t)(bm+rowA)*K + k8;
  const ushort_t* gA1 = A  + (size_t)(bm+64+rowA)*K + k8;
  const ushort_t* gB0 = Bw + (size_t)(bn+rowA)*K + k8;
  const ushort_t* gB1 = Bw + (size_t)(bn+64+rowA)*K + k8;

  auto STAGE = [&](int buf, int k0){
    gload16(gA0 + k0, &As[buf][w*512]);
    gload16(gA1 + k0, &As[buf][2048 + w*512]);
    gload16(gB0 + k0, &Bs[buf][w*512]);
    gload16(gB1 + k0, &Bs[buf][2048 + w*512]);
  };

  STAGE(0, 0);
  __syncthreads();           // drains vmcnt(0): buf0 ready
  int cur = 0;
  for (int k0=0; k0<K; k0+=BK){
    if (k0 + BK < K) STAGE(cur^1, k0 + BK);   // prefetch next tile (in flight during MFMA)
    short8v af[4], bfv[4];
    #pragma unroll
    for (int i=0;i<4;++i) af[i]  = *(const short8v*)&As[cur][(wm+i*16+lr)*BK + lk*8];
    #pragma unroll
    for (int j=0;j<4;++j) bfv[j] = *(const short8v*)&Bs[cur][(wn+j*16+lr)*BK + lk*8];
    #pragma unroll
    for (int i=0;i<4;++i)
      #pragma unroll
      for (int j=0;j<4;++j)
        acc[i][j] = __builtin_amdgcn_mfma_f32_16x16x32_bf16(af[i], bfv[j], acc[i][j], 0,0,0);
    __syncthreads();         // vmcnt(0)+lgkmcnt(0)+barrier: prefetch landed, reads done
    cur ^= 1;
  }
  #pragma unroll
  for (int i=0;i<4;++i)
    #pragma unroll
    for (int j=0;j<4;++j)
      #pragma unroll
      for (int r=0;r<4;++r){
        int row = bm + wm + i*16 + lk*4 + r;
        int col = bn + wn + j*16 + lr;
        if (OUTBF) ((ushort_t*)Cout)[(size_t)row*N + col] = f2bf(acc[i][j][r]);
        else       ((float*)Cout)[(size_t)row*N + col]    = acc[i][j][r];
      }
}

// ---------------- fallback fp32-B fused-cvt GEMM ----------------
template<int BN, bool OUTBF>
__global__ __launch_bounds__(256) void gemm_bt(const ushort_t* __restrict__ A,
    const float* __restrict__ Bw, void* __restrict__ Cout, int M, int N, int K){
  constexpr int BM=128, BK=32, LD=40;
  __shared__ ushort_t As[BM*LD];
  __shared__ ushort_t Bs[BN*LD];
  const int tid = threadIdx.x;
  const int bm = blockIdx.x*BM, bn = blockIdx.y*BN;
  const int wv = tid>>6, lane = tid&63;
  const int wm = (wv>>1)*64, wn = (wv&1)*(BN/2);
  const int lr = lane&15, lk = lane>>4;
  constexpr int NJ = BN/32;
  f32x4 acc[4][NJ];
  #pragma unroll
  for (int i=0;i<4;++i)
    #pragma unroll
    for (int j=0;j<NJ;++j) acc[i][j] = (f32x4){0.f,0.f,0.f,0.f};
  const int arow = tid>>1, ak=(tid&1)*16;
  constexpr int BPT = BN*BK/256;
  const int brow = (BN==128)?(tid>>1):(tid>>2);
  const int bk   = (BN==128)?((tid&1)*16):((tid&3)*8);
  const ushort_t* gA = A + (size_t)(bm+arow)*K + ak;
  const float*    gB = Bw + (size_t)(bn+brow)*K + bk;
  for (int k0=0;k0<K;k0+=BK){
    ushort8 a0 = *(const ushort8*)(gA + k0);
    ushort8 a1 = *(const ushort8*)(gA + k0 + 8);
    float vals[BPT];
    #pragma unroll
    for (int i=0;i<BPT;i+=4){
      float4 v = *(const float4*)(gB + k0 + i);
      vals[i]=v.x; vals[i+1]=v.y; vals[i+2]=v.z; vals[i+3]=v.w;
    }
    *(ushort8*)&As[arow*LD+ak]   = a0;
    *(ushort8*)&As[arow*LD+ak+8] = a1;
    #pragma unroll
    for (int i=0;i<BPT;i+=8){
      ushort8 u;
      #pragma unroll
      for (int q=0;q<8;++q) u[q]=f2bf(vals[i+q]);
      *(ushort8*)&Bs[brow*LD+bk+i] = u;
    }
    __syncthreads();
    short8v af[4], bfv[NJ];
    #pragma unroll
    for (int i=0;i<4;++i) af[i] = *(const short8v*)&As[(wm+i*16+lr)*LD + lk*8];
    #pragma unroll
    for (int j=0;j<NJ;++j) bfv[j] = *(const short8v*)&Bs[(wn+j*16+lr)*LD + lk*8];
    #pragma unroll
    for (int i=0;i<4;++i)
      #pragma unroll
      for (int j=0;j<NJ;++j)
        acc[i][j] = __builtin_amdgcn_mfma_f32_16x16x32_bf16(af[i], bfv[j], acc[i][j], 0,0,0);
    __syncthreads();
  }
  #pragma unroll
  for (int i=0;i<4;++i)
    #pragma unroll
    for (int j=0;j<NJ;++j)
      #pragma unroll
      for (int r=0;r<4;++r){
        int row = bm + wm + i*16 + lk*4 + r;
        int col = bn + wn + j*16 + lr;
        if (OUTBF) ((ushort_t*)Cout)[(size_t)row*N + col] = f2bf(acc[i][j][r]);
        else       ((float*)Cout)[(size_t)row*N + col]    = acc[i][j][r];
      }
}

// ---------------- LoRA A projections via MFMA ----------------
__global__ __launch_bounds__(256) void lora_a_mfma(const int* __restrict__ meta,
    const int* __restrict__ list_tok, const ushort_t* __restrict__ xbf,
    const float* __restrict__ A1, const float* __restrict__ A3,
    ushort_t* __restrict__ u1bf, ushort_t* __restrict__ u3bf){
  int ti = blockIdx.x;
  if (ti >= meta[0]) return;
  int e  = meta[1+ti];
  int p0 = meta[1+MAXT+ti];
  int np = meta[1+2*MAXT+ti];
  int wv = threadIdx.x>>6, lane = threadIdx.x&63;
  int lr = lane&15, lk = lane>>4;
  int t = list_tok[p0+lr];
  const ushort_t* xrow = xbf + (size_t)t*H;
  const int kbase = wv*(H/4);
  f32x4 acc1[2], acc3[2];
  #pragma unroll
  for (int j=0;j<2;++j){ acc1[j]=(f32x4){0,0,0,0}; acc3[j]=(f32x4){0,0,0,0}; }
  for (int ks=0; ks<H/4; ks+=32){
    int k = kbase + ks + lk*8;
    short8v a = *(const short8v*)(xrow + k);
    #pragma unroll
    for (int j=0;j<2;++j){
      const float* b1 = A1 + ((size_t)e*RR + j*16 + lr)*H + k;
      const float* b3 = A3 + ((size_t)e*RR + j*16 + lr)*H + k;
      acc1[j] = __builtin_amdgcn_mfma_f32_16x16x32_bf16(a, cvt8(b1), acc1[j], 0,0,0);
      acc3[j] = __builtin_amdgcn_mfma_f32_16x16x32_bf16(a, cvt8(b3), acc3[j], 0,0,0);
    }
  }
  __shared__ float red[4][2][2][4][64];
  #pragma unroll
  for (int j=0;j<2;++j)
    #pragma unroll
    for (int r=0;r<4;++r){
      red[wv][0][j][r][lane] = acc1[j][r];
      red[wv][1][j][r][lane] = acc3[j][r];
    }
  __syncthreads();
  if (wv==0){
    #pragma unroll
    for (int j=0;j<2;++j)
      #pragma unroll
      for (int r=0;r<4;++r){
        int p = lk*4 + r;
        if (p < np){
          float s1 = red[0][0][j][r][lane]+red[1][0][j][r][lane]+red[2][0][j][r][lane]+red[3][0][j][r][lane];
          float s3 = red[0][1][j][r][lane]+red[1][1][j][r][lane]+red[2][1][j][r][lane]+red[3][1][j][r][lane];
          u1bf[(size_t)(p0+p)*RR + j*16 + lr] = f2bf(s1);
          u3bf[(size_t)(p0+p)*RR + j*16 + lr] = f2bf(s3);
        }
      }
  }
}

// ---------------- per-expert fused: d1/d3 via MFMA, silu, x2 ----------------
template<typename WT>
__global__ __launch_bounds__(256) void expert_x2(const int* __restrict__ meta, const int* __restrict__ list_tok,
    const WT* __restrict__ B1g, const WT* __restrict__ B3g,
    const ushort_t* __restrict__ u1bf, const ushort_t* __restrict__ u3bf,
    const ushort_t* __restrict__ x1b, const ushort_t* __restrict__ x3b,
    ushort_t* __restrict__ x2buf){
  int ti = blockIdx.x;
  if (ti >= meta[0]) return;
  int e  = meta[1+ti];
  int p0 = meta[1+MAXT+ti];
  int np = meta[1+2*MAXT+ti];
  int fc = blockIdx.y*128 + (threadIdx.x>>6)*32;
  int lane = threadIdx.x&63;
  int lr = lane&15, lk = lane>>4;
  short8v au1 = *(const short8v*)(u1bf + (size_t)(p0+lr)*RR + lk*8);
  short8v au3 = *(const short8v*)(u3bf + (size_t)(p0+lr)*RR + lk*8);
  f32x4 z = (f32x4){0.f,0.f,0.f,0.f};
  f32x4 acc1[2], acc3[2];
  #pragma unroll
  for (int j=0;j<2;++j){
    acc1[j]=z; acc3[j]=z;
    int f = fc + j*16 + lr;
    const WT* b1r = B1g + ((size_t)e*F + f)*RR + lk*8;
    const WT* b3r = B3g + ((size_t)e*F + f)*RR + lk*8;
    acc1[j] = __builtin_amdgcn_mfma_f32_16x16x32_bf16(au1, load8w(b1r), acc1[j], 0,0,0);
    acc3[j] = __builtin_amdgcn_mfma_f32_16x16x32_bf16(au3, load8w(b3r), acc3[j], 0,0,0);
  }
  #pragma unroll
  for (int r=0;r<4;++r){
    int p = lk*4 + r;
    if (p < np){
      int t = list_tok[p0+p];
      #pragma unroll
      for (int j=0;j<2;++j){
        int f = fc + j*16 + lr;
        size_t ix = (size_t)t*F + f;
        float x1  = bf2f(x1b[ix]) + acc1[j][r];
        float x3v = bf2f(x3b[ix]) + acc3[j][r];
        float sl = x1/(1.f + __expf(-x1));
        x2buf[(size_t)(p0+p)*F + f] = f2bf(sl*x3v);
      }
    }
  }
}

// ---------------- combine ----------------
__global__ __launch_bounds__(256) void combine_x2(const int* __restrict__ tok2pair, const float* __restrict__ rwn,
    const ushort_t* __restrict__ x2buf, ushort_t* __restrict__ x2c){
  size_t i = (size_t)blockIdx.x*256 + threadIdx.x;
  size_t total = (size_t)NT*(F/8);
  if (i>=total) return;
  int t = (int)(i/(F/8));
  int c = (int)(i%(F/8))*8;
  int pa = tok2pair[t*2], pb = tok2pair[t*2+1];
  float wa = rwn[t*2], wb = rwn[t*2+1];
  ushort8 va = *(const ushort8*)(x2buf + (size_t)pa*F + c);
  ushort8 vb = *(const ushort8*)(x2buf + (size_t)pb*F + c);
  ushort8 o;
  #pragma unroll
  for (int q=0;q<8;++q) o[q] = f2bf(wa*bf2f(va[q]) + wb*bf2f(vb[q]));
  *(ushort8*)(x2c + (size_t)t*F + c) = o;
}

// ---------------- u2 = A2[e] @ x2 via MFMA ----------------
__global__ __launch_bounds__(256) void u2_mfma(const int* __restrict__ meta,
    const float* __restrict__ A2, const ushort_t* __restrict__ x2buf, float* __restrict__ u2){
  int ti = blockIdx.x;
  if (ti >= meta[0]) return;
  int e  = meta[1+ti];
  int p0 = meta[1+MAXT+ti];
  int np = meta[1+2*MAXT+ti];
  int wv = threadIdx.x>>6, lane = threadIdx.x&63;
  int lr = lane&15, lk = lane>>4;
  const ushort_t* xrow = x2buf + (size_t)(p0+lr)*F;
  const int kbase = wv*(F/4);
  f32x4 acc[2];
  acc[0]=(f32x4){0,0,0,0}; acc[1]=(f32x4){0,0,0,0};
  for (int ks=0; ks<F/4; ks+=32){
    int k = kbase + ks + lk*8;
    short8v a = *(const short8v*)(xrow + k);
    #pragma unroll
    for (int j=0;j<2;++j){
      const float* br = A2 + ((size_t)e*RR + j*16 + lr)*F + k;
      acc[j] = __builtin_amdgcn_mfma_f32_16x16x32_bf16(a, cvt8(br), acc[j], 0,0,0);
    }
  }
  __shared__ float red[4][2][4][64];
  #pragma unroll
  for (int j=0;j<2;++j)
    #pragma unroll
    for (int r=0;r<4;++r) red[wv][j][r][lane] = acc[j][r];
  __syncthreads();
  if (wv==0){
    #pragma unroll
    for (int j=0;j<2;++j)
      #pragma unroll
      for (int r=0;r<4;++r){
        int p = lk*4 + r;
        if (p < np){
          float s = red[0][j][r][lane]+red[1][j][r][lane]+red[2][j][r][lane]+red[3][j][r][lane];
          u2[(size_t)(p0+p)*RR + j*16 + lr] = s;
        }
      }
  }
}

// ---------------- lora2 add ----------------
__global__ __launch_bounds__(256) void lora2_add(const int* __restrict__ tok2pair, const int* __restrict__ list_e,
    const float* __restrict__ rwn, const float* __restrict__ B2, const float* __restrict__ u2,
    float* __restrict__ out){
  int t = blockIdx.x;
  __shared__ float u2s[2][RR];
  __shared__ int es[2];
  __shared__ float wss[2];
  if (threadIdx.x < 64){
    int s = threadIdx.x>>5, r = threadIdx.x&31;
    int pair = tok2pair[t*2+s];
    u2s[s][r] = u2[(size_t)pair*RR + r];
    if (r==0){ es[s]=list_e[pair]; wss[s]=rwn[t*2+s]; }
  }
  __syncthreads();
  int e0=es[0], e1=es[1];
  float w0=wss[0], w1=wss[1];
  for (int h=threadIdx.x; h<H; h+=256){
    const float4* b0 = (const float4*)(B2 + ((size_t)e0*H + h)*RR);
    const float4* b1 = (const float4*)(B2 + ((size_t)e1*H + h)*RR);
    float d0=0.f, d1=0.f;
    #pragma unroll
    for (int c=0;c<RR/4;++c){
      float4 v0=b0[c]; d0 += v0.x*u2s[0][c*4+0] + v0.y*u2s[0][c*4+1] + v0.z*u2s[0][c*4+2] + v0.w*u2s[0][c*4+3];
      float4 v1=b1[c]; d1 += v1.x*u2s[1][c*4+0] + v1.y*u2s[1][c*4+1] + v1.z*u2s[1][c*4+2] + v1.w*u2s[1][c*4+3];
    }
    out[(size_t)t*H + h] += w0*d0 + w1*d1;
  }
}

extern "C" void kernel_launch(void* const* d_in, const int* in_sizes, int n_in,
                              void* d_out, int out_size, void* d_ws, size_t ws_size,
                              hipStream_t stream){
  const float* x   = (const float*)d_in[0];
  const float* gw  = (const float*)d_in[1];
  const float* W1  = (const float*)d_in[2];
  const float* W2  = (const float*)d_in[3];
  const float* W3  = (const float*)d_in[4];
  const float* A1  = (const float*)d_in[5];
  const float* B1  = (const float*)d_in[6];
  const float* A2  = (const float*)d_in[7];
  const float* B2  = (const float*)d_in[8];
  const float* A3  = (const float*)d_in[9];
  const float* B3  = (const float*)d_in[10];
  float* outF = (float*)d_out;
  float* outL = outF + (size_t)NT*H;

  char* base = (char*)d_ws;
  size_t o = 0;
  auto mk = [&](size_t bytes){ void* p = base + o; o += (bytes + 255) & ~(size_t)255; return p; };
  int*   sel      = (int*)  mk((size_t)NT*2*4);
  float* rwn      = (float*)mk((size_t)NT*2*4);
  int*   cnts     = (int*)  mk(512);
  int*   cnt      = cnts;
  int*   cnt2     = cnts + 64;
  int*   off      = (int*)  mk(256);
  int*   meta     = (int*)  mk((size_t)(1+3*MAXT)*4);
  int*   list_tok = (int*)  mk((size_t)NPAIRP*4);
  int*   list_e   = (int*)  mk((size_t)NPAIRP*4);
  int*   tok2pair = (int*)  mk((size_t)NT*2*4);
  ushort_t* xbf   = (ushort_t*)mk((size_t)NT*H*2);
  ushort_t* x1b   = (ushort_t*)mk((size_t)NT*F*2);
  ushort_t* x3b   = (ushort_t*)mk((size_t)NT*F*2);
  ushort_t* x2buf = (ushort_t*)mk((size_t)NPAIRP*F*2);
  ushort_t* x2c   = (ushort_t*)mk((size_t)NT*F*2);
  ushort_t* u1bf  = (ushort_t*)mk((size_t)NPAIRP*RR*2);
  ushort_t* u3bf  = (ushort_t*)mk((size_t)NPAIRP*RR*2);
  float* u2       = (float*)mk((size_t)NPAIRP*RR*4);
  // bf16 weight copies (used only if ws is large enough)
  ushort_t* w1bf = (ushort_t*)mk((size_t)F*H*2);
  ushort_t* w3bf = (ushort_t*)mk((size_t)F*H*2);
  ushort_t* w2bf = (ushort_t*)mk((size_t)H*F*2);
  ushort_t* b1bf = (ushort_t*)mk((size_t)NE*F*RR*2);
  ushort_t* b3bf = (ushort_t*)mk((size_t)NE*F*RR*2);
  bool useBF = (o <= ws_size);
  (void)in_sizes; (void)n_in; (void)out_size;

  hipMemsetAsync(cnts, 0, 512, stream);
  cast_x<<<(NT*H/4)/256, 256, 0, stream>>>(x, xbf);
  router_kernel<<<NT/4, 256, 0, stream>>>(x, gw, outL, sel, rwn, cnt);
  prefix_kernel<<<1, 1, 0, stream>>>(cnt, off, meta);
  scatter_kernel<<<(NPAIRP+255)/256, 256, 0, stream>>>(sel, off, cnt2, list_tok, list_e, tok2pair);

  if (useBF){
    cast_f2bf<<<2048, 256, 0, stream>>>(W1, w1bf, (long)F*H/8);
    cast_f2bf<<<2048, 256, 0, stream>>>(W3, w3bf, (long)F*H/8);
    cast_f2bf<<<2048, 256, 0, stream>>>(W2, w2bf, (long)H*F/8);
    cast_f2bf<<<512, 256, 0, stream>>>(B1, b1bf, (long)NE*F*RR/8);
    cast_f2bf<<<512, 256, 0, stream>>>(B3, b3bf, (long)NE*F*RR/8);
    gemm_2ph<true><<<(NT/128)*(F/128), 256, 0, stream>>>(xbf, w1bf, x1b, NT, F, H);
    gemm_2ph<true><<<(NT/128)*(F/128), 256, 0, stream>>>(xbf, w3bf, x3b, NT, F, H);
  } else {
    gemm_bt<128,true><<<dim3(NT/128, F/128), 256, 0, stream>>>(xbf, W1, x1b, NT, F, H);
    gemm_bt<128,true><<<dim3(NT/128, F/128), 256, 0, stream>>>(xbf, W3, x3b, NT, F, H);
  }
  lora_a_mfma<<<MAXT, 256, 0, stream>>>(meta, list_tok, xbf, A1, A3, u1bf, u3bf);
  if (useBF)
    expert_x2<ushort_t><<<dim3(MAXT, F/128), 256, 0, stream>>>(meta, list_tok, b1bf, b3bf, u1bf, u3bf, x1b, x3b, x2buf);
  else
    expert_x2<float><<<dim3(MAXT, F/128), 256, 0, stream>>>(meta, list_tok, B1, B3, u1bf, u3bf, x1b, x3b, x2buf);
  combine_x2<<<(NT*(F/8))/256, 256, 0, stream>>>(tok2pair, rwn, x2buf, x2c);
  u2_mfma<<<MAXT, 256, 0, stream>>>(meta, A2, x2buf, u2);
  if (useBF)
    gemm_2ph<false><<<(NT/128)*(H/128), 256, 0, stream>>>(x2c, w2bf, outF, NT, H, F);
  else
    gemm_bt<128,false><<<dim3(NT/128, H/128), 256, 0, stream>>>(x2c, W2, outF, NT, H, F);
  lora2_add<<<NT, 256, 0, stream>>>(tok2pair, list_e, rwn, B2, u2, outF);
}

// Round 5
// 1337.310 us; speedup vs baseline: 1.6897x; 1.0036x over previous
//
#include <hip/hip_runtime.h>

#define H 4096
#define F 14336
#define NE 8
#define RR 32
#define NT 1024
#define MAXT 136
#define NPAIR 2048
#define NPAIRP 2064   // padded (tile overrun on last expert)

typedef unsigned short ushort_t;
typedef __attribute__((ext_vector_type(4))) float f32x4;
typedef __attribute__((ext_vector_type(8))) short short8v;
typedef __attribute__((ext_vector_type(8))) unsigned short ushort8;
typedef __attribute__((ext_vector_type(4))) unsigned short ushort4v;

__device__ inline unsigned short f2bf(float f){
  unsigned int x = __float_as_uint(f);
  return (unsigned short)((x + 0x7fffu + ((x>>16)&1u)) >> 16);
}
__device__ inline float bf2f(unsigned short u){
  return __uint_as_float(((unsigned int)u)<<16);
}
__device__ inline short8v cvt8(const float* p){
  float4 v0 = *(const float4*)p, v1 = *(const float4*)(p+4);
  short8v b;
  b[0]=(short)f2bf(v0.x); b[1]=(short)f2bf(v0.y); b[2]=(short)f2bf(v0.z); b[3]=(short)f2bf(v0.w);
  b[4]=(short)f2bf(v1.x); b[5]=(short)f2bf(v1.y); b[6]=(short)f2bf(v1.z); b[7]=(short)f2bf(v1.w);
  return b;
}
__device__ inline short8v load8w(const float* p){ return cvt8(p); }
__device__ inline short8v load8w(const ushort_t* p){ return *(const short8v*)p; }

__device__ inline void gload16(const void* g, void* l){
  __builtin_amdgcn_global_load_lds(
      (const __attribute__((address_space(1))) void*)g,
      (__attribute__((address_space(3))) void*)l, 16, 0, 0);
}

// ---------------- fp32 -> bf16 streaming cast ----------------
__global__ __launch_bounds__(256) void cast_f2bf(const float* __restrict__ src,
    ushort_t* __restrict__ dst, long n8){
  long stride = (long)gridDim.x*256;
  for (long i = (long)blockIdx.x*256 + threadIdx.x; i < n8; i += stride){
    const float4* p = (const float4*)(src + i*8);
    float4 v0 = p[0], v1 = p[1];
    ushort8 o;
    o[0]=f2bf(v0.x); o[1]=f2bf(v0.y); o[2]=f2bf(v0.z); o[3]=f2bf(v0.w);
    o[4]=f2bf(v1.x); o[5]=f2bf(v1.y); o[6]=f2bf(v1.z); o[7]=f2bf(v1.w);
    *(ushort8*)(dst + i*8) = o;
  }
}

// ---------------- router ----------------
__global__ __launch_bounds__(256) void router_kernel(const float* __restrict__ x,
    const float* __restrict__ gw, float* __restrict__ logits,
    int* __restrict__ sel, float* __restrict__ rwn, int* __restrict__ cnt){
  int t = blockIdx.x*4 + (threadIdx.x>>6);
  int lane = threadIdx.x & 63;
  const float4* xr = (const float4*)(x + (size_t)t*H);
  float s[NE];
  #pragma unroll
  for (int e=0;e<NE;++e) s[e]=0.f;
  for (int c=lane; c<H/4; c+=64){
    float4 xv = xr[c];
    #pragma unroll
    for (int e=0;e<NE;++e){
      float4 g = ((const float4*)(gw + (size_t)e*H))[c];
      s[e] += xv.x*g.x + xv.y*g.y + xv.z*g.z + xv.w*g.w;
    }
  }
  #pragma unroll
  for (int e=0;e<NE;++e){
    for (int off=32; off; off>>=1) s[e] += __shfl_down(s[e], off);
  }
  if (lane==0){
    float mx = s[0];
    #pragma unroll
    for (int e=1;e<NE;++e) mx = fmaxf(mx, s[e]);
    float p[NE]; float den=0.f;
    #pragma unroll
    for (int e=0;e<NE;++e){ p[e]=__expf(s[e]-mx); den+=p[e]; }
    int i0=0;
    #pragma unroll
    for (int e=1;e<NE;++e) if (p[e]>p[i0]) i0=e;
    int i1 = (i0==0)?1:0;
    #pragma unroll
    for (int e=0;e<NE;++e){ if (e!=i0 && p[e]>p[i1]) i1=e; }
    float p0=p[i0]/den, p1=p[i1]/den;
    float inv = 1.f/(p0+p1);
    #pragma unroll
    for (int e=0;e<NE;++e) logits[t*NE+e] = s[e];
    sel[t*2]=i0; sel[t*2+1]=i1;
    rwn[t*2]=p0*inv; rwn[t*2+1]=p1*inv;
    atomicAdd(&cnt[i0],1); atomicAdd(&cnt[i1],1);
  }
}

// ---------------- prefix + tile table ----------------
__global__ void prefix_kernel(const int* __restrict__ cnt, int* __restrict__ off, int* __restrict__ meta){
  if (threadIdx.x==0 && blockIdx.x==0){
    int o=0;
    for (int e=0;e<NE;++e){ off[e]=o; o+=cnt[e]; }
    off[NE]=o;
    int ntl=0;
    for (int e=0;e<NE;++e){
      int c=cnt[e], b=off[e];
      for (int ps=0; ps<c; ps+=16){
        meta[1+ntl] = e;
        meta[1+MAXT+ntl] = b+ps;
        meta[1+2*MAXT+ntl] = (c-ps<16)?(c-ps):16;
        ++ntl;
      }
    }
    meta[0]=ntl;
  }
}

// ---------------- scatter ----------------
__global__ void scatter_kernel(const int* __restrict__ sel, const int* __restrict__ off,
    int* __restrict__ cnt2, int* __restrict__ list_tok, int* __restrict__ list_e,
    int* __restrict__ tok2pair){
  int idx = blockIdx.x*256 + threadIdx.x;
  if (idx >= NT*2){
    if (idx < NPAIRP){ list_tok[idx]=0; list_e[idx]=0; }
    return;
  }
  int e = sel[idx];
  int pos = atomicAdd(&cnt2[e], 1);
  int pair = off[e] + pos;
  list_tok[pair] = idx>>1;
  list_e[pair] = e;
  tok2pair[idx] = pair;
}

// ---------------- cast hidden states to bf16 ----------------
__global__ __launch_bounds__(256) void cast_x(const float* __restrict__ x, ushort_t* __restrict__ xbf){
  size_t i = ((size_t)blockIdx.x*256 + threadIdx.x)*4;
  if (i >= (size_t)NT*H) return;
  float4 v = *(const float4*)(x+i);
  ushort4v o;
  o[0]=f2bf(v.x); o[1]=f2bf(v.y); o[2]=f2bf(v.z); o[3]=f2bf(v.w);
  *(ushort4v*)(xbf+i) = o;
}

// ---------------- bf16 MFMA GEMM: 4-slot LDS ring, depth-3 prefetch, counted vmcnt ----------------
// One raw s_barrier per K-step; s_waitcnt vmcnt(8) waits only the oldest stage (4 loads).
// Safety: each wave waits its OWN loads before the collective barrier (wait-then-barrier);
// STAGE(t+3) overwrites buf[(t-1)%4], whose readers all passed the top-of-t barrier.
template<bool OUTBF>
__global__ __launch_bounds__(256) void gemm_pipe(const ushort_t* __restrict__ A,
    const ushort_t* __restrict__ Bw, void* __restrict__ Cout, int M, int N, int K){
  constexpr int BM=128, BN=128, BK=32, NB=4;
  __shared__ ushort_t As[NB][BM*BK];   // 4 x 8 KB
  __shared__ ushort_t Bs[NB][BN*BK];   // 4 x 8 KB  -> 64 KB total
  const int tid = threadIdx.x;
  const int w = tid>>6, l = tid&63;
  const int GM = M/BM, GN = N/BN;
  int id = blockIdx.x;
  int m, n;
  if ((GN & 7) == 0){
    int xcd = id & 7, t = id >> 3;
    m = t % GM;
    n = xcd*(GN>>3) + t/GM;
  } else { m = id % GM; n = id / GM; }
  const int bm = m*BM, bn = n*BN;
  const int lr = l&15, lk = l>>4;
  const int wm = (w>>1)*64, wn = (w&1)*64;
  f32x4 acc[4][4];
  #pragma unroll
  for (int i=0;i<4;++i)
    #pragma unroll
    for (int j=0;j<4;++j) acc[i][j] = (f32x4){0.f,0.f,0.f,0.f};
  const int rowA = tid>>2, k8 = (tid&3)*8;
  const ushort_t* gA0 = A  + (size_t)(bm+rowA)*K + k8;
  const ushort_t* gA1 = A  + (size_t)(bm+64+rowA)*K + k8;
  const ushort_t* gB0 = Bw + (size_t)(bn+rowA)*K + k8;
  const ushort_t* gB1 = Bw + (size_t)(bn+64+rowA)*K + k8;

  auto STAGE = [&](int buf, int k0){
    gload16(gA0 + k0, &As[buf][w*512]);
    gload16(gA1 + k0, &As[buf][2048 + w*512]);
    gload16(gB0 + k0, &Bs[buf][w*512]);
    gload16(gB1 + k0, &Bs[buf][2048 + w*512]);
  };

  const int nsteps = K/BK;
  STAGE(0, 0);
  STAGE(1, BK);
  STAGE(2, 2*BK);      // 12 loads in flight (3 stages x 4)
  for (int t=0; t<nsteps; ++t){
    int rem = nsteps - t;
    if (rem > 2)       asm volatile("s_waitcnt vmcnt(8)" ::: "memory");
    else if (rem == 2) asm volatile("s_waitcnt vmcnt(4)" ::: "memory");
    else               asm volatile("s_waitcnt vmcnt(0)" ::: "memory");
    __builtin_amdgcn_sched_barrier(0);
    __builtin_amdgcn_s_barrier();
    __builtin_amdgcn_sched_barrier(0);
    if (t + 3 < nsteps) STAGE((t+3)&3, (t+3)*BK);   // issue early: max flight time
    const ushort_t* as = &As[t&3][0];
    const ushort_t* bs = &Bs[t&3][0];
    short8v af[4], bfv[4];
    #pragma unroll
    for (int i=0;i<4;++i) af[i]  = *(const short8v*)&as[(wm+i*16+lr)*BK + lk*8];
    #pragma unroll
    for (int j=0;j<4;++j) bfv[j] = *(const short8v*)&bs[(wn+j*16+lr)*BK + lk*8];
    #pragma unroll
    for (int i=0;i<4;++i)
      #pragma unroll
      for (int j=0;j<4;++j)
        acc[i][j] = __builtin_amdgcn_mfma_f32_16x16x32_bf16(af[i], bfv[j], acc[i][j], 0,0,0);
  }
  #pragma unroll
  for (int i=0;i<4;++i)
    #pragma unroll
    for (int j=0;j<4;++j)
      #pragma unroll
      for (int r=0;r<4;++r){
        int row = bm + wm + i*16 + lk*4 + r;
        int col = bn + wn + j*16 + lr;
        if (OUTBF) ((ushort_t*)Cout)[(size_t)row*N + col] = f2bf(acc[i][j][r]);
        else       ((float*)Cout)[(size_t)row*N + col]    = acc[i][j][r];
      }
}

// ---------------- fallback fp32-B fused-cvt GEMM ----------------
template<int BN, bool OUTBF>
__global__ __launch_bounds__(256) void gemm_bt(const ushort_t* __restrict__ A,
    const float* __restrict__ Bw, void* __restrict__ Cout, int M, int N, int K){
  constexpr int BM=128, BK=32, LD=40;
  __shared__ ushort_t As[BM*LD];
  __shared__ ushort_t Bs[BN*LD];
  const int tid = threadIdx.x;
  const int bm = blockIdx.x*BM, bn = blockIdx.y*BN;
  const int wv = tid>>6, lane = tid&63;
  const int wm = (wv>>1)*64, wn = (wv&1)*(BN/2);
  const int lr = lane&15, lk = lane>>4;
  constexpr int NJ = BN/32;
  f32x4 acc[4][NJ];
  #pragma unroll
  for (int i=0;i<4;++i)
    #pragma unroll
    for (int j=0;j<NJ;++j) acc[i][j] = (f32x4){0.f,0.f,0.f,0.f};
  const int arow = tid>>1, ak=(tid&1)*16;
  constexpr int BPT = BN*BK/256;
  const int brow = (BN==128)?(tid>>1):(tid>>2);
  const int bk   = (BN==128)?((tid&1)*16):((tid&3)*8);
  const ushort_t* gA = A + (size_t)(bm+arow)*K + ak;
  const float*    gB = Bw + (size_t)(bn+brow)*K + bk;
  for (int k0=0;k0<K;k0+=BK){
    ushort8 a0 = *(const ushort8*)(gA + k0);
    ushort8 a1 = *(const ushort8*)(gA + k0 + 8);
    float vals[BPT];
    #pragma unroll
    for (int i=0;i<BPT;i+=4){
      float4 v = *(const float4*)(gB + k0 + i);
      vals[i]=v.x; vals[i+1]=v.y; vals[i+2]=v.z; vals[i+3]=v.w;
    }
    *(ushort8*)&As[arow*LD+ak]   = a0;
    *(ushort8*)&As[arow*LD+ak+8] = a1;
    #pragma unroll
    for (int i=0;i<BPT;i+=8){
      ushort8 u;
      #pragma unroll
      for (int q=0;q<8;++q) u[q]=f2bf(vals[i+q]);
      *(ushort8*)&Bs[brow*LD+bk+i] = u;
    }
    __syncthreads();
    short8v af[4], bfv[NJ];
    #pragma unroll
    for (int i=0;i<4;++i) af[i] = *(const short8v*)&As[(wm+i*16+lr)*LD + lk*8];
    #pragma unroll
    for (int j=0;j<NJ;++j) bfv[j] = *(const short8v*)&Bs[(wn+j*16+lr)*LD + lk*8];
    #pragma unroll
    for (int i=0;i<4;++i)
      #pragma unroll
      for (int j=0;j<NJ;++j)
        acc[i][j] = __builtin_amdgcn_mfma_f32_16x16x32_bf16(af[i], bfv[j], acc[i][j], 0,0,0);
    __syncthreads();
  }
  #pragma unroll
  for (int i=0;i<4;++i)
    #pragma unroll
    for (int j=0;j<NJ;++j)
      #pragma unroll
      for (int r=0;r<4;++r){
        int row = bm + wm + i*16 + lk*4 + r;
        int col = bn + wn + j*16 + lr;
        if (OUTBF) ((ushort_t*)Cout)[(size_t)row*N + col] = f2bf(acc[i][j][r]);
        else       ((float*)Cout)[(size_t)row*N + col]    = acc[i][j][r];
      }
}

// ---------------- LoRA A projections via MFMA ----------------
__global__ __launch_bounds__(256) void lora_a_mfma(const int* __restrict__ meta,
    const int* __restrict__ list_tok, const ushort_t* __restrict__ xbf,
    const float* __restrict__ A1, const float* __restrict__ A3,
    ushort_t* __restrict__ u1bf, ushort_t* __restrict__ u3bf){
  int ti = blockIdx.x;
  if (ti >= meta[0]) return;
  int e  = meta[1+ti];
  int p0 = meta[1+MAXT+ti];
  int np = meta[1+2*MAXT+ti];
  int wv = threadIdx.x>>6, lane = threadIdx.x&63;
  int lr = lane&15, lk = lane>>4;
  int t = list_tok[p0+lr];
  const ushort_t* xrow = xbf + (size_t)t*H;
  const int kbase = wv*(H/4);
  f32x4 acc1[2], acc3[2];
  #pragma unroll
  for (int j=0;j<2;++j){ acc1[j]=(f32x4){0,0,0,0}; acc3[j]=(f32x4){0,0,0,0}; }
  for (int ks=0; ks<H/4; ks+=32){
    int k = kbase + ks + lk*8;
    short8v a = *(const short8v*)(xrow + k);
    #pragma unroll
    for (int j=0;j<2;++j){
      const float* b1 = A1 + ((size_t)e*RR + j*16 + lr)*H + k;
      const float* b3 = A3 + ((size_t)e*RR + j*16 + lr)*H + k;
      acc1[j] = __builtin_amdgcn_mfma_f32_16x16x32_bf16(a, cvt8(b1), acc1[j], 0,0,0);
      acc3[j] = __builtin_amdgcn_mfma_f32_16x16x32_bf16(a, cvt8(b3), acc3[j], 0,0,0);
    }
  }
  __shared__ float red[4][2][2][4][64];
  #pragma unroll
  for (int j=0;j<2;++j)
    #pragma unroll
    for (int r=0;r<4;++r){
      red[wv][0][j][r][lane] = acc1[j][r];
      red[wv][1][j][r][lane] = acc3[j][r];
    }
  __syncthreads();
  if (wv==0){
    #pragma unroll
    for (int j=0;j<2;++j)
      #pragma unroll
      for (int r=0;r<4;++r){
        int p = lk*4 + r;
        if (p < np){
          float s1 = red[0][0][j][r][lane]+red[1][0][j][r][lane]+red[2][0][j][r][lane]+red[3][0][j][r][lane];
          float s3 = red[0][1][j][r][lane]+red[1][1][j][r][lane]+red[2][1][j][r][lane]+red[3][1][j][r][lane];
          u1bf[(size_t)(p0+p)*RR + j*16 + lr] = f2bf(s1);
          u3bf[(size_t)(p0+p)*RR + j*16 + lr] = f2bf(s3);
        }
      }
  }
}

// ---------------- per-expert fused: d1/d3 via MFMA, silu, x2 ----------------
template<typename WT>
__global__ __launch_bounds__(256) void expert_x2(const int* __restrict__ meta, const int* __restrict__ list_tok,
    const WT* __restrict__ B1g, const WT* __restrict__ B3g,
    const ushort_t* __restrict__ u1bf, const ushort_t* __restrict__ u3bf,
    const ushort_t* __restrict__ x1b, const ushort_t* __restrict__ x3b,
    ushort_t* __restrict__ x2buf){
  int ti = blockIdx.x;
  if (ti >= meta[0]) return;
  int e  = meta[1+ti];
  int p0 = meta[1+MAXT+ti];
  int np = meta[1+2*MAXT+ti];
  int fc = blockIdx.y*128 + (threadIdx.x>>6)*32;
  int lane = threadIdx.x&63;
  int lr = lane&15, lk = lane>>4;
  short8v au1 = *(const short8v*)(u1bf + (size_t)(p0+lr)*RR + lk*8);
  short8v au3 = *(const short8v*)(u3bf + (size_t)(p0+lr)*RR + lk*8);
  f32x4 z = (f32x4){0.f,0.f,0.f,0.f};
  f32x4 acc1[2], acc3[2];
  #pragma unroll
  for (int j=0;j<2;++j){
    acc1[j]=z; acc3[j]=z;
    int f = fc + j*16 + lr;
    const WT* b1r = B1g + ((size_t)e*F + f)*RR + lk*8;
    const WT* b3r = B3g + ((size_t)e*F + f)*RR + lk*8;
    acc1[j] = __builtin_amdgcn_mfma_f32_16x16x32_bf16(au1, load8w(b1r), acc1[j], 0,0,0);
    acc3[j] = __builtin_amdgcn_mfma_f32_16x16x32_bf16(au3, load8w(b3r), acc3[j], 0,0,0);
  }
  #pragma unroll
  for (int r=0;r<4;++r){
    int p = lk*4 + r;
    if (p < np){
      int t = list_tok[p0+p];
      #pragma unroll
      for (int j=0;j<2;++j){
        int f = fc + j*16 + lr;
        size_t ix = (size_t)t*F + f;
        float x1  = bf2f(x1b[ix]) + acc1[j][r];
        float x3v = bf2f(x3b[ix]) + acc3[j][r];
        float sl = x1/(1.f + __expf(-x1));
        x2buf[(size_t)(p0+p)*F + f] = f2bf(sl*x3v);
      }
    }
  }
}

// ---------------- combine ----------------
__global__ __launch_bounds__(256) void combine_x2(const int* __restrict__ tok2pair, const float* __restrict__ rwn,
    const ushort_t* __restrict__ x2buf, ushort_t* __restrict__ x2c){
  size_t i = (size_t)blockIdx.x*256 + threadIdx.x;
  size_t total = (size_t)NT*(F/8);
  if (i>=total) return;
  int t = (int)(i/(F/8));
  int c = (int)(i%(F/8))*8;
  int pa = tok2pair[t*2], pb = tok2pair[t*2+1];
  float wa = rwn[t*2], wb = rwn[t*2+1];
  ushort8 va = *(const ushort8*)(x2buf + (size_t)pa*F + c);
  ushort8 vb = *(const ushort8*)(x2buf + (size_t)pb*F + c);
  ushort8 o;
  #pragma unroll
  for (int q=0;q<8;++q) o[q] = f2bf(wa*bf2f(va[q]) + wb*bf2f(vb[q]));
  *(ushort8*)(x2c + (size_t)t*F + c) = o;
}

// ---------------- u2 = A2[e] @ x2 via MFMA ----------------
__global__ __launch_bounds__(256) void u2_mfma(const int* __restrict__ meta,
    const float* __restrict__ A2, const ushort_t* __restrict__ x2buf, float* __restrict__ u2){
  int ti = blockIdx.x;
  if (ti >= meta[0]) return;
  int e  = meta[1+ti];
  int p0 = meta[1+MAXT+ti];
  int np = meta[1+2*MAXT+ti];
  int wv = threadIdx.x>>6, lane = threadIdx.x&63;
  int lr = lane&15, lk = lane>>4;
  const ushort_t* xrow = x2buf + (size_t)(p0+lr)*F;
  const int kbase = wv*(F/4);
  f32x4 acc[2];
  acc[0]=(f32x4){0,0,0,0}; acc[1]=(f32x4){0,0,0,0};
  for (int ks=0; ks<F/4; ks+=32){
    int k = kbase + ks + lk*8;
    short8v a = *(const short8v*)(xrow + k);
    #pragma unroll
    for (int j=0;j<2;++j){
      const float* br = A2 + ((size_t)e*RR + j*16 + lr)*F + k;
      acc[j] = __builtin_amdgcn_mfma_f32_16x16x32_bf16(a, cvt8(br), acc[j], 0,0,0);
    }
  }
  __shared__ float red[4][2][4][64];
  #pragma unroll
  for (int j=0;j<2;++j)
    #pragma unroll
    for (int r=0;r<4;++r) red[wv][j][r][lane] = acc[j][r];
  __syncthreads();
  if (wv==0){
    #pragma unroll
    for (int j=0;j<2;++j)
      #pragma unroll
      for (int r=0;r<4;++r){
        int p = lk*4 + r;
        if (p < np){
          float s = red[0][j][r][lane]+red[1][j][r][lane]+red[2][j][r][lane]+red[3][j][r][lane];
          u2[(size_t)(p0+p)*RR + j*16 + lr] = s;
        }
      }
  }
}

// ---------------- lora2 add ----------------
__global__ __launch_bounds__(256) void lora2_add(const int* __restrict__ tok2pair, const int* __restrict__ list_e,
    const float* __restrict__ rwn, const float* __restrict__ B2, const float* __restrict__ u2,
    float* __restrict__ out){
  int t = blockIdx.x;
  __shared__ float u2s[2][RR];
  __shared__ int es[2];
  __shared__ float wss[2];
  if (threadIdx.x < 64){
    int s = threadIdx.x>>5, r = threadIdx.x&31;
    int pair = tok2pair[t*2+s];
    u2s[s][r] = u2[(size_t)pair*RR + r];
    if (r==0){ es[s]=list_e[pair]; wss[s]=rwn[t*2+s]; }
  }
  __syncthreads();
  int e0=es[0], e1=es[1];
  float w0=wss[0], w1=wss[1];
  for (int h=threadIdx.x; h<H; h+=256){
    const float4* b0 = (const float4*)(B2 + ((size_t)e0*H + h)*RR);
    const float4* b1 = (const float4*)(B2 + ((size_t)e1*H + h)*RR);
    float d0=0.f, d1=0.f;
    #pragma unroll
    for (int c=0;c<RR/4;++c){
      float4 v0=b0[c]; d0 += v0.x*u2s[0][c*4+0] + v0.y*u2s[0][c*4+1] + v0.z*u2s[0][c*4+2] + v0.w*u2s[0][c*4+3];
      float4 v1=b1[c]; d1 += v1.x*u2s[1][c*4+0] + v1.y*u2s[1][c*4+1] + v1.z*u2s[1][c*4+2] + v1.w*u2s[1][c*4+3];
    }
    out[(size_t)t*H + h] += w0*d0 + w1*d1;
  }
}

extern "C" void kernel_launch(void* const* d_in, const int* in_sizes, int n_in,
                              void* d_out, int out_size, void* d_ws, size_t ws_size,
                              hipStream_t stream){
  const float* x   = (const float*)d_in[0];
  const float* gw  = (const float*)d_in[1];
  const float* W1  = (const float*)d_in[2];
  const float* W2  = (const float*)d_in[3];
  const float* W3  = (const float*)d_in[4];
  const float* A1  = (const float*)d_in[5];
  const float* B1  = (const float*)d_in[6];
  const float* A2  = (const float*)d_in[7];
  const float* B2  = (const float*)d_in[8];
  const float* A3  = (const float*)d_in[9];
  const float* B3  = (const float*)d_in[10];
  float* outF = (float*)d_out;
  float* outL = outF + (size_t)NT*H;

  char* base = (char*)d_ws;
  size_t o = 0;
  auto mk = [&](size_t bytes){ void* p = base + o; o += (bytes + 255) & ~(size_t)255; return p; };
  int*   sel      = (int*)  mk((size_t)NT*2*4);
  float* rwn      = (float*)mk((size_t)NT*2*4);
  int*   cnts     = (int*)  mk(512);
  int*   cnt      = cnts;
  int*   cnt2     = cnts + 64;
  int*   off      = (int*)  mk(256);
  int*   meta     = (int*)  mk((size_t)(1+3*MAXT)*4);
  int*   list_tok = (int*)  mk((size_t)NPAIRP*4);
  int*   list_e   = (int*)  mk((size_t)NPAIRP*4);
  int*   tok2pair = (int*)  mk((size_t)NT*2*4);
  ushort_t* xbf   = (ushort_t*)mk((size_t)NT*H*2);
  ushort_t* x1b   = (ushort_t*)mk((size_t)NT*F*2);
  ushort_t* x3b   = (ushort_t*)mk((size_t)NT*F*2);
  ushort_t* x2buf = (ushort_t*)mk((size_t)NPAIRP*F*2);
  ushort_t* x2c   = (ushort_t*)mk((size_t)NT*F*2);
  ushort_t* u1bf  = (ushort_t*)mk((size_t)NPAIRP*RR*2);
  ushort_t* u3bf  = (ushort_t*)mk((size_t)NPAIRP*RR*2);
  float* u2       = (float*)mk((size_t)NPAIRP*RR*4);
  // bf16 weight copies (used only if ws is large enough)
  ushort_t* w1bf = (ushort_t*)mk((size_t)F*H*2);
  ushort_t* w3bf = (ushort_t*)mk((size_t)F*H*2);
  ushort_t* w2bf = (ushort_t*)mk((size_t)H*F*2);
  ushort_t* b1bf = (ushort_t*)mk((size_t)NE*F*RR*2);
  ushort_t* b3bf = (ushort_t*)mk((size_t)NE*F*RR*2);
  bool useBF = (o <= ws_size);
  (void)in_sizes; (void)n_in; (void)out_size;

  hipMemsetAsync(cnts, 0, 512, stream);
  cast_x<<<(NT*H/4)/256, 256, 0, stream>>>(x, xbf);
  router_kernel<<<NT/4, 256, 0, stream>>>(x, gw, outL, sel, rwn, cnt);
  prefix_kernel<<<1, 1, 0, stream>>>(cnt, off, meta);
  scatter_kernel<<<(NPAIRP+255)/256, 256, 0, stream>>>(sel, off, cnt2, list_tok, list_e, tok2pair);

  if (useBF){
    cast_f2bf<<<2048, 256, 0, stream>>>(W1, w1bf, (long)F*H/8);
    cast_f2bf<<<2048, 256, 0, stream>>>(W3, w3bf, (long)F*H/8);
    cast_f2bf<<<2048, 256, 0, stream>>>(W2, w2bf, (long)H*F/8);
    cast_f2bf<<<512, 256, 0, stream>>>(B1, b1bf, (long)NE*F*RR/8);
    cast_f2bf<<<512, 256, 0, stream>>>(B3, b3bf, (long)NE*F*RR/8);
    gemm_pipe<true><<<(NT/128)*(F/128), 256, 0, stream>>>(xbf, w1bf, x1b, NT, F, H);
    gemm_pipe<true><<<(NT/128)*(F/128), 256, 0, stream>>>(xbf, w3bf, x3b, NT, F, H);
  } else {
    gemm_bt<128,true><<<dim3(NT/128, F/128), 256, 0, stream>>>(xbf, W1, x1b, NT, F, H);
    gemm_bt<128,true><<<dim3(NT/128, F/128), 256, 0, stream>>>(xbf, W3, x3b, NT, F, H);
  }
  lora_a_mfma<<<MAXT, 256, 0, stream>>>(meta, list_tok, xbf, A1, A3, u1bf, u3bf);
  if (useBF)
    expert_x2<ushort_t><<<dim3(MAXT, F/128), 256, 0, stream>>>(meta, list_tok, b1bf, b3bf, u1bf, u3bf, x1b, x3b, x2buf);
  else
    expert_x2<float><<<dim3(MAXT, F/128), 256, 0, stream>>>(meta, list_tok, B1, B3, u1bf, u3bf, x1b, x3b, x2buf);
  combine_x2<<<(NT*(F/8))/256, 256, 0, stream>>>(tok2pair, rwn, x2buf, x2c);
  u2_mfma<<<MAXT, 256, 0, stream>>>(meta, A2, x2buf, u2);
  if (useBF)
    gemm_pipe<false><<<(NT/128)*(H/128), 256, 0, stream>>>(x2c, w2bf, outF, NT, H, F);
  else
    gemm_bt<128,false><<<dim3(NT/128, H/128), 256, 0, stream>>>(x2c, W2, outF, NT, H, F);
  lora2_add<<<NT, 256, 0, stream>>>(tok2pair, list_e, rwn, B2, u2, outF);
}

// Round 6
// 1197.201 us; speedup vs baseline: 1.8874x; 1.1170x over previous
//
#include <hip/hip_runtime.h>

#define H 4096
#define F 14336
#define NE 8
#define RR 32
#define NT 1024
#define MAXT 136
#define NPAIR 2048
#define NPAIRP 2064   // padded (tile overrun on last expert)

typedef unsigned short ushort_t;
typedef __attribute__((ext_vector_type(4))) float f32x4;
typedef __attribute__((ext_vector_type(8))) short short8v;
typedef __attribute__((ext_vector_type(8))) unsigned short ushort8;
typedef __attribute__((ext_vector_type(4))) unsigned short ushort4v;

__device__ inline unsigned short f2bf(float f){
  unsigned int x = __float_as_uint(f);
  return (unsigned short)((x + 0x7fffu + ((x>>16)&1u)) >> 16);
}
__device__ inline float bf2f(unsigned short u){
  return __uint_as_float(((unsigned int)u)<<16);
}
__device__ inline short8v cvt8(const float* p){
  float4 v0 = *(const float4*)p, v1 = *(const float4*)(p+4);
  short8v b;
  b[0]=(short)f2bf(v0.x); b[1]=(short)f2bf(v0.y); b[2]=(short)f2bf(v0.z); b[3]=(short)f2bf(v0.w);
  b[4]=(short)f2bf(v1.x); b[5]=(short)f2bf(v1.y); b[6]=(short)f2bf(v1.z); b[7]=(short)f2bf(v1.w);
  return b;
}
__device__ inline short8v load8w(const float* p){ return cvt8(p); }
__device__ inline short8v load8w(const ushort_t* p){ return *(const short8v*)p; }

__device__ inline void gload16(const void* g, void* l){
  __builtin_amdgcn_global_load_lds(
      (const __attribute__((address_space(1))) void*)g,
      (__attribute__((address_space(3))) void*)l, 16, 0, 0);
}

// ---------------- fp32 -> bf16 streaming cast ----------------
__global__ __launch_bounds__(256) void cast_f2bf(const float* __restrict__ src,
    ushort_t* __restrict__ dst, long n8){
  long stride = (long)gridDim.x*256;
  for (long i = (long)blockIdx.x*256 + threadIdx.x; i < n8; i += stride){
    const float4* p = (const float4*)(src + i*8);
    float4 v0 = p[0], v1 = p[1];
    ushort8 o;
    o[0]=f2bf(v0.x); o[1]=f2bf(v0.y); o[2]=f2bf(v0.z); o[3]=f2bf(v0.w);
    o[4]=f2bf(v1.x); o[5]=f2bf(v1.y); o[6]=f2bf(v1.z); o[7]=f2bf(v1.w);
    *(ushort8*)(dst + i*8) = o;
  }
}

// ---------------- router ----------------
__global__ __launch_bounds__(256) void router_kernel(const float* __restrict__ x,
    const float* __restrict__ gw, float* __restrict__ logits,
    int* __restrict__ sel, float* __restrict__ rwn, int* __restrict__ cnt){
  int t = blockIdx.x*4 + (threadIdx.x>>6);
  int lane = threadIdx.x & 63;
  const float4* xr = (const float4*)(x + (size_t)t*H);
  float s[NE];
  #pragma unroll
  for (int e=0;e<NE;++e) s[e]=0.f;
  for (int c=lane; c<H/4; c+=64){
    float4 xv = xr[c];
    #pragma unroll
    for (int e=0;e<NE;++e){
      float4 g = ((const float4*)(gw + (size_t)e*H))[c];
      s[e] += xv.x*g.x + xv.y*g.y + xv.z*g.z + xv.w*g.w;
    }
  }
  #pragma unroll
  for (int e=0;e<NE;++e){
    for (int off=32; off; off>>=1) s[e] += __shfl_down(s[e], off);
  }
  if (lane==0){
    float mx = s[0];
    #pragma unroll
    for (int e=1;e<NE;++e) mx = fmaxf(mx, s[e]);
    float p[NE]; float den=0.f;
    #pragma unroll
    for (int e=0;e<NE;++e){ p[e]=__expf(s[e]-mx); den+=p[e]; }
    int i0=0;
    #pragma unroll
    for (int e=1;e<NE;++e) if (p[e]>p[i0]) i0=e;
    int i1 = (i0==0)?1:0;
    #pragma unroll
    for (int e=0;e<NE;++e){ if (e!=i0 && p[e]>p[i1]) i1=e; }
    float p0=p[i0]/den, p1=p[i1]/den;
    float inv = 1.f/(p0+p1);
    #pragma unroll
    for (int e=0;e<NE;++e) logits[t*NE+e] = s[e];
    sel[t*2]=i0; sel[t*2+1]=i1;
    rwn[t*2]=p0*inv; rwn[t*2+1]=p1*inv;
    atomicAdd(&cnt[i0],1); atomicAdd(&cnt[i1],1);
  }
}

// ---------------- prefix + tile table ----------------
__global__ void prefix_kernel(const int* __restrict__ cnt, int* __restrict__ off, int* __restrict__ meta){
  if (threadIdx.x==0 && blockIdx.x==0){
    int o=0;
    for (int e=0;e<NE;++e){ off[e]=o; o+=cnt[e]; }
    off[NE]=o;
    int ntl=0;
    for (int e=0;e<NE;++e){
      int c=cnt[e], b=off[e];
      for (int ps=0; ps<c; ps+=16){
        meta[1+ntl] = e;
        meta[1+MAXT+ntl] = b+ps;
        meta[1+2*MAXT+ntl] = (c-ps<16)?(c-ps):16;
        ++ntl;
      }
    }
    meta[0]=ntl;
  }
}

// ---------------- scatter ----------------
__global__ void scatter_kernel(const int* __restrict__ sel, const int* __restrict__ off,
    int* __restrict__ cnt2, int* __restrict__ list_tok, int* __restrict__ list_e,
    int* __restrict__ tok2pair){
  int idx = blockIdx.x*256 + threadIdx.x;
  if (idx >= NT*2){
    if (idx < NPAIRP){ list_tok[idx]=0; list_e[idx]=0; }
    return;
  }
  int e = sel[idx];
  int pos = atomicAdd(&cnt2[e], 1);
  int pair = off[e] + pos;
  list_tok[pair] = idx>>1;
  list_e[pair] = e;
  tok2pair[idx] = pair;
}

// ---------------- cast hidden states to bf16 ----------------
__global__ __launch_bounds__(256) void cast_x(const float* __restrict__ x, ushort_t* __restrict__ xbf){
  size_t i = ((size_t)blockIdx.x*256 + threadIdx.x)*4;
  if (i >= (size_t)NT*H) return;
  float4 v = *(const float4*)(x+i);
  ushort4v o;
  o[0]=f2bf(v.x); o[1]=f2bf(v.y); o[2]=f2bf(v.z); o[3]=f2bf(v.w);
  *(ushort4v*)(xbf+i) = o;
}

// ---------------- 256x256 MFMA GEMM, 8 waves, BK=64, 2-phase dbuf ----------------
// A: bf16 via global_load_lds (linear LDS). B: fp32 weights reg-staged + cvt to bf16
// (kills the separate weight-cast pass). One __syncthreads per K-tile (implicit
// vmcnt(0)+lgkmcnt(0) is the pipeline wait). Optional fused 2nd matrix (W1|W3) and
// deterministic split-K (partials per split, no atomics).
template<bool OUTBF>
__global__ __launch_bounds__(512) void gemm_256(const ushort_t* __restrict__ A,
    const float* __restrict__ Bw0, const float* __restrict__ Bw1,
    void* __restrict__ C0, void* __restrict__ C1,
    int M, int N, int GN, int GNt, int Klen, int Kfull){
  constexpr int BM=256, BN=256, BK=64;
  __shared__ ushort_t As[2][BM*BK];   // 2 x 32 KB
  __shared__ ushort_t Bs[2][BN*BK];   // 2 x 32 KB  -> 128 KB total
  const int tid = threadIdx.x;
  const int w = tid>>6, lane = tid&63;
  const int wr = w>>2, wc = w&3;
  const int lr = lane&15, lk = lane>>4;
  const int GM = M/BM;
  // bijective XCD swizzle (m204 form)
  const int T = gridDim.x;
  const int q8 = T>>3, r8 = T&7;
  const int xcd = blockIdx.x & 7, oo = blockIdx.x>>3;
  const int id2 = (xcd < r8 ? xcd*(q8+1) : r8*(q8+1) + (xcd-r8)*q8) + oo;
  const int m  = id2 % GM;
  const int sn = id2 / GM;
  const int n2 = sn % GNt;
  const int s  = sn / GNt;
  const int bm = m*BM;
  const int mat = (n2 >= GN) ? 1 : 0;
  const int ncb = (n2 - mat*GN)*BN;
  const float* Bw = mat ? Bw1 : Bw0;
  const int koff = s*Klen;

  f32x4 acc[8][4];
  #pragma unroll
  for (int i=0;i<8;++i)
    #pragma unroll
    for (int j=0;j<4;++j) acc[i][j]=(f32x4){0.f,0.f,0.f,0.f};

  // A staging: 4 global_load_lds per wave; wave w covers rows [w*32, w*32+32)
  const int aRow = w*32 + (lane>>3);
  const ushort_t* gA = A + (size_t)(bm + aRow)*Kfull + koff + (lane&7)*8;
  const int aL = w*2048 + lane*8;            // ushort idx; +q*512 per chunk
  // B staging: thread covers half-row (32 fp32) of B tile
  const int bRow = tid>>1;
  const int bCol = (tid&1)*32;
  const float* gB = Bw + (size_t)(ncb + bRow)*Kfull + koff + bCol;
  const int bL = bRow*64 + bCol;

  float4 fb0,fb1,fb2,fb3,fb4,fb5,fb6,fb7;
  auto BLOAD = [&](int k0){
    fb0 = *(const float4*)(gB + k0);      fb1 = *(const float4*)(gB + k0 + 4);
    fb2 = *(const float4*)(gB + k0 + 8);  fb3 = *(const float4*)(gB + k0 + 12);
    fb4 = *(const float4*)(gB + k0 + 16); fb5 = *(const float4*)(gB + k0 + 20);
    fb6 = *(const float4*)(gB + k0 + 24); fb7 = *(const float4*)(gB + k0 + 28);
  };
  auto BWRITE = [&](int buf){
    ushort_t* d = &Bs[buf][bL];
    float4 U[8] = {fb0,fb1,fb2,fb3,fb4,fb5,fb6,fb7};
    #pragma unroll
    for (int j=0;j<4;++j){
      float4 u = U[2*j], v = U[2*j+1];
      short8v o;
      o[0]=(short)f2bf(u.x); o[1]=(short)f2bf(u.y); o[2]=(short)f2bf(u.z); o[3]=(short)f2bf(u.w);
      o[4]=(short)f2bf(v.x); o[5]=(short)f2bf(v.y); o[6]=(short)f2bf(v.z); o[7]=(short)f2bf(v.w);
      *(short8v*)(d + j*8) = o;
    }
  };
  auto ASTAGE = [&](int buf, int k0){
    #pragma unroll
    for (int qq=0;qq<4;++qq)
      gload16(gA + k0 + qq*8*Kfull, &As[buf][aL + qq*512]);
  };

  const int nt = Klen/BK;
  ASTAGE(0,0); BLOAD(0); BWRITE(0);
  __syncthreads();
  int cur = 0;
  for (int t=0; t<nt; ++t){
    const bool pf = (t+1 < nt);
    if (pf){ ASTAGE(cur^1, (t+1)*BK); BLOAD((t+1)*BK); }   // issue early, land under MFMA
    const ushort_t* as = &As[cur][0];
    const ushort_t* bs = &Bs[cur][0];
    #pragma unroll
    for (int ks=0; ks<2; ++ks){
      short8v af[8], bfv[4];
      #pragma unroll
      for (int mi=0;mi<8;++mi) af[mi]  = *(const short8v*)&as[(wr*128+mi*16+lr)*64 + ks*32 + lk*8];
      #pragma unroll
      for (int ni=0;ni<4;++ni) bfv[ni] = *(const short8v*)&bs[(wc*64+ni*16+lr)*64 + ks*32 + lk*8];
      #pragma unroll
      for (int mi=0;mi<8;++mi)
        #pragma unroll
        for (int ni=0;ni<4;++ni)
          acc[mi][ni] = __builtin_amdgcn_mfma_f32_16x16x32_bf16(af[mi], bfv[ni], acc[mi][ni], 0,0,0);
    }
    if (pf) BWRITE(cur^1);          // cvt+ds_write after compute (global latency hidden)
    __syncthreads();                 // drains vmcnt(0)+lgkmcnt(0): next tile ready
    cur ^= 1;
  }
  // epilogue
  const int rowb = bm + wr*128 + lk*4;
  const int colb = ncb + wc*64 + lr;
  if (OUTBF){
    ushort_t* C = (ushort_t*)(mat ? C1 : C0);
    #pragma unroll
    for (int mi=0;mi<8;++mi)
      #pragma unroll
      for (int ni=0;ni<4;++ni)
        #pragma unroll
        for (int rr2=0;rr2<4;++rr2)
          C[(size_t)(rowb+mi*16+rr2)*N + colb + ni*16] = f2bf(acc[mi][ni][rr2]);
  } else {
    float* C = (float*)C0 + (size_t)s*M*N;
    #pragma unroll
    for (int mi=0;mi<8;++mi)
      #pragma unroll
      for (int ni=0;ni<4;++ni)
        #pragma unroll
        for (int rr2=0;rr2<4;++rr2)
          C[(size_t)(rowb+mi*16+rr2)*N + colb + ni*16] = acc[mi][ni][rr2];
  }
}

// ---------------- split-K reduce: out = sum of 4 partials ----------------
__global__ __launch_bounds__(256) void reduce4(const float* __restrict__ part, float* __restrict__ out){
  size_t i = ((size_t)blockIdx.x*256 + threadIdx.x)*4;
  if (i >= (size_t)NT*H) return;
  const size_t S = (size_t)NT*H;
  float4 a = *(const float4*)(part+i);
  float4 b = *(const float4*)(part+S+i);
  float4 c = *(const float4*)(part+2*S+i);
  float4 d = *(const float4*)(part+3*S+i);
  float4 o;
  o.x = a.x+b.x+c.x+d.x; o.y = a.y+b.y+c.y+d.y;
  o.z = a.z+b.z+c.z+d.z; o.w = a.w+b.w+c.w+d.w;
  *(float4*)(out+i) = o;
}

// ---------------- fallback fp32-B fused-cvt GEMM ----------------
template<int BN, bool OUTBF>
__global__ __launch_bounds__(256) void gemm_bt(const ushort_t* __restrict__ A,
    const float* __restrict__ Bw, void* __restrict__ Cout, int M, int N, int K){
  constexpr int BM=128, BK=32, LD=40;
  __shared__ ushort_t As[BM*LD];
  __shared__ ushort_t Bs[BN*LD];
  const int tid = threadIdx.x;
  const int bm = blockIdx.x*BM, bn = blockIdx.y*BN;
  const int wv = tid>>6, lane = tid&63;
  const int wm = (wv>>1)*64, wn = (wv&1)*(BN/2);
  const int lr = lane&15, lk = lane>>4;
  constexpr int NJ = BN/32;
  f32x4 acc[4][NJ];
  #pragma unroll
  for (int i=0;i<4;++i)
    #pragma unroll
    for (int j=0;j<NJ;++j) acc[i][j] = (f32x4){0.f,0.f,0.f,0.f};
  const int arow = tid>>1, ak=(tid&1)*16;
  constexpr int BPT = BN*BK/256;
  const int brow = (BN==128)?(tid>>1):(tid>>2);
  const int bk   = (BN==128)?((tid&1)*16):((tid&3)*8);
  const ushort_t* gA = A + (size_t)(bm+arow)*K + ak;
  const float*    gB = Bw + (size_t)(bn+brow)*K + bk;
  for (int k0=0;k0<K;k0+=BK){
    ushort8 a0 = *(const ushort8*)(gA + k0);
    ushort8 a1 = *(const ushort8*)(gA + k0 + 8);
    float vals[BPT];
    #pragma unroll
    for (int i=0;i<BPT;i+=4){
      float4 v = *(const float4*)(gB + k0 + i);
      vals[i]=v.x; vals[i+1]=v.y; vals[i+2]=v.z; vals[i+3]=v.w;
    }
    *(ushort8*)&As[arow*LD+ak]   = a0;
    *(ushort8*)&As[arow*LD+ak+8] = a1;
    #pragma unroll
    for (int i=0;i<BPT;i+=8){
      ushort8 u;
      #pragma unroll
      for (int q=0;q<8;++q) u[q]=f2bf(vals[i+q]);
      *(ushort8*)&Bs[brow*LD+bk+i] = u;
    }
    __syncthreads();
    short8v af[4], bfv[NJ];
    #pragma unroll
    for (int i=0;i<4;++i) af[i] = *(const short8v*)&As[(wm+i*16+lr)*LD + lk*8];
    #pragma unroll
    for (int j=0;j<NJ;++j) bfv[j] = *(const short8v*)&Bs[(wn+j*16+lr)*LD + lk*8];
    #pragma unroll
    for (int i=0;i<4;++i)
      #pragma unroll
      for (int j=0;j<NJ;++j)
        acc[i][j] = __builtin_amdgcn_mfma_f32_16x16x32_bf16(af[i], bfv[j], acc[i][j], 0,0,0);
    __syncthreads();
  }
  #pragma unroll
  for (int i=0;i<4;++i)
    #pragma unroll
    for (int j=0;j<NJ;++j)
      #pragma unroll
      for (int r=0;r<4;++r){
        int row = bm + wm + i*16 + lk*4 + r;
        int col = bn + wn + j*16 + lr;
        if (OUTBF) ((ushort_t*)Cout)[(size_t)row*N + col] = f2bf(acc[i][j][r]);
        else       ((float*)Cout)[(size_t)row*N + col]    = acc[i][j][r];
      }
}

// ---------------- LoRA A projections via MFMA ----------------
__global__ __launch_bounds__(256) void lora_a_mfma(const int* __restrict__ meta,
    const int* __restrict__ list_tok, const ushort_t* __restrict__ xbf,
    const float* __restrict__ A1, const float* __restrict__ A3,
    ushort_t* __restrict__ u1bf, ushort_t* __restrict__ u3bf){
  int ti = blockIdx.x;
  if (ti >= meta[0]) return;
  int e  = meta[1+ti];
  int p0 = meta[1+MAXT+ti];
  int np = meta[1+2*MAXT+ti];
  int wv = threadIdx.x>>6, lane = threadIdx.x&63;
  int lr = lane&15, lk = lane>>4;
  int t = list_tok[p0+lr];
  const ushort_t* xrow = xbf + (size_t)t*H;
  const int kbase = wv*(H/4);
  f32x4 acc1[2], acc3[2];
  #pragma unroll
  for (int j=0;j<2;++j){ acc1[j]=(f32x4){0,0,0,0}; acc3[j]=(f32x4){0,0,0,0}; }
  for (int ks=0; ks<H/4; ks+=32){
    int k = kbase + ks + lk*8;
    short8v a = *(const short8v*)(xrow + k);
    #pragma unroll
    for (int j=0;j<2;++j){
      const float* b1 = A1 + ((size_t)e*RR + j*16 + lr)*H + k;
      const float* b3 = A3 + ((size_t)e*RR + j*16 + lr)*H + k;
      acc1[j] = __builtin_amdgcn_mfma_f32_16x16x32_bf16(a, cvt8(b1), acc1[j], 0,0,0);
      acc3[j] = __builtin_amdgcn_mfma_f32_16x16x32_bf16(a, cvt8(b3), acc3[j], 0,0,0);
    }
  }
  __shared__ float red[4][2][2][4][64];
  #pragma unroll
  for (int j=0;j<2;++j)
    #pragma unroll
    for (int r=0;r<4;++r){
      red[wv][0][j][r][lane] = acc1[j][r];
      red[wv][1][j][r][lane] = acc3[j][r];
    }
  __syncthreads();
  if (wv==0){
    #pragma unroll
    for (int j=0;j<2;++j)
      #pragma unroll
      for (int r=0;r<4;++r){
        int p = lk*4 + r;
        if (p < np){
          float s1 = red[0][0][j][r][lane]+red[1][0][j][r][lane]+red[2][0][j][r][lane]+red[3][0][j][r][lane];
          float s3 = red[0][1][j][r][lane]+red[1][1][j][r][lane]+red[2][1][j][r][lane]+red[3][1][j][r][lane];
          u1bf[(size_t)(p0+p)*RR + j*16 + lr] = f2bf(s1);
          u3bf[(size_t)(p0+p)*RR + j*16 + lr] = f2bf(s3);
        }
      }
  }
}

// ---------------- per-expert fused: d1/d3 via MFMA, silu, x2 ----------------
template<typename WT>
__global__ __launch_bounds__(256) void expert_x2(const int* __restrict__ meta, const int* __restrict__ list_tok,
    const WT* __restrict__ B1g, const WT* __restrict__ B3g,
    const ushort_t* __restrict__ u1bf, const ushort_t* __restrict__ u3bf,
    const ushort_t* __restrict__ x1b, const ushort_t* __restrict__ x3b,
    ushort_t* __restrict__ x2buf){
  int ti = blockIdx.x;
  if (ti >= meta[0]) return;
  int e  = meta[1+ti];
  int p0 = meta[1+MAXT+ti];
  int np = meta[1+2*MAXT+ti];
  int fc = blockIdx.y*128 + (threadIdx.x>>6)*32;
  int lane = threadIdx.x&63;
  int lr = lane&15, lk = lane>>4;
  short8v au1 = *(const short8v*)(u1bf + (size_t)(p0+lr)*RR + lk*8);
  short8v au3 = *(const short8v*)(u3bf + (size_t)(p0+lr)*RR + lk*8);
  f32x4 z = (f32x4){0.f,0.f,0.f,0.f};
  f32x4 acc1[2], acc3[2];
  #pragma unroll
  for (int j=0;j<2;++j){
    acc1[j]=z; acc3[j]=z;
    int f = fc + j*16 + lr;
    const WT* b1r = B1g + ((size_t)e*F + f)*RR + lk*8;
    const WT* b3r = B3g + ((size_t)e*F + f)*RR + lk*8;
    acc1[j] = __builtin_amdgcn_mfma_f32_16x16x32_bf16(au1, load8w(b1r), acc1[j], 0,0,0);
    acc3[j] = __builtin_amdgcn_mfma_f32_16x16x32_bf16(au3, load8w(b3r), acc3[j], 0,0,0);
  }
  #pragma unroll
  for (int r=0;r<4;++r){
    int p = lk*4 + r;
    if (p < np){
      int t = list_tok[p0+p];
      #pragma unroll
      for (int j=0;j<2;++j){
        int f = fc + j*16 + lr;
        size_t ix = (size_t)t*F + f;
        float x1  = bf2f(x1b[ix]) + acc1[j][r];
        float x3v = bf2f(x3b[ix]) + acc3[j][r];
        float sl = x1/(1.f + __expf(-x1));
        x2buf[(size_t)(p0+p)*F + f] = f2bf(sl*x3v);
      }
    }
  }
}

// ---------------- combine ----------------
__global__ __launch_bounds__(256) void combine_x2(const int* __restrict__ tok2pair, const float* __restrict__ rwn,
    const ushort_t* __restrict__ x2buf, ushort_t* __restrict__ x2c){
  size_t i = (size_t)blockIdx.x*256 + threadIdx.x;
  size_t total = (size_t)NT*(F/8);
  if (i>=total) return;
  int t = (int)(i/(F/8));
  int c = (int)(i%(F/8))*8;
  int pa = tok2pair[t*2], pb = tok2pair[t*2+1];
  float wa = rwn[t*2], wb = rwn[t*2+1];
  ushort8 va = *(const ushort8*)(x2buf + (size_t)pa*F + c);
  ushort8 vb = *(const ushort8*)(x2buf + (size_t)pb*F + c);
  ushort8 o;
  #pragma unroll
  for (int q=0;q<8;++q) o[q] = f2bf(wa*bf2f(va[q]) + wb*bf2f(vb[q]));
  *(ushort8*)(x2c + (size_t)t*F + c) = o;
}

// ---------------- u2 = A2[e] @ x2 via MFMA ----------------
__global__ __launch_bounds__(256) void u2_mfma(const int* __restrict__ meta,
    const float* __restrict__ A2, const ushort_t* __restrict__ x2buf, float* __restrict__ u2){
  int ti = blockIdx.x;
  if (ti >= meta[0]) return;
  int e  = meta[1+ti];
  int p0 = meta[1+MAXT+ti];
  int np = meta[1+2*MAXT+ti];
  int wv = threadIdx.x>>6, lane = threadIdx.x&63;
  int lr = lane&15, lk = lane>>4;
  const ushort_t* xrow = x2buf + (size_t)(p0+lr)*F;
  const int kbase = wv*(F/4);
  f32x4 acc[2];
  acc[0]=(f32x4){0,0,0,0}; acc[1]=(f32x4){0,0,0,0};
  for (int ks=0; ks<F/4; ks+=32){
    int k = kbase + ks + lk*8;
    short8v a = *(const short8v*)(xrow + k);
    #pragma unroll
    for (int j=0;j<2;++j){
      const float* br = A2 + ((size_t)e*RR + j*16 + lr)*F + k;
      acc[j] = __builtin_amdgcn_mfma_f32_16x16x32_bf16(a, cvt8(br), acc[j], 0,0,0);
    }
  }
  __shared__ float red[4][2][4][64];
  #pragma unroll
  for (int j=0;j<2;++j)
    #pragma unroll
    for (int r=0;r<4;++r) red[wv][j][r][lane] = acc[j][r];
  __syncthreads();
  if (wv==0){
    #pragma unroll
    for (int j=0;j<2;++j)
      #pragma unroll
      for (int r=0;r<4;++r){
        int p = lk*4 + r;
        if (p < np){
          float s = red[0][j][r][lane]+red[1][j][r][lane]+red[2][j][r][lane]+red[3][j][r][lane];
          u2[(size_t)(p0+p)*RR + j*16 + lr] = s;
        }
      }
  }
}

// ---------------- lora2 add ----------------
__global__ __launch_bounds__(256) void lora2_add(const int* __restrict__ tok2pair, const int* __restrict__ list_e,
    const float* __restrict__ rwn, const float* __restrict__ B2, const float* __restrict__ u2,
    float* __restrict__ out){
  int t = blockIdx.x;
  __shared__ float u2s[2][RR];
  __shared__ int es[2];
  __shared__ float wss[2];
  if (threadIdx.x < 64){
    int s = threadIdx.x>>5, r = threadIdx.x&31;
    int pair = tok2pair[t*2+s];
    u2s[s][r] = u2[(size_t)pair*RR + r];
    if (r==0){ es[s]=list_e[pair]; wss[s]=rwn[t*2+s]; }
  }
  __syncthreads();
  int e0=es[0], e1=es[1];
  float w0=wss[0], w1=wss[1];
  for (int h=threadIdx.x; h<H; h+=256){
    const float4* b0 = (const float4*)(B2 + ((size_t)e0*H + h)*RR);
    const float4* b1 = (const float4*)(B2 + ((size_t)e1*H + h)*RR);
    float d0=0.f, d1=0.f;
    #pragma unroll
    for (int c=0;c<RR/4;++c){
      float4 v0=b0[c]; d0 += v0.x*u2s[0][c*4+0] + v0.y*u2s[0][c*4+1] + v0.z*u2s[0][c*4+2] + v0.w*u2s[0][c*4+3];
      float4 v1=b1[c]; d1 += v1.x*u2s[1][c*4+0] + v1.y*u2s[1][c*4+1] + v1.z*u2s[1][c*4+2] + v1.w*u2s[1][c*4+3];
    }
    out[(size_t)t*H + h] += w0*d0 + w1*d1;
  }
}

extern "C" void kernel_launch(void* const* d_in, const int* in_sizes, int n_in,
                              void* d_out, int out_size, void* d_ws, size_t ws_size,
                              hipStream_t stream){
  const float* x   = (const float*)d_in[0];
  const float* gw  = (const float*)d_in[1];
  const float* W1  = (const float*)d_in[2];
  const float* W2  = (const float*)d_in[3];
  const float* W3  = (const float*)d_in[4];
  const float* A1  = (const float*)d_in[5];
  const float* B1  = (const float*)d_in[6];
  const float* A2  = (const float*)d_in[7];
  const float* B2  = (const float*)d_in[8];
  const float* A3  = (const float*)d_in[9];
  const float* B3  = (const float*)d_in[10];
  float* outF = (float*)d_out;
  float* outL = outF + (size_t)NT*H;

  char* base = (char*)d_ws;
  size_t o = 0;
  auto mk = [&](size_t bytes){ void* p = base + o; o += (bytes + 255) & ~(size_t)255; return p; };
  int*   sel      = (int*)  mk((size_t)NT*2*4);
  float* rwn      = (float*)mk((size_t)NT*2*4);
  int*   cnts     = (int*)  mk(512);
  int*   cnt      = cnts;
  int*   cnt2     = cnts + 64;
  int*   off      = (int*)  mk(256);
  int*   meta     = (int*)  mk((size_t)(1+3*MAXT)*4);
  int*   list_tok = (int*)  mk((size_t)NPAIRP*4);
  int*   list_e   = (int*)  mk((size_t)NPAIRP*4);
  int*   tok2pair = (int*)  mk((size_t)NT*2*4);
  ushort_t* xbf   = (ushort_t*)mk((size_t)NT*H*2);
  ushort_t* x1b   = (ushort_t*)mk((size_t)NT*F*2);
  ushort_t* x3b   = (ushort_t*)mk((size_t)NT*F*2);
  ushort_t* x2buf = (ushort_t*)mk((size_t)NPAIRP*F*2);
  ushort_t* x2c   = (ushort_t*)mk((size_t)NT*F*2);
  ushort_t* u1bf  = (ushort_t*)mk((size_t)NPAIRP*RR*2);
  ushort_t* u3bf  = (ushort_t*)mk((size_t)NPAIRP*RR*2);
  float* u2       = (float*)mk((size_t)NPAIRP*RR*4);
  ushort_t* b1bf  = (ushort_t*)mk((size_t)NE*F*RR*2);
  ushort_t* b3bf  = (ushort_t*)mk((size_t)NE*F*RR*2);
  float* part     = (float*)mk((size_t)4*NT*H*4);   // split-K partials (64 MB)
  bool useBF = (o <= ws_size);
  (void)in_sizes; (void)n_in; (void)out_size;

  hipMemsetAsync(cnts, 0, 512, stream);
  cast_x<<<(NT*H/4)/256, 256, 0, stream>>>(x, xbf);
  router_kernel<<<NT/4, 256, 0, stream>>>(x, gw, outL, sel, rwn, cnt);
  prefix_kernel<<<1, 1, 0, stream>>>(cnt, off, meta);
  scatter_kernel<<<(NPAIRP+255)/256, 256, 0, stream>>>(sel, off, cnt2, list_tok, list_e, tok2pair);

  if (useBF){
    cast_f2bf<<<512, 256, 0, stream>>>(B1, b1bf, (long)NE*F*RR/8);
    cast_f2bf<<<512, 256, 0, stream>>>(B3, b3bf, (long)NE*F*RR/8);
    // W1|W3 fused: M=1024, per-matrix N=F, GN=56, GNt=112, no split -> 4*112 = 448 blocks
    gemm_256<true><<<448, 512, 0, stream>>>(xbf, W1, W3, x1b, x3b,
                                            NT, F, F/256, 2*(F/256), H, H);
    lora_a_mfma<<<MAXT, 256, 0, stream>>>(meta, list_tok, xbf, A1, A3, u1bf, u3bf);
    expert_x2<ushort_t><<<dim3(MAXT, F/128), 256, 0, stream>>>(meta, list_tok, b1bf, b3bf, u1bf, u3bf, x1b, x3b, x2buf);
    combine_x2<<<(NT*(F/8))/256, 256, 0, stream>>>(tok2pair, rwn, x2buf, x2c);
    u2_mfma<<<MAXT, 256, 0, stream>>>(meta, A2, x2buf, u2);
    // W2 with split-K=4: M=1024, N=H, GN=GNt=16, Klen=F/4 -> 4*16*4 = 256 blocks
    gemm_256<false><<<256, 512, 0, stream>>>(x2c, W2, W2, part, part,
                                             NT, H, H/256, H/256, F/4, F);
    reduce4<<<(NT*H/4)/256, 256, 0, stream>>>(part, outF);
  } else {
    gemm_bt<128,true><<<dim3(NT/128, F/128), 256, 0, stream>>>(xbf, W1, x1b, NT, F, H);
    gemm_bt<128,true><<<dim3(NT/128, F/128), 256, 0, stream>>>(xbf, W3, x3b, NT, F, H);
    lora_a_mfma<<<MAXT, 256, 0, stream>>>(meta, list_tok, xbf, A1, A3, u1bf, u3bf);
    expert_x2<float><<<dim3(MAXT, F/128), 256, 0, stream>>>(meta, list_tok, B1, B3, u1bf, u3bf, x1b, x3b, x2buf);
    combine_x2<<<(NT*(F/8))/256, 256, 0, stream>>>(tok2pair, rwn, x2buf, x2c);
    u2_mfma<<<MAXT, 256, 0, stream>>>(meta, A2, x2buf, u2);
    gemm_bt<128,false><<<dim3(NT/128, H/128), 256, 0, stream>>>(x2c, W2, outF, NT, H, F);
  }
  lora2_add<<<NT, 256, 0, stream>>>(tok2pair, list_e, rwn, B2, u2, outF);
}

// Round 7
// 1027.414 us; speedup vs baseline: 2.1994x; 1.1653x over previous
//
#include <hip/hip_runtime.h>

#define H 4096
#define F 14336
#define NE 8
#define RR 32
#define NT 1024
#define MAXT 136
#define NPAIR 2048
#define NPAIRP 2064   // padded (tile overrun on last expert)

typedef unsigned short ushort_t;
typedef __attribute__((ext_vector_type(4))) float f32x4;
typedef __attribute__((ext_vector_type(8))) short short8v;
typedef __attribute__((ext_vector_type(8))) unsigned short ushort8;
typedef __attribute__((ext_vector_type(4))) unsigned short ushort4v;

__device__ inline unsigned short f2bf(float f){
  unsigned int x = __float_as_uint(f);
  return (unsigned short)((x + 0x7fffu + ((x>>16)&1u)) >> 16);
}
__device__ inline float bf2f(unsigned short u){
  return __uint_as_float(((unsigned int)u)<<16);
}
__device__ inline short8v cvt8(const float* p){
  float4 v0 = *(const float4*)p, v1 = *(const float4*)(p+4);
  short8v b;
  b[0]=(short)f2bf(v0.x); b[1]=(short)f2bf(v0.y); b[2]=(short)f2bf(v0.z); b[3]=(short)f2bf(v0.w);
  b[4]=(short)f2bf(v1.x); b[5]=(short)f2bf(v1.y); b[6]=(short)f2bf(v1.z); b[7]=(short)f2bf(v1.w);
  return b;
}
__device__ inline short8v load8w(const float* p){ return cvt8(p); }
__device__ inline short8v load8w(const ushort_t* p){ return *(const short8v*)p; }

__device__ inline void gload16(const void* g, void* l){
  __builtin_amdgcn_global_load_lds(
      (const __attribute__((address_space(1))) void*)g,
      (__attribute__((address_space(3))) void*)l, 16, 0, 0);
}

// ---------------- fp32 -> bf16 streaming cast ----------------
__global__ __launch_bounds__(256) void cast_f2bf(const float* __restrict__ src,
    ushort_t* __restrict__ dst, long n8){
  long stride = (long)gridDim.x*256;
  for (long i = (long)blockIdx.x*256 + threadIdx.x; i < n8; i += stride){
    const float4* p = (const float4*)(src + i*8);
    float4 v0 = p[0], v1 = p[1];
    ushort8 o;
    o[0]=f2bf(v0.x); o[1]=f2bf(v0.y); o[2]=f2bf(v0.z); o[3]=f2bf(v0.w);
    o[4]=f2bf(v1.x); o[5]=f2bf(v1.y); o[6]=f2bf(v1.z); o[7]=f2bf(v1.w);
    *(ushort8*)(dst + i*8) = o;
  }
}

// ---------------- router ----------------
__global__ __launch_bounds__(256) void router_kernel(const float* __restrict__ x,
    const float* __restrict__ gw, float* __restrict__ logits,
    int* __restrict__ sel, float* __restrict__ rwn, int* __restrict__ cnt){
  int t = blockIdx.x*4 + (threadIdx.x>>6);
  int lane = threadIdx.x & 63;
  const float4* xr = (const float4*)(x + (size_t)t*H);
  float s[NE];
  #pragma unroll
  for (int e=0;e<NE;++e) s[e]=0.f;
  for (int c=lane; c<H/4; c+=64){
    float4 xv = xr[c];
    #pragma unroll
    for (int e=0;e<NE;++e){
      float4 g = ((const float4*)(gw + (size_t)e*H))[c];
      s[e] += xv.x*g.x + xv.y*g.y + xv.z*g.z + xv.w*g.w;
    }
  }
  #pragma unroll
  for (int e=0;e<NE;++e){
    for (int off=32; off; off>>=1) s[e] += __shfl_down(s[e], off);
  }
  if (lane==0){
    float mx = s[0];
    #pragma unroll
    for (int e=1;e<NE;++e) mx = fmaxf(mx, s[e]);
    float p[NE]; float den=0.f;
    #pragma unroll
    for (int e=0;e<NE;++e){ p[e]=__expf(s[e]-mx); den+=p[e]; }
    int i0=0;
    #pragma unroll
    for (int e=1;e<NE;++e) if (p[e]>p[i0]) i0=e;
    int i1 = (i0==0)?1:0;
    #pragma unroll
    for (int e=0;e<NE;++e){ if (e!=i0 && p[e]>p[i1]) i1=e; }
    float p0=p[i0]/den, p1=p[i1]/den;
    float inv = 1.f/(p0+p1);
    #pragma unroll
    for (int e=0;e<NE;++e) logits[t*NE+e] = s[e];
    sel[t*2]=i0; sel[t*2+1]=i1;
    rwn[t*2]=p0*inv; rwn[t*2+1]=p1*inv;
    atomicAdd(&cnt[i0],1); atomicAdd(&cnt[i1],1);
  }
}

// ---------------- prefix + tile table ----------------
__global__ void prefix_kernel(const int* __restrict__ cnt, int* __restrict__ off, int* __restrict__ meta){
  if (threadIdx.x==0 && blockIdx.x==0){
    int o=0;
    for (int e=0;e<NE;++e){ off[e]=o; o+=cnt[e]; }
    off[NE]=o;
    int ntl=0;
    for (int e=0;e<NE;++e){
      int c=cnt[e], b=off[e];
      for (int ps=0; ps<c; ps+=16){
        meta[1+ntl] = e;
        meta[1+MAXT+ntl] = b+ps;
        meta[1+2*MAXT+ntl] = (c-ps<16)?(c-ps):16;
        ++ntl;
      }
    }
    meta[0]=ntl;
  }
}

// ---------------- scatter ----------------
__global__ void scatter_kernel(const int* __restrict__ sel, const int* __restrict__ off,
    int* __restrict__ cnt2, int* __restrict__ list_tok, int* __restrict__ list_e,
    int* __restrict__ tok2pair){
  int idx = blockIdx.x*256 + threadIdx.x;
  if (idx >= NT*2){
    if (idx < NPAIRP){ list_tok[idx]=0; list_e[idx]=0; }
    return;
  }
  int e = sel[idx];
  int pos = atomicAdd(&cnt2[e], 1);
  int pair = off[e] + pos;
  list_tok[pair] = idx>>1;
  list_e[pair] = e;
  tok2pair[idx] = pair;
}

// ---------------- cast hidden states to bf16 ----------------
__global__ __launch_bounds__(256) void cast_x(const float* __restrict__ x, ushort_t* __restrict__ xbf){
  size_t i = ((size_t)blockIdx.x*256 + threadIdx.x)*4;
  if (i >= (size_t)NT*H) return;
  float4 v = *(const float4*)(x+i);
  ushort4v o;
  o[0]=f2bf(v.x); o[1]=f2bf(v.y); o[2]=f2bf(v.z); o[3]=f2bf(v.w);
  *(ushort4v*)(xbf+i) = o;
}

// ---------------- 256x256 MFMA GEMM, 8 waves, BK=64, 2-phase dbuf, LDS XOR-swizzle ----------------
// Both A and B bf16 via global_load_lds with PRE-SWIZZLED global source (rule #21:
// linear LDS dest + inverse-swizzled source + same XOR on ds_read). row&7 == lane>>3
// for every staged row (rows advance by 8 per chunk), so src granule = (lane&7)^(lane>>3).
// Reads: granule (ks*4+lk) ^ (row&7) -> 8 lanes per bank-group = conflict-free minimum.
template<bool OUTBF>
__global__ __launch_bounds__(512) void gemm_256(const ushort_t* __restrict__ A,
    const ushort_t* __restrict__ Bw0, const ushort_t* __restrict__ Bw1,
    void* __restrict__ C0, void* __restrict__ C1,
    int M, int N, int GN, int GNt, int Klen, int Kfull){
  constexpr int BM=256, BN=256, BK=64;
  __shared__ ushort_t As[2][BM*BK];   // 2 x 32 KB
  __shared__ ushort_t Bs[2][BN*BK];   // 2 x 32 KB  -> 128 KB total
  const int tid = threadIdx.x;
  const int w = tid>>6, lane = tid&63;
  const int wr = w>>2, wc = w&3;
  const int lr = lane&15, lk = lane>>4;
  const int GM = M/BM;
  // bijective XCD swizzle (m204 form)
  const int T = gridDim.x;
  const int q8 = T>>3, r8 = T&7;
  const int xcd = blockIdx.x & 7, oo = blockIdx.x>>3;
  const int id2 = (xcd < r8 ? xcd*(q8+1) : r8*(q8+1) + (xcd-r8)*q8) + oo;
  const int m  = id2 % GM;
  const int sn = id2 / GM;
  const int n2 = sn % GNt;
  const int s  = sn / GNt;
  const int bm = m*BM;
  const int mat = (n2 >= GN) ? 1 : 0;
  const int ncb = (n2 - mat*GN)*BN;
  const ushort_t* Bw = mat ? Bw1 : Bw0;
  const int koff = s*Klen;

  f32x4 acc[8][4];
  #pragma unroll
  for (int i=0;i<8;++i)
    #pragma unroll
    for (int j=0;j<4;++j) acc[i][j]=(f32x4){0.f,0.f,0.f,0.f};

  // staging: wave w covers rows [w*32, w*32+32) in chunks of 8 rows; lane -> (row, granule)
  const int srow = w*32 + (lane>>3);
  const int sg   = ((lane&7) ^ (lane>>3))*8;          // pre-swizzled source granule (ushort off)
  const ushort_t* gA = A  + (size_t)(bm  + srow)*Kfull + koff + sg;
  const ushort_t* gB = Bw + (size_t)(ncb + srow)*Kfull + koff + sg;
  const int dL = w*2048 + lane*8;                      // linear LDS dest (ushort idx)

  auto STAGE = [&](int buf, int k0){
    #pragma unroll
    for (int q=0;q<4;++q){
      gload16(gA + (size_t)q*8*Kfull + k0, &As[buf][dL + q*512]);
      gload16(gB + (size_t)q*8*Kfull + k0, &Bs[buf][dL + q*512]);
    }
  };

  const int nt = Klen/BK;
  STAGE(0,0);
  __syncthreads();
  int cur = 0;
  for (int t=0; t<nt; ++t){
    if (t+1 < nt) STAGE(cur^1, (t+1)*BK);   // issue early; lands under MFMA, waited by barrier
    const ushort_t* as = &As[cur][0];
    const ushort_t* bs = &Bs[cur][0];
    #pragma unroll
    for (int ks=0; ks<2; ++ks){
      short8v af[8], bfv[4];
      #pragma unroll
      for (int mi=0;mi<8;++mi){
        int ra = wr*128 + mi*16 + lr;
        af[mi]  = *(const short8v*)&as[ra*64 + (((ks*4+lk) ^ (lr&7))*8)];
      }
      #pragma unroll
      for (int ni=0;ni<4;++ni){
        int rb = wc*64 + ni*16 + lr;
        bfv[ni] = *(const short8v*)&bs[rb*64 + (((ks*4+lk) ^ (lr&7))*8)];
      }
      #pragma unroll
      for (int mi=0;mi<8;++mi)
        #pragma unroll
        for (int ni=0;ni<4;++ni)
          acc[mi][ni] = __builtin_amdgcn_mfma_f32_16x16x32_bf16(af[mi], bfv[ni], acc[mi][ni], 0,0,0);
    }
    __syncthreads();                 // drains vmcnt(0)+lgkmcnt(0): next tile ready
    cur ^= 1;
  }
  // epilogue
  const int rowb = bm + wr*128 + lk*4;
  const int colb = ncb + wc*64 + lr;
  if (OUTBF){
    ushort_t* C = (ushort_t*)(mat ? C1 : C0);
    #pragma unroll
    for (int mi=0;mi<8;++mi)
      #pragma unroll
      for (int ni=0;ni<4;++ni)
        #pragma unroll
        for (int rr2=0;rr2<4;++rr2)
          C[(size_t)(rowb+mi*16+rr2)*N + colb + ni*16] = f2bf(acc[mi][ni][rr2]);
  } else {
    float* C = (float*)C0 + (size_t)s*M*N;
    #pragma unroll
    for (int mi=0;mi<8;++mi)
      #pragma unroll
      for (int ni=0;ni<4;++ni)
        #pragma unroll
        for (int rr2=0;rr2<4;++rr2)
          C[(size_t)(rowb+mi*16+rr2)*N + colb + ni*16] = acc[mi][ni][rr2];
  }
}

// ---------------- split-K reduce: out = sum of 4 partials ----------------
__global__ __launch_bounds__(256) void reduce4(const float* __restrict__ part, float* __restrict__ out){
  size_t i = ((size_t)blockIdx.x*256 + threadIdx.x)*4;
  if (i >= (size_t)NT*H) return;
  const size_t S = (size_t)NT*H;
  float4 a = *(const float4*)(part+i);
  float4 b = *(const float4*)(part+S+i);
  float4 c = *(const float4*)(part+2*S+i);
  float4 d = *(const float4*)(part+3*S+i);
  float4 o;
  o.x = a.x+b.x+c.x+d.x; o.y = a.y+b.y+c.y+d.y;
  o.z = a.z+b.z+c.z+d.z; o.w = a.w+b.w+c.w+d.w;
  *(float4*)(out+i) = o;
}

// ---------------- fallback fp32-B fused-cvt GEMM ----------------
template<int BN, bool OUTBF>
__global__ __launch_bounds__(256) void gemm_bt(const ushort_t* __restrict__ A,
    const float* __restrict__ Bw, void* __restrict__ Cout, int M, int N, int K){
  constexpr int BM=128, BK=32, LD=40;
  __shared__ ushort_t As[BM*LD];
  __shared__ ushort_t Bs[BN*LD];
  const int tid = threadIdx.x;
  const int bm = blockIdx.x*BM, bn = blockIdx.y*BN;
  const int wv = tid>>6, lane = tid&63;
  const int wm = (wv>>1)*64, wn = (wv&1)*(BN/2);
  const int lr = lane&15, lk = lane>>4;
  constexpr int NJ = BN/32;
  f32x4 acc[4][NJ];
  #pragma unroll
  for (int i=0;i<4;++i)
    #pragma unroll
    for (int j=0;j<NJ;++j) acc[i][j] = (f32x4){0.f,0.f,0.f,0.f};
  const int arow = tid>>1, ak=(tid&1)*16;
  constexpr int BPT = BN*BK/256;
  const int brow = (BN==128)?(tid>>1):(tid>>2);
  const int bk   = (BN==128)?((tid&1)*16):((tid&3)*8);
  const ushort_t* gA = A + (size_t)(bm+arow)*K + ak;
  const float*    gB = Bw + (size_t)(bn+brow)*K + bk;
  for (int k0=0;k0<K;k0+=BK){
    ushort8 a0 = *(const ushort8*)(gA + k0);
    ushort8 a1 = *(const ushort8*)(gA + k0 + 8);
    float vals[BPT];
    #pragma unroll
    for (int i=0;i<BPT;i+=4){
      float4 v = *(const float4*)(gB + k0 + i);
      vals[i]=v.x; vals[i+1]=v.y; vals[i+2]=v.z; vals[i+3]=v.w;
    }
    *(ushort8*)&As[arow*LD+ak]   = a0;
    *(ushort8*)&As[arow*LD+ak+8] = a1;
    #pragma unroll
    for (int i=0;i<BPT;i+=8){
      ushort8 u;
      #pragma unroll
      for (int q=0;q<8;++q) u[q]=f2bf(vals[i+q]);
      *(ushort8*)&Bs[brow*LD+bk+i] = u;
    }
    __syncthreads();
    short8v af[4], bfv[NJ];
    #pragma unroll
    for (int i=0;i<4;++i) af[i] = *(const short8v*)&As[(wm+i*16+lr)*LD + lk*8];
    #pragma unroll
    for (int j=0;j<NJ;++j) bfv[j] = *(const short8v*)&Bs[(wn+j*16+lr)*LD + lk*8];
    #pragma unroll
    for (int i=0;i<4;++i)
      #pragma unroll
      for (int j=0;j<NJ;++j)
        acc[i][j] = __builtin_amdgcn_mfma_f32_16x16x32_bf16(af[i], bfv[j], acc[i][j], 0,0,0);
    __syncthreads();
  }
  #pragma unroll
  for (int i=0;i<4;++i)
    #pragma unroll
    for (int j=0;j<NJ;++j)
      #pragma unroll
      for (int r=0;r<4;++r){
        int row = bm + wm + i*16 + lk*4 + r;
        int col = bn + wn + j*16 + lr;
        if (OUTBF) ((ushort_t*)Cout)[(size_t)row*N + col] = f2bf(acc[i][j][r]);
        else       ((float*)Cout)[(size_t)row*N + col]    = acc[i][j][r];
      }
}

// ---------------- LoRA A projections via MFMA ----------------
__global__ __launch_bounds__(256) void lora_a_mfma(const int* __restrict__ meta,
    const int* __restrict__ list_tok, const ushort_t* __restrict__ xbf,
    const float* __restrict__ A1, const float* __restrict__ A3,
    ushort_t* __restrict__ u1bf, ushort_t* __restrict__ u3bf){
  int ti = blockIdx.x;
  if (ti >= meta[0]) return;
  int e  = meta[1+ti];
  int p0 = meta[1+MAXT+ti];
  int np = meta[1+2*MAXT+ti];
  int wv = threadIdx.x>>6, lane = threadIdx.x&63;
  int lr = lane&15, lk = lane>>4;
  int t = list_tok[p0+lr];
  const ushort_t* xrow = xbf + (size_t)t*H;
  const int kbase = wv*(H/4);
  f32x4 acc1[2], acc3[2];
  #pragma unroll
  for (int j=0;j<2;++j){ acc1[j]=(f32x4){0,0,0,0}; acc3[j]=(f32x4){0,0,0,0}; }
  for (int ks=0; ks<H/4; ks+=32){
    int k = kbase + ks + lk*8;
    short8v a = *(const short8v*)(xrow + k);
    #pragma unroll
    for (int j=0;j<2;++j){
      const float* b1 = A1 + ((size_t)e*RR + j*16 + lr)*H + k;
      const float* b3 = A3 + ((size_t)e*RR + j*16 + lr)*H + k;
      acc1[j] = __builtin_amdgcn_mfma_f32_16x16x32_bf16(a, cvt8(b1), acc1[j], 0,0,0);
      acc3[j] = __builtin_amdgcn_mfma_f32_16x16x32_bf16(a, cvt8(b3), acc3[j], 0,0,0);
    }
  }
  __shared__ float red[4][2][2][4][64];
  #pragma unroll
  for (int j=0;j<2;++j)
    #pragma unroll
    for (int r=0;r<4;++r){
      red[wv][0][j][r][lane] = acc1[j][r];
      red[wv][1][j][r][lane] = acc3[j][r];
    }
  __syncthreads();
  if (wv==0){
    #pragma unroll
    for (int j=0;j<2;++j)
      #pragma unroll
      for (int r=0;r<4;++r){
        int p = lk*4 + r;
        if (p < np){
          float s1 = red[0][0][j][r][lane]+red[1][0][j][r][lane]+red[2][0][j][r][lane]+red[3][0][j][r][lane];
          float s3 = red[0][1][j][r][lane]+red[1][1][j][r][lane]+red[2][1][j][r][lane]+red[3][1][j][r][lane];
          u1bf[(size_t)(p0+p)*RR + j*16 + lr] = f2bf(s1);
          u3bf[(size_t)(p0+p)*RR + j*16 + lr] = f2bf(s3);
        }
      }
  }
}

// ---------------- per-expert fused: d1/d3 via MFMA, silu, x2 ----------------
template<typename WT>
__global__ __launch_bounds__(256) void expert_x2(const int* __restrict__ meta, const int* __restrict__ list_tok,
    const WT* __restrict__ B1g, const WT* __restrict__ B3g,
    const ushort_t* __restrict__ u1bf, const ushort_t* __restrict__ u3bf,
    const ushort_t* __restrict__ x1b, const ushort_t* __restrict__ x3b,
    ushort_t* __restrict__ x2buf){
  int ti = blockIdx.x;
  if (ti >= meta[0]) return;
  int e  = meta[1+ti];
  int p0 = meta[1+MAXT+ti];
  int np = meta[1+2*MAXT+ti];
  int fc = blockIdx.y*128 + (threadIdx.x>>6)*32;
  int lane = threadIdx.x&63;
  int lr = lane&15, lk = lane>>4;
  short8v au1 = *(const short8v*)(u1bf + (size_t)(p0+lr)*RR + lk*8);
  short8v au3 = *(const short8v*)(u3bf + (size_t)(p0+lr)*RR + lk*8);
  f32x4 z = (f32x4){0.f,0.f,0.f,0.f};
  f32x4 acc1[2], acc3[2];
  #pragma unroll
  for (int j=0;j<2;++j){
    acc1[j]=z; acc3[j]=z;
    int f = fc + j*16 + lr;
    const WT* b1r = B1g + ((size_t)e*F + f)*RR + lk*8;
    const WT* b3r = B3g + ((size_t)e*F + f)*RR + lk*8;
    acc1[j] = __builtin_amdgcn_mfma_f32_16x16x32_bf16(au1, load8w(b1r), acc1[j], 0,0,0);
    acc3[j] = __builtin_amdgcn_mfma_f32_16x16x32_bf16(au3, load8w(b3r), acc3[j], 0,0,0);
  }
  #pragma unroll
  for (int r=0;r<4;++r){
    int p = lk*4 + r;
    if (p < np){
      int t = list_tok[p0+p];
      #pragma unroll
      for (int j=0;j<2;++j){
        int f = fc + j*16 + lr;
        size_t ix = (size_t)t*F + f;
        float x1  = bf2f(x1b[ix]) + acc1[j][r];
        float x3v = bf2f(x3b[ix]) + acc3[j][r];
        float sl = x1/(1.f + __expf(-x1));
        x2buf[(size_t)(p0+p)*F + f] = f2bf(sl*x3v);
      }
    }
  }
}

// ---------------- combine ----------------
__global__ __launch_bounds__(256) void combine_x2(const int* __restrict__ tok2pair, const float* __restrict__ rwn,
    const ushort_t* __restrict__ x2buf, ushort_t* __restrict__ x2c){
  size_t i = (size_t)blockIdx.x*256 + threadIdx.x;
  size_t total = (size_t)NT*(F/8);
  if (i>=total) return;
  int t = (int)(i/(F/8));
  int c = (int)(i%(F/8))*8;
  int pa = tok2pair[t*2], pb = tok2pair[t*2+1];
  float wa = rwn[t*2], wb = rwn[t*2+1];
  ushort8 va = *(const ushort8*)(x2buf + (size_t)pa*F + c);
  ushort8 vb = *(const ushort8*)(x2buf + (size_t)pb*F + c);
  ushort8 o;
  #pragma unroll
  for (int q=0;q<8;++q) o[q] = f2bf(wa*bf2f(va[q]) + wb*bf2f(vb[q]));
  *(ushort8*)(x2c + (size_t)t*F + c) = o;
}

// ---------------- u2 = A2[e] @ x2 via MFMA ----------------
__global__ __launch_bounds__(256) void u2_mfma(const int* __restrict__ meta,
    const float* __restrict__ A2, const ushort_t* __restrict__ x2buf, float* __restrict__ u2){
  int ti = blockIdx.x;
  if (ti >= meta[0]) return;
  int e  = meta[1+ti];
  int p0 = meta[1+MAXT+ti];
  int np = meta[1+2*MAXT+ti];
  int wv = threadIdx.x>>6, lane = threadIdx.x&63;
  int lr = lane&15, lk = lane>>4;
  const ushort_t* xrow = x2buf + (size_t)(p0+lr)*F;
  const int kbase = wv*(F/4);
  f32x4 acc[2];
  acc[0]=(f32x4){0,0,0,0}; acc[1]=(f32x4){0,0,0,0};
  for (int ks=0; ks<F/4; ks+=32){
    int k = kbase + ks + lk*8;
    short8v a = *(const short8v*)(xrow + k);
    #pragma unroll
    for (int j=0;j<2;++j){
      const float* br = A2 + ((size_t)e*RR + j*16 + lr)*F + k;
      acc[j] = __builtin_amdgcn_mfma_f32_16x16x32_bf16(a, cvt8(br), acc[j], 0,0,0);
    }
  }
  __shared__ float red[4][2][4][64];
  #pragma unroll
  for (int j=0;j<2;++j)
    #pragma unroll
    for (int r=0;r<4;++r) red[wv][j][r][lane] = acc[j][r];
  __syncthreads();
  if (wv==0){
    #pragma unroll
    for (int j=0;j<2;++j)
      #pragma unroll
      for (int r=0;r<4;++r){
        int p = lk*4 + r;
        if (p < np){
          float s = red[0][j][r][lane]+red[1][j][r][lane]+red[2][j][r][lane]+red[3][j][r][lane];
          u2[(size_t)(p0+p)*RR + j*16 + lr] = s;
        }
      }
  }
}

// ---------------- lora2 add ----------------
__global__ __launch_bounds__(256) void lora2_add(const int* __restrict__ tok2pair, const int* __restrict__ list_e,
    const float* __restrict__ rwn, const float* __restrict__ B2, const float* __restrict__ u2,
    float* __restrict__ out){
  int t = blockIdx.x;
  __shared__ float u2s[2][RR];
  __shared__ int es[2];
  __shared__ float wss[2];
  if (threadIdx.x < 64){
    int s = threadIdx.x>>5, r = threadIdx.x&31;
    int pair = tok2pair[t*2+s];
    u2s[s][r] = u2[(size_t)pair*RR + r];
    if (r==0){ es[s]=list_e[pair]; wss[s]=rwn[t*2+s]; }
  }
  __syncthreads();
  int e0=es[0], e1=es[1];
  float w0=wss[0], w1=wss[1];
  for (int h=threadIdx.x; h<H; h+=256){
    const float4* b0 = (const float4*)(B2 + ((size_t)e0*H + h)*RR);
    const float4* b1 = (const float4*)(B2 + ((size_t)e1*H + h)*RR);
    float d0=0.f, d1=0.f;
    #pragma unroll
    for (int c=0;c<RR/4;++c){
      float4 v0=b0[c]; d0 += v0.x*u2s[0][c*4+0] + v0.y*u2s[0][c*4+1] + v0.z*u2s[0][c*4+2] + v0.w*u2s[0][c*4+3];
      float4 v1=b1[c]; d1 += v1.x*u2s[1][c*4+0] + v1.y*u2s[1][c*4+1] + v1.z*u2s[1][c*4+2] + v1.w*u2s[1][c*4+3];
    }
    out[(size_t)t*H + h] += w0*d0 + w1*d1;
  }
}

extern "C" void kernel_launch(void* const* d_in, const int* in_sizes, int n_in,
                              void* d_out, int out_size, void* d_ws, size_t ws_size,
                              hipStream_t stream){
  const float* x   = (const float*)d_in[0];
  const float* gw  = (const float*)d_in[1];
  const float* W1  = (const float*)d_in[2];
  const float* W2  = (const float*)d_in[3];
  const float* W3  = (const float*)d_in[4];
  const float* A1  = (const float*)d_in[5];
  const float* B1  = (const float*)d_in[6];
  const float* A2  = (const float*)d_in[7];
  const float* B2  = (const float*)d_in[8];
  const float* A3  = (const float*)d_in[9];
  const float* B3  = (const float*)d_in[10];
  float* outF = (float*)d_out;
  float* outL = outF + (size_t)NT*H;

  char* base = (char*)d_ws;
  size_t o = 0;
  auto mk = [&](size_t bytes){ void* p = base + o; o += (bytes + 255) & ~(size_t)255; return p; };
  int*   sel      = (int*)  mk((size_t)NT*2*4);
  float* rwn      = (float*)mk((size_t)NT*2*4);
  int*   cnts     = (int*)  mk(512);
  int*   cnt      = cnts;
  int*   cnt2     = cnts + 64;
  int*   off      = (int*)  mk(256);
  int*   meta     = (int*)  mk((size_t)(1+3*MAXT)*4);
  int*   list_tok = (int*)  mk((size_t)NPAIRP*4);
  int*   list_e   = (int*)  mk((size_t)NPAIRP*4);
  int*   tok2pair = (int*)  mk((size_t)NT*2*4);
  ushort_t* xbf   = (ushort_t*)mk((size_t)NT*H*2);
  ushort_t* x1b   = (ushort_t*)mk((size_t)NT*F*2);
  ushort_t* x3b   = (ushort_t*)mk((size_t)NT*F*2);
  ushort_t* x2buf = (ushort_t*)mk((size_t)NPAIRP*F*2);
  ushort_t* x2c   = (ushort_t*)mk((size_t)NT*F*2);
  ushort_t* u1bf  = (ushort_t*)mk((size_t)NPAIRP*RR*2);
  ushort_t* u3bf  = (ushort_t*)mk((size_t)NPAIRP*RR*2);
  float* u2       = (float*)mk((size_t)NPAIRP*RR*4);
  // bf16 weight copies (used only if ws is large enough)
  ushort_t* w1bf = (ushort_t*)mk((size_t)F*H*2);
  ushort_t* w3bf = (ushort_t*)mk((size_t)F*H*2);
  ushort_t* w2bf = (ushort_t*)mk((size_t)H*F*2);
  ushort_t* b1bf = (ushort_t*)mk((size_t)NE*F*RR*2);
  ushort_t* b3bf = (ushort_t*)mk((size_t)NE*F*RR*2);
  // split-K partials alias w1bf (64 MB <= 114 MB): w1bf is dead once the fused
  // W1|W3 GEMM completes, and the W2 GEMM is stream-ordered after it.
  float* part = (float*)w1bf;
  bool useBF = (o <= ws_size);
  (void)in_sizes; (void)n_in; (void)out_size;

  hipMemsetAsync(cnts, 0, 512, stream);
  cast_x<<<(NT*H/4)/256, 256, 0, stream>>>(x, xbf);
  router_kernel<<<NT/4, 256, 0, stream>>>(x, gw, outL, sel, rwn, cnt);
  prefix_kernel<<<1, 1, 0, stream>>>(cnt, off, meta);
  scatter_kernel<<<(NPAIRP+255)/256, 256, 0, stream>>>(sel, off, cnt2, list_tok, list_e, tok2pair);

  if (useBF){
    cast_f2bf<<<2048, 256, 0, stream>>>(W1, w1bf, (long)F*H/8);
    cast_f2bf<<<2048, 256, 0, stream>>>(W3, w3bf, (long)F*H/8);
    cast_f2bf<<<2048, 256, 0, stream>>>(W2, w2bf, (long)H*F/8);
    cast_f2bf<<<512, 256, 0, stream>>>(B1, b1bf, (long)NE*F*RR/8);
    cast_f2bf<<<512, 256, 0, stream>>>(B3, b3bf, (long)NE*F*RR/8);
    // W1|W3 fused: M=1024, per-matrix N=F, GN=56, GNt=112 -> 4*112 = 448 blocks
    gemm_256<true><<<448, 512, 0, stream>>>(xbf, w1bf, w3bf, x1b, x3b,
                                            NT, F, F/256, 2*(F/256), H, H);
    lora_a_mfma<<<MAXT, 256, 0, stream>>>(meta, list_tok, xbf, A1, A3, u1bf, u3bf);
    expert_x2<ushort_t><<<dim3(MAXT, F/128), 256, 0, stream>>>(meta, list_tok, b1bf, b3bf, u1bf, u3bf, x1b, x3b, x2buf);
    combine_x2<<<(NT*(F/8))/256, 256, 0, stream>>>(tok2pair, rwn, x2buf, x2c);
    u2_mfma<<<MAXT, 256, 0, stream>>>(meta, A2, x2buf, u2);
    // W2 with split-K=4: M=1024, N=H, GN=GNt=16, Klen=F/4 -> 4*16*4 = 256 blocks
    gemm_256<false><<<256, 512, 0, stream>>>(x2c, w2bf, w2bf, part, part,
                                             NT, H, H/256, H/256, F/4, F);
    reduce4<<<(NT*H/4)/256, 256, 0, stream>>>(part, outF);
  } else {
    gemm_bt<128,true><<<dim3(NT/128, F/128), 256, 0, stream>>>(xbf, W1, x1b, NT, F, H);
    gemm_bt<128,true><<<dim3(NT/128, F/128), 256, 0, stream>>>(xbf, W3, x3b, NT, F, H);
    lora_a_mfma<<<MAXT, 256, 0, stream>>>(meta, list_tok, xbf, A1, A3, u1bf, u3bf);
    expert_x2<float><<<dim3(MAXT, F/128), 256, 0, stream>>>(meta, list_tok, B1, B3, u1bf, u3bf, x1b, x3b, x2buf);
    combine_x2<<<(NT*(F/8))/256, 256, 0, stream>>>(tok2pair, rwn, x2buf, x2c);
    u2_mfma<<<MAXT, 256, 0, stream>>>(meta, A2, x2buf, u2);
    gemm_bt<128,false><<<dim3(NT/128, H/128), 256, 0, stream>>>(x2c, W2, outF, NT, H, F);
  }
  lora2_add<<<NT, 256, 0, stream>>>(tok2pair, list_e, rwn, B2, u2, outF);
}

// Round 8
// 1011.017 us; speedup vs baseline: 2.2350x; 1.0162x over previous
//
#include <hip/hip_runtime.h>

#define H 4096
#define F 14336
#define NE 8
#define RR 32
#define NT 1024
#define MAXT 136
#define NPAIR 2048
#define NPAIRP 2064   // padded (tile overrun on last expert)

typedef unsigned short ushort_t;
typedef __attribute__((ext_vector_type(4))) float f32x4;
typedef __attribute__((ext_vector_type(8))) short short8v;
typedef __attribute__((ext_vector_type(8))) unsigned short ushort8;
typedef __attribute__((ext_vector_type(4))) unsigned short ushort4v;

__device__ inline unsigned short f2bf(float f){
  unsigned int x = __float_as_uint(f);
  return (unsigned short)((x + 0x7fffu + ((x>>16)&1u)) >> 16);
}
__device__ inline float bf2f(unsigned short u){
  return __uint_as_float(((unsigned int)u)<<16);
}
__device__ inline short8v cvt8(const float* p){
  float4 v0 = *(const float4*)p, v1 = *(const float4*)(p+4);
  short8v b;
  b[0]=(short)f2bf(v0.x); b[1]=(short)f2bf(v0.y); b[2]=(short)f2bf(v0.z); b[3]=(short)f2bf(v0.w);
  b[4]=(short)f2bf(v1.x); b[5]=(short)f2bf(v1.y); b[6]=(short)f2bf(v1.z); b[7]=(short)f2bf(v1.w);
  return b;
}
__device__ inline short8v load8w(const float* p){ return cvt8(p); }
__device__ inline short8v load8w(const ushort_t* p){ return *(const short8v*)p; }

__device__ inline void gload16(const void* g, void* l){
  __builtin_amdgcn_global_load_lds(
      (const __attribute__((address_space(1))) void*)g,
      (__attribute__((address_space(3))) void*)l, 16, 0, 0);
}

// ---------------- fp32 -> bf16 streaming cast ----------------
__global__ __launch_bounds__(256) void cast_f2bf(const float* __restrict__ src,
    ushort_t* __restrict__ dst, long n8){
  long stride = (long)gridDim.x*256;
  for (long i = (long)blockIdx.x*256 + threadIdx.x; i < n8; i += stride){
    const float4* p = (const float4*)(src + i*8);
    float4 v0 = p[0], v1 = p[1];
    ushort8 o;
    o[0]=f2bf(v0.x); o[1]=f2bf(v0.y); o[2]=f2bf(v0.z); o[3]=f2bf(v0.w);
    o[4]=f2bf(v1.x); o[5]=f2bf(v1.y); o[6]=f2bf(v1.z); o[7]=f2bf(v1.w);
    *(ushort8*)(dst + i*8) = o;
  }
}

// ---------------- router ----------------
__global__ __launch_bounds__(256) void router_kernel(const float* __restrict__ x,
    const float* __restrict__ gw, float* __restrict__ logits,
    int* __restrict__ sel, float* __restrict__ rwn, int* __restrict__ cnt){
  int t = blockIdx.x*4 + (threadIdx.x>>6);
  int lane = threadIdx.x & 63;
  const float4* xr = (const float4*)(x + (size_t)t*H);
  float s[NE];
  #pragma unroll
  for (int e=0;e<NE;++e) s[e]=0.f;
  for (int c=lane; c<H/4; c+=64){
    float4 xv = xr[c];
    #pragma unroll
    for (int e=0;e<NE;++e){
      float4 g = ((const float4*)(gw + (size_t)e*H))[c];
      s[e] += xv.x*g.x + xv.y*g.y + xv.z*g.z + xv.w*g.w;
    }
  }
  #pragma unroll
  for (int e=0;e<NE;++e){
    for (int off=32; off; off>>=1) s[e] += __shfl_down(s[e], off);
  }
  if (lane==0){
    float mx = s[0];
    #pragma unroll
    for (int e=1;e<NE;++e) mx = fmaxf(mx, s[e]);
    float p[NE]; float den=0.f;
    #pragma unroll
    for (int e=0;e<NE;++e){ p[e]=__expf(s[e]-mx); den+=p[e]; }
    int i0=0;
    #pragma unroll
    for (int e=1;e<NE;++e) if (p[e]>p[i0]) i0=e;
    int i1 = (i0==0)?1:0;
    #pragma unroll
    for (int e=0;e<NE;++e){ if (e!=i0 && p[e]>p[i1]) i1=e; }
    float p0=p[i0]/den, p1=p[i1]/den;
    float inv = 1.f/(p0+p1);
    #pragma unroll
    for (int e=0;e<NE;++e) logits[t*NE+e] = s[e];
    sel[t*2]=i0; sel[t*2+1]=i1;
    rwn[t*2]=p0*inv; rwn[t*2+1]=p1*inv;
    atomicAdd(&cnt[i0],1); atomicAdd(&cnt[i1],1);
  }
}

// ---------------- prefix + tile table ----------------
__global__ void prefix_kernel(const int* __restrict__ cnt, int* __restrict__ off, int* __restrict__ meta){
  if (threadIdx.x==0 && blockIdx.x==0){
    int o=0;
    for (int e=0;e<NE;++e){ off[e]=o; o+=cnt[e]; }
    off[NE]=o;
    int ntl=0;
    for (int e=0;e<NE;++e){
      int c=cnt[e], b=off[e];
      for (int ps=0; ps<c; ps+=16){
        meta[1+ntl] = e;
        meta[1+MAXT+ntl] = b+ps;
        meta[1+2*MAXT+ntl] = (c-ps<16)?(c-ps):16;
        ++ntl;
      }
    }
    meta[0]=ntl;
  }
}

// ---------------- scatter ----------------
__global__ void scatter_kernel(const int* __restrict__ sel, const int* __restrict__ off,
    int* __restrict__ cnt2, int* __restrict__ list_tok, int* __restrict__ list_e,
    int* __restrict__ tok2pair){
  int idx = blockIdx.x*256 + threadIdx.x;
  if (idx >= NT*2){
    if (idx < NPAIRP){ list_tok[idx]=0; list_e[idx]=0; }
    return;
  }
  int e = sel[idx];
  int pos = atomicAdd(&cnt2[e], 1);
  int pair = off[e] + pos;
  list_tok[pair] = idx>>1;
  list_e[pair] = e;
  tok2pair[idx] = pair;
}

// ---------------- cast hidden states to bf16 ----------------
__global__ __launch_bounds__(256) void cast_x(const float* __restrict__ x, ushort_t* __restrict__ xbf){
  size_t i = ((size_t)blockIdx.x*256 + threadIdx.x)*4;
  if (i >= (size_t)NT*H) return;
  float4 v = *(const float4*)(x+i);
  ushort4v o;
  o[0]=f2bf(v.x); o[1]=f2bf(v.y); o[2]=f2bf(v.z); o[3]=f2bf(v.w);
  *(ushort4v*)(xbf+i) = o;
}

// ---------------- 256x256 MFMA GEMM, 8 waves, BK=64, 8-phase counted-vmcnt pipeline ----------------
// Conflict-free LDS via pre-swizzled global source (rule #21). K-loop: 4 phases per
// K-tile (quadrants ks x mi-half, 16 MFMA each); each phase {ds_read subtile || issue 2
// next-tile gloads -> lgkmcnt(0) -> setprio(1) MFMA setprio(0) -> barrier}. vmcnt(2)
// counted at phase 0 (never 0 mid-loop): next tile's first loads fly across the barrier.
template<bool OUTBF>
__global__ __launch_bounds__(512) void gemm_256(const ushort_t* __restrict__ A,
    const ushort_t* __restrict__ Bw0, const ushort_t* __restrict__ Bw1,
    void* __restrict__ C0, void* __restrict__ C1,
    int M, int N, int GN, int GNt, int Klen, int Kfull){
  constexpr int BM=256, BN=256, BK=64;
  __shared__ ushort_t As[2][BM*BK];   // 2 x 32 KB
  __shared__ ushort_t Bs[2][BN*BK];   // 2 x 32 KB  -> 128 KB total
  const int tid = threadIdx.x;
  const int w = tid>>6, lane = tid&63;
  const int wr = w>>2, wc = w&3;
  const int lr = lane&15, lk = lane>>4;
  const int GM = M/BM;
  // bijective XCD swizzle (m204 form)
  const int T = gridDim.x;
  const int q8 = T>>3, r8 = T&7;
  const int xcd = blockIdx.x & 7, oo = blockIdx.x>>3;
  const int id2 = (xcd < r8 ? xcd*(q8+1) : r8*(q8+1) + (xcd-r8)*q8) + oo;
  const int m  = id2 % GM;
  const int sn = id2 / GM;
  const int n2 = sn % GNt;
  const int s  = sn / GNt;
  const int bm = m*BM;
  const int mat = (n2 >= GN) ? 1 : 0;
  const int ncb = (n2 - mat*GN)*BN;
  const ushort_t* Bw = mat ? Bw1 : Bw0;
  const int koff = s*Klen;

  f32x4 acc[8][4];
  #pragma unroll
  for (int i=0;i<8;++i)
    #pragma unroll
    for (int j=0;j<4;++j) acc[i][j]=(f32x4){0.f,0.f,0.f,0.f};

  // staging: wave w covers rows [w*32, w*32+32) in chunks of 8 rows; lane -> (row, granule)
  const int srow = w*32 + (lane>>3);
  const int sg   = ((lane&7) ^ (lane>>3))*8;          // pre-swizzled source granule (ushort off)
  const ushort_t* gA = A  + (size_t)(bm  + srow)*Kfull + koff + sg;
  const ushort_t* gB = Bw + (size_t)(ncb + srow)*Kfull + koff + sg;
  const int dL = w*2048 + lane*8;                      // linear LDS dest (ushort idx)

  auto SA2 = [&](int buf, int k0, int q0){             // A chunks q0,q0+1 (2 gloads)
    gload16(gA + (size_t)q0*8*Kfull + k0,     &As[buf][dL + q0*512]);
    gload16(gA + (size_t)(q0+1)*8*Kfull + k0, &As[buf][dL + (q0+1)*512]);
  };
  auto SB2 = [&](int buf, int k0, int q0){
    gload16(gB + (size_t)q0*8*Kfull + k0,     &Bs[buf][dL + q0*512]);
    gload16(gB + (size_t)(q0+1)*8*Kfull + k0, &Bs[buf][dL + (q0+1)*512]);
  };

  const int rA = wr*128 + lr;   // + mi*16, row in A tile
  const int rB = wc*64  + lr;   // + ni*16, row in B tile
  const int g0 = ((lk     ) ^ (lr&7))*8;   // ks0 swizzled granule
  const int g1 = ((lk +  4) ^ (lr&7))*8;   // ks1 swizzled granule

  const int nt = Klen/BK;
  // prologue: stage tile 0 fully
  SA2(0, 0, 0); SA2(0, 0, 2); SB2(0, 0, 0); SB2(0, 0, 2);
  int cur = 0;
  for (int t=0; t<nt; ++t){
    const bool pf = (t+1 < nt);
    const int nxt = cur^1;
    const int kn = (t+1)*BK;
    const ushort_t* as = &As[cur][0];
    const ushort_t* bs = &Bs[cur][0];
    short8v af[8], bfv[4];
    // ---- phase 0: ks0, mi 0-3 ----
    if (pf){ SA2(nxt, kn, 0);
             asm volatile("s_waitcnt vmcnt(2)" ::: "memory"); }
    else     asm volatile("s_waitcnt vmcnt(0)" ::: "memory");
    __builtin_amdgcn_sched_barrier(0);
    __builtin_amdgcn_s_barrier();
    __builtin_amdgcn_sched_barrier(0);
    #pragma unroll
    for (int mi=0;mi<4;++mi) af[mi]  = *(const short8v*)&as[(rA+mi*16)*64 + g0];
    #pragma unroll
    for (int ni=0;ni<4;++ni) bfv[ni] = *(const short8v*)&bs[(rB+ni*16)*64 + g0];
    if (pf) SA2(nxt, kn, 2);
    asm volatile("s_waitcnt lgkmcnt(0)" ::: "memory");
    __builtin_amdgcn_sched_barrier(0);
    __builtin_amdgcn_s_setprio(1);
    #pragma unroll
    for (int mi=0;mi<4;++mi)
      #pragma unroll
      for (int ni=0;ni<4;++ni)
        acc[mi][ni] = __builtin_amdgcn_mfma_f32_16x16x32_bf16(af[mi], bfv[ni], acc[mi][ni], 0,0,0);
    __builtin_amdgcn_s_setprio(0);
    __builtin_amdgcn_s_barrier();
    // ---- phase 1: ks0, mi 4-7 ----
    #pragma unroll
    for (int mi=4;mi<8;++mi) af[mi] = *(const short8v*)&as[(rA+mi*16)*64 + g0];
    if (pf) SB2(nxt, kn, 0);
    asm volatile("s_waitcnt lgkmcnt(0)" ::: "memory");
    __builtin_amdgcn_sched_barrier(0);
    __builtin_amdgcn_s_setprio(1);
    #pragma unroll
    for (int mi=4;mi<8;++mi)
      #pragma unroll
      for (int ni=0;ni<4;++ni)
        acc[mi][ni] = __builtin_amdgcn_mfma_f32_16x16x32_bf16(af[mi], bfv[ni], acc[mi][ni], 0,0,0);
    __builtin_amdgcn_s_setprio(0);
    __builtin_amdgcn_s_barrier();
    // ---- phase 2: ks1, mi 0-3 ----
    #pragma unroll
    for (int mi=0;mi<4;++mi) af[mi]  = *(const short8v*)&as[(rA+mi*16)*64 + g1];
    #pragma unroll
    for (int ni=0;ni<4;++ni) bfv[ni] = *(const short8v*)&bs[(rB+ni*16)*64 + g1];
    if (pf) SB2(nxt, kn, 2);
    asm volatile("s_waitcnt lgkmcnt(0)" ::: "memory");
    __builtin_amdgcn_sched_barrier(0);
    __builtin_amdgcn_s_setprio(1);
    #pragma unroll
    for (int mi=0;mi<4;++mi)
      #pragma unroll
      for (int ni=0;ni<4;++ni)
        acc[mi][ni] = __builtin_amdgcn_mfma_f32_16x16x32_bf16(af[mi], bfv[ni], acc[mi][ni], 0,0,0);
    __builtin_amdgcn_s_setprio(0);
    __builtin_amdgcn_s_barrier();
    // ---- phase 3: ks1, mi 4-7 ----
    #pragma unroll
    for (int mi=4;mi<8;++mi) af[mi] = *(const short8v*)&as[(rA+mi*16)*64 + g1];
    asm volatile("s_waitcnt lgkmcnt(0)" ::: "memory");
    __builtin_amdgcn_sched_barrier(0);
    __builtin_amdgcn_s_setprio(1);
    #pragma unroll
    for (int mi=4;mi<8;++mi)
      #pragma unroll
      for (int ni=0;ni<4;++ni)
        acc[mi][ni] = __builtin_amdgcn_mfma_f32_16x16x32_bf16(af[mi], bfv[ni], acc[mi][ni], 0,0,0);
    __builtin_amdgcn_s_setprio(0);
    __builtin_amdgcn_s_barrier();
    cur ^= 1;
  }
  // epilogue
  const int rowb = bm + wr*128 + lk*4;
  const int colb = ncb + wc*64 + lr;
  if (OUTBF){
    ushort_t* C = (ushort_t*)(mat ? C1 : C0);
    #pragma unroll
    for (int mi=0;mi<8;++mi)
      #pragma unroll
      for (int ni=0;ni<4;++ni)
        #pragma unroll
        for (int rr2=0;rr2<4;++rr2)
          C[(size_t)(rowb+mi*16+rr2)*N + colb + ni*16] = f2bf(acc[mi][ni][rr2]);
  } else {
    float* C = (float*)C0 + (size_t)s*M*N;
    #pragma unroll
    for (int mi=0;mi<8;++mi)
      #pragma unroll
      for (int ni=0;ni<4;++ni)
        #pragma unroll
        for (int rr2=0;rr2<4;++rr2)
          C[(size_t)(rowb+mi*16+rr2)*N + colb + ni*16] = acc[mi][ni][rr2];
  }
}

// ---------------- split-K reduce: out = sum of 4 partials ----------------
__global__ __launch_bounds__(256) void reduce4(const float* __restrict__ part, float* __restrict__ out){
  size_t i = ((size_t)blockIdx.x*256 + threadIdx.x)*4;
  if (i >= (size_t)NT*H) return;
  const size_t S = (size_t)NT*H;
  float4 a = *(const float4*)(part+i);
  float4 b = *(const float4*)(part+S+i);
  float4 c = *(const float4*)(part+2*S+i);
  float4 d = *(const float4*)(part+3*S+i);
  float4 o;
  o.x = a.x+b.x+c.x+d.x; o.y = a.y+b.y+c.y+d.y;
  o.z = a.z+b.z+c.z+d.z; o.w = a.w+b.w+c.w+d.w;
  *(float4*)(out+i) = o;
}

// ---------------- fallback fp32-B fused-cvt GEMM ----------------
template<int BN, bool OUTBF>
__global__ __launch_bounds__(256) void gemm_bt(const ushort_t* __restrict__ A,
    const float* __restrict__ Bw, void* __restrict__ Cout, int M, int N, int K){
  constexpr int BM=128, BK=32, LD=40;
  __shared__ ushort_t As[BM*LD];
  __shared__ ushort_t Bs[BN*LD];
  const int tid = threadIdx.x;
  const int bm = blockIdx.x*BM, bn = blockIdx.y*BN;
  const int wv = tid>>6, lane = tid&63;
  const int wm = (wv>>1)*64, wn = (wv&1)*(BN/2);
  const int lr = lane&15, lk = lane>>4;
  constexpr int NJ = BN/32;
  f32x4 acc[4][NJ];
  #pragma unroll
  for (int i=0;i<4;++i)
    #pragma unroll
    for (int j=0;j<NJ;++j) acc[i][j] = (f32x4){0.f,0.f,0.f,0.f};
  const int arow = tid>>1, ak=(tid&1)*16;
  constexpr int BPT = BN*BK/256;
  const int brow = (BN==128)?(tid>>1):(tid>>2);
  const int bk   = (BN==128)?((tid&1)*16):((tid&3)*8);
  const ushort_t* gA = A + (size_t)(bm+arow)*K + ak;
  const float*    gB = Bw + (size_t)(bn+brow)*K + bk;
  for (int k0=0;k0<K;k0+=BK){
    ushort8 a0 = *(const ushort8*)(gA + k0);
    ushort8 a1 = *(const ushort8*)(gA + k0 + 8);
    float vals[BPT];
    #pragma unroll
    for (int i=0;i<BPT;i+=4){
      float4 v = *(const float4*)(gB + k0 + i);
      vals[i]=v.x; vals[i+1]=v.y; vals[i+2]=v.z; vals[i+3]=v.w;
    }
    *(ushort8*)&As[arow*LD+ak]   = a0;
    *(ushort8*)&As[arow*LD+ak+8] = a1;
    #pragma unroll
    for (int i=0;i<BPT;i+=8){
      ushort8 u;
      #pragma unroll
      for (int q=0;q<8;++q) u[q]=f2bf(vals[i+q]);
      *(ushort8*)&Bs[brow*LD+bk+i] = u;
    }
    __syncthreads();
    short8v af[4], bfv[NJ];
    #pragma unroll
    for (int i=0;i<4;++i) af[i] = *(const short8v*)&As[(wm+i*16+lr)*LD + lk*8];
    #pragma unroll
    for (int j=0;j<NJ;++j) bfv[j] = *(const short8v*)&Bs[(wn+j*16+lr)*LD + lk*8];
    #pragma unroll
    for (int i=0;i<4;++i)
      #pragma unroll
      for (int j=0;j<NJ;++j)
        acc[i][j] = __builtin_amdgcn_mfma_f32_16x16x32_bf16(af[i], bfv[j], acc[i][j], 0,0,0);
    __syncthreads();
  }
  #pragma unroll
  for (int i=0;i<4;++i)
    #pragma unroll
    for (int j=0;j<NJ;++j)
      #pragma unroll
      for (int r=0;r<4;++r){
        int row = bm + wm + i*16 + lk*4 + r;
        int col = bn + wn + j*16 + lr;
        if (OUTBF) ((ushort_t*)Cout)[(size_t)row*N + col] = f2bf(acc[i][j][r]);
        else       ((float*)Cout)[(size_t)row*N + col]    = acc[i][j][r];
      }
}

// ---------------- LoRA A projections via MFMA ----------------
__global__ __launch_bounds__(256) void lora_a_mfma(const int* __restrict__ meta,
    const int* __restrict__ list_tok, const ushort_t* __restrict__ xbf,
    const float* __restrict__ A1, const float* __restrict__ A3,
    ushort_t* __restrict__ u1bf, ushort_t* __restrict__ u3bf){
  int ti = blockIdx.x;
  if (ti >= meta[0]) return;
  int e  = meta[1+ti];
  int p0 = meta[1+MAXT+ti];
  int np = meta[1+2*MAXT+ti];
  int wv = threadIdx.x>>6, lane = threadIdx.x&63;
  int lr = lane&15, lk = lane>>4;
  int t = list_tok[p0+lr];
  const ushort_t* xrow = xbf + (size_t)t*H;
  const int kbase = wv*(H/4);
  f32x4 acc1[2], acc3[2];
  #pragma unroll
  for (int j=0;j<2;++j){ acc1[j]=(f32x4){0,0,0,0}; acc3[j]=(f32x4){0,0,0,0}; }
  for (int ks=0; ks<H/4; ks+=32){
    int k = kbase + ks + lk*8;
    short8v a = *(const short8v*)(xrow + k);
    #pragma unroll
    for (int j=0;j<2;++j){
      const float* b1 = A1 + ((size_t)e*RR + j*16 + lr)*H + k;
      const float* b3 = A3 + ((size_t)e*RR + j*16 + lr)*H + k;
      acc1[j] = __builtin_amdgcn_mfma_f32_16x16x32_bf16(a, cvt8(b1), acc1[j], 0,0,0);
      acc3[j] = __builtin_amdgcn_mfma_f32_16x16x32_bf16(a, cvt8(b3), acc3[j], 0,0,0);
    }
  }
  __shared__ float red[4][2][2][4][64];
  #pragma unroll
  for (int j=0;j<2;++j)
    #pragma unroll
    for (int r=0;r<4;++r){
      red[wv][0][j][r][lane] = acc1[j][r];
      red[wv][1][j][r][lane] = acc3[j][r];
    }
  __syncthreads();
  if (wv==0){
    #pragma unroll
    for (int j=0;j<2;++j)
      #pragma unroll
      for (int r=0;r<4;++r){
        int p = lk*4 + r;
        if (p < np){
          float s1 = red[0][0][j][r][lane]+red[1][0][j][r][lane]+red[2][0][j][r][lane]+red[3][0][j][r][lane];
          float s3 = red[0][1][j][r][lane]+red[1][1][j][r][lane]+red[2][1][j][r][lane]+red[3][1][j][r][lane];
          u1bf[(size_t)(p0+p)*RR + j*16 + lr] = f2bf(s1);
          u3bf[(size_t)(p0+p)*RR + j*16 + lr] = f2bf(s3);
        }
      }
  }
}

// ---------------- per-expert fused: d1/d3 via MFMA, silu, x2 ----------------
template<typename WT>
__global__ __launch_bounds__(256) void expert_x2(const int* __restrict__ meta, const int* __restrict__ list_tok,
    const WT* __restrict__ B1g, const WT* __restrict__ B3g,
    const ushort_t* __restrict__ u1bf, const ushort_t* __restrict__ u3bf,
    const ushort_t* __restrict__ x1b, const ushort_t* __restrict__ x3b,
    ushort_t* __restrict__ x2buf){
  int ti = blockIdx.x;
  if (ti >= meta[0]) return;
  int e  = meta[1+ti];
  int p0 = meta[1+MAXT+ti];
  int np = meta[1+2*MAXT+ti];
  int fc = blockIdx.y*128 + (threadIdx.x>>6)*32;
  int lane = threadIdx.x&63;
  int lr = lane&15, lk = lane>>4;
  short8v au1 = *(const short8v*)(u1bf + (size_t)(p0+lr)*RR + lk*8);
  short8v au3 = *(const short8v*)(u3bf + (size_t)(p0+lr)*RR + lk*8);
  f32x4 z = (f32x4){0.f,0.f,0.f,0.f};
  f32x4 acc1[2], acc3[2];
  #pragma unroll
  for (int j=0;j<2;++j){
    acc1[j]=z; acc3[j]=z;
    int f = fc + j*16 + lr;
    const WT* b1r = B1g + ((size_t)e*F + f)*RR + lk*8;
    const WT* b3r = B3g + ((size_t)e*F + f)*RR + lk*8;
    acc1[j] = __builtin_amdgcn_mfma_f32_16x16x32_bf16(au1, load8w(b1r), acc1[j], 0,0,0);
    acc3[j] = __builtin_amdgcn_mfma_f32_16x16x32_bf16(au3, load8w(b3r), acc3[j], 0,0,0);
  }
  #pragma unroll
  for (int r=0;r<4;++r){
    int p = lk*4 + r;
    if (p < np){
      int t = list_tok[p0+p];
      #pragma unroll
      for (int j=0;j<2;++j){
        int f = fc + j*16 + lr;
        size_t ix = (size_t)t*F + f;
        float x1  = bf2f(x1b[ix]) + acc1[j][r];
        float x3v = bf2f(x3b[ix]) + acc3[j][r];
        float sl = x1/(1.f + __expf(-x1));
        x2buf[(size_t)(p0+p)*F + f] = f2bf(sl*x3v);
      }
    }
  }
}

// ---------------- combine ----------------
__global__ __launch_bounds__(256) void combine_x2(const int* __restrict__ tok2pair, const float* __restrict__ rwn,
    const ushort_t* __restrict__ x2buf, ushort_t* __restrict__ x2c){
  size_t i = (size_t)blockIdx.x*256 + threadIdx.x;
  size_t total = (size_t)NT*(F/8);
  if (i>=total) return;
  int t = (int)(i/(F/8));
  int c = (int)(i%(F/8))*8;
  int pa = tok2pair[t*2], pb = tok2pair[t*2+1];
  float wa = rwn[t*2], wb = rwn[t*2+1];
  ushort8 va = *(const ushort8*)(x2buf + (size_t)pa*F + c);
  ushort8 vb = *(const ushort8*)(x2buf + (size_t)pb*F + c);
  ushort8 o;
  #pragma unroll
  for (int q=0;q<8;++q) o[q] = f2bf(wa*bf2f(va[q]) + wb*bf2f(vb[q]));
  *(ushort8*)(x2c + (size_t)t*F + c) = o;
}

// ---------------- u2 = A2[e] @ x2 via MFMA ----------------
__global__ __launch_bounds__(256) void u2_mfma(const int* __restrict__ meta,
    const float* __restrict__ A2, const ushort_t* __restrict__ x2buf, float* __restrict__ u2){
  int ti = blockIdx.x;
  if (ti >= meta[0]) return;
  int e  = meta[1+ti];
  int p0 = meta[1+MAXT+ti];
  int np = meta[1+2*MAXT+ti];
  int wv = threadIdx.x>>6, lane = threadIdx.x&63;
  int lr = lane&15, lk = lane>>4;
  const ushort_t* xrow = x2buf + (size_t)(p0+lr)*F;
  const int kbase = wv*(F/4);
  f32x4 acc[2];
  acc[0]=(f32x4){0,0,0,0}; acc[1]=(f32x4){0,0,0,0};
  for (int ks=0; ks<F/4; ks+=32){
    int k = kbase + ks + lk*8;
    short8v a = *(const short8v*)(xrow + k);
    #pragma unroll
    for (int j=0;j<2;++j){
      const float* br = A2 + ((size_t)e*RR + j*16 + lr)*F + k;
      acc[j] = __builtin_amdgcn_mfma_f32_16x16x32_bf16(a, cvt8(br), acc[j], 0,0,0);
    }
  }
  __shared__ float red[4][2][4][64];
  #pragma unroll
  for (int j=0;j<2;++j)
    #pragma unroll
    for (int r=0;r<4;++r) red[wv][j][r][lane] = acc[j][r];
  __syncthreads();
  if (wv==0){
    #pragma unroll
    for (int j=0;j<2;++j)
      #pragma unroll
      for (int r=0;r<4;++r){
        int p = lk*4 + r;
        if (p < np){
          float s = red[0][j][r][lane]+red[1][j][r][lane]+red[2][j][r][lane]+red[3][j][r][lane];
          u2[(size_t)(p0+p)*RR + j*16 + lr] = s;
        }
      }
  }
}

// ---------------- lora2 add ----------------
__global__ __launch_bounds__(256) void lora2_add(const int* __restrict__ tok2pair, const int* __restrict__ list_e,
    const float* __restrict__ rwn, const float* __restrict__ B2, const float* __restrict__ u2,
    float* __restrict__ out){
  int t = blockIdx.x;
  __shared__ float u2s[2][RR];
  __shared__ int es[2];
  __shared__ float wss[2];
  if (threadIdx.x < 64){
    int s = threadIdx.x>>5, r = threadIdx.x&31;
    int pair = tok2pair[t*2+s];
    u2s[s][r] = u2[(size_t)pair*RR + r];
    if (r==0){ es[s]=list_e[pair]; wss[s]=rwn[t*2+s]; }
  }
  __syncthreads();
  int e0=es[0], e1=es[1];
  float w0=wss[0], w1=wss[1];
  for (int h=threadIdx.x; h<H; h+=256){
    const float4* b0 = (const float4*)(B2 + ((size_t)e0*H + h)*RR);
    const float4* b1 = (const float4*)(B2 + ((size_t)e1*H + h)*RR);
    float d0=0.f, d1=0.f;
    #pragma unroll
    for (int c=0;c<RR/4;++c){
      float4 v0=b0[c]; d0 += v0.x*u2s[0][c*4+0] + v0.y*u2s[0][c*4+1] + v0.z*u2s[0][c*4+2] + v0.w*u2s[0][c*4+3];
      float4 v1=b1[c]; d1 += v1.x*u2s[1][c*4+0] + v1.y*u2s[1][c*4+1] + v1.z*u2s[1][c*4+2] + v1.w*u2s[1][c*4+3];
    }
    out[(size_t)t*H + h] += w0*d0 + w1*d1;
  }
}

extern "C" void kernel_launch(void* const* d_in, const int* in_sizes, int n_in,
                              void* d_out, int out_size, void* d_ws, size_t ws_size,
                              hipStream_t stream){
  const float* x   = (const float*)d_in[0];
  const float* gw  = (const float*)d_in[1];
  const float* W1  = (const float*)d_in[2];
  const float* W2  = (const float*)d_in[3];
  const float* W3  = (const float*)d_in[4];
  const float* A1  = (const float*)d_in[5];
  const float* B1  = (const float*)d_in[6];
  const float* A2  = (const float*)d_in[7];
  const float* B2  = (const float*)d_in[8];
  const float* A3  = (const float*)d_in[9];
  const float* B3  = (const float*)d_in[10];
  float* outF = (float*)d_out;
  float* outL = outF + (size_t)NT*H;

  char* base = (char*)d_ws;
  size_t o = 0;
  auto mk = [&](size_t bytes){ void* p = base + o; o += (bytes + 255) & ~(size_t)255; return p; };
  int*   sel      = (int*)  mk((size_t)NT*2*4);
  float* rwn      = (float*)mk((size_t)NT*2*4);
  int*   cnts     = (int*)  mk(512);
  int*   cnt      = cnts;
  int*   cnt2     = cnts + 64;
  int*   off      = (int*)  mk(256);
  int*   meta     = (int*)  mk((size_t)(1+3*MAXT)*4);
  int*   list_tok = (int*)  mk((size_t)NPAIRP*4);
  int*   list_e   = (int*)  mk((size_t)NPAIRP*4);
  int*   tok2pair = (int*)  mk((size_t)NT*2*4);
  ushort_t* xbf   = (ushort_t*)mk((size_t)NT*H*2);
  ushort_t* x1b   = (ushort_t*)mk((size_t)NT*F*2);
  ushort_t* x3b   = (ushort_t*)mk((size_t)NT*F*2);
  ushort_t* x2buf = (ushort_t*)mk((size_t)NPAIRP*F*2);
  ushort_t* x2c   = (ushort_t*)mk((size_t)NT*F*2);
  ushort_t* u1bf  = (ushort_t*)mk((size_t)NPAIRP*RR*2);
  ushort_t* u3bf  = (ushort_t*)mk((size_t)NPAIRP*RR*2);
  float* u2       = (float*)mk((size_t)NPAIRP*RR*4);
  // bf16 weight copies (used only if ws is large enough)
  ushort_t* w1bf = (ushort_t*)mk((size_t)F*H*2);
  ushort_t* w3bf = (ushort_t*)mk((size_t)F*H*2);
  ushort_t* w2bf = (ushort_t*)mk((size_t)H*F*2);
  ushort_t* b1bf = (ushort_t*)mk((size_t)NE*F*RR*2);
  ushort_t* b3bf = (ushort_t*)mk((size_t)NE*F*RR*2);
  // split-K partials alias w1bf (64 MB <= 114 MB): w1bf is dead once the fused
  // W1|W3 GEMM completes, and the W2 GEMM is stream-ordered after it.
  float* part = (float*)w1bf;
  bool useBF = (o <= ws_size);
  (void)in_sizes; (void)n_in; (void)out_size;

  hipMemsetAsync(cnts, 0, 512, stream);
  cast_x<<<(NT*H/4)/256, 256, 0, stream>>>(x, xbf);
  router_kernel<<<NT/4, 256, 0, stream>>>(x, gw, outL, sel, rwn, cnt);
  prefix_kernel<<<1, 1, 0, stream>>>(cnt, off, meta);
  scatter_kernel<<<(NPAIRP+255)/256, 256, 0, stream>>>(sel, off, cnt2, list_tok, list_e, tok2pair);

  if (useBF){
    cast_f2bf<<<2048, 256, 0, stream>>>(W1, w1bf, (long)F*H/8);
    cast_f2bf<<<2048, 256, 0, stream>>>(W3, w3bf, (long)F*H/8);
    cast_f2bf<<<2048, 256, 0, stream>>>(W2, w2bf, (long)H*F/8);
    cast_f2bf<<<512, 256, 0, stream>>>(B1, b1bf, (long)NE*F*RR/8);
    cast_f2bf<<<512, 256, 0, stream>>>(B3, b3bf, (long)NE*F*RR/8);
    // W1|W3 fused: M=1024, per-matrix N=F, GN=56, GNt=112 -> 4*112 = 448 blocks
    gemm_256<true><<<448, 512, 0, stream>>>(xbf, w1bf, w3bf, x1b, x3b,
                                            NT, F, F/256, 2*(F/256), H, H);
    lora_a_mfma<<<MAXT, 256, 0, stream>>>(meta, list_tok, xbf, A1, A3, u1bf, u3bf);
    expert_x2<ushort_t><<<dim3(MAXT, F/128), 256, 0, stream>>>(meta, list_tok, b1bf, b3bf, u1bf, u3bf, x1b, x3b, x2buf);
    combine_x2<<<(NT*(F/8))/256, 256, 0, stream>>>(tok2pair, rwn, x2buf, x2c);
    u2_mfma<<<MAXT, 256, 0, stream>>>(meta, A2, x2buf, u2);
    // W2 with split-K=4: M=1024, N=H, GN=GNt=16, Klen=F/4 -> 4*16*4 = 256 blocks
    gemm_256<false><<<256, 512, 0, stream>>>(x2c, w2bf, w2bf, part, part,
                                             NT, H, H/256, H/256, F/4, F);
    reduce4<<<(NT*H/4)/256, 256, 0, stream>>>(part, outF);
  } else {
    gemm_bt<128,true><<<dim3(NT/128, F/128), 256, 0, stream>>>(xbf, W1, x1b, NT, F, H);
    gemm_bt<128,true><<<dim3(NT/128, F/128), 256, 0, stream>>>(xbf, W3, x3b, NT, F, H);
    lora_a_mfma<<<MAXT, 256, 0, stream>>>(meta, list_tok, xbf, A1, A3, u1bf, u3bf);
    expert_x2<float><<<dim3(MAXT, F/128), 256, 0, stream>>>(meta, list_tok, B1, B3, u1bf, u3bf, x1b, x3b, x2buf);
    combine_x2<<<(NT*(F/8))/256, 256, 0, stream>>>(tok2pair, rwn, x2buf, x2c);
    u2_mfma<<<MAXT, 256, 0, stream>>>(meta, A2, x2buf, u2);
    gemm_bt<128,false><<<dim3(NT/128, H/128), 256, 0, stream>>>(x2c, W2, outF, NT, H, F);
  }
  lora2_add<<<NT, 256, 0, stream>>>(tok2pair, list_e, rwn, B2, u2, outF);
}